// Round 1
// baseline (9082.767 us; speedup 1.0000x reference)
//
#include <hip/hip_runtime.h>

#define NTOK 22500
#define N1   22501
#define NPAD 22528
#define PADR 27
#define DIM  512
#define NH   8
#define DHD  64
#define MM   256
#define LLM  88
#define HSZ  150
#define CSZ  512
#define NCH  44   // NPAD / CSZ

// ---------------- reduction helpers ----------------
__device__ __forceinline__ float waveSum(float v){
#pragma unroll
  for (int o=32;o>0;o>>=1) v += __shfl_down(v,o);
  return v;
}
__device__ __forceinline__ float waveMax(float v){
#pragma unroll
  for (int o=32;o>0;o>>=1) v = fmaxf(v,__shfl_down(v,o));
  return v;
}
__device__ __forceinline__ float blockSum256(float v, float* sb){
  v = waveSum(v);
  __syncthreads();
  if ((threadIdx.x&63)==0) sb[threadIdx.x>>6]=v;
  __syncthreads();
  return sb[0]+sb[1]+sb[2]+sb[3];
}
__device__ __forceinline__ float blockMax256(float v, float* sb){
  v = waveMax(v);
  __syncthreads();
  if ((threadIdx.x&63)==0) sb[threadIdx.x>>6]=v;
  __syncthreads();
  return fmaxf(fmaxf(sb[0],sb[1]),fmaxf(sb[2],sb[3]));
}

// ---------------- fc1: (22500x1024)@(1024x512)+bias, relu -> X rows 1.. ----------------
__global__ __launch_bounds__(256) void k_fc1(const float* __restrict__ A,
    const float* __restrict__ B, const float* __restrict__ bias, float* __restrict__ X)
{
  __shared__ float As[16][64];
  __shared__ float Bs[16][64];
  const int tid = threadIdx.x;
  const int m0 = blockIdx.x*64, n0 = blockIdx.y*64;
  const int tm = tid>>4, tn = tid&15;
  const int lr = tid>>2, lk4 = (tid&3)*4;
  const int lbk = tid>>4, lc4 = (tid&15)*4;
  float acc[4][4] = {};
  for (int k0=0;k0<1024;k0+=16){
    int gm = m0+lr;
    float4 av = (gm<NTOK) ? *(const float4*)(A + (size_t)gm*1024 + k0 + lk4)
                          : make_float4(0.f,0.f,0.f,0.f);
    As[lk4+0][lr]=av.x; As[lk4+1][lr]=av.y; As[lk4+2][lr]=av.z; As[lk4+3][lr]=av.w;
    float4 bv = *(const float4*)(B + (size_t)(k0+lbk)*DIM + n0 + lc4);
    Bs[lbk][lc4+0]=bv.x; Bs[lbk][lc4+1]=bv.y; Bs[lbk][lc4+2]=bv.z; Bs[lbk][lc4+3]=bv.w;
    __syncthreads();
#pragma unroll
    for (int kk=0;kk<16;++kk){
      float a_[4], b_[4];
#pragma unroll
      for (int i=0;i<4;++i) a_[i]=As[kk][tm*4+i];
#pragma unroll
      for (int j=0;j<4;++j) b_[j]=Bs[kk][tn*4+j];
#pragma unroll
      for (int i=0;i<4;++i)
#pragma unroll
        for (int j=0;j<4;++j) acc[i][j] += a_[i]*b_[j];
    }
    __syncthreads();
  }
#pragma unroll
  for (int i=0;i<4;++i){
    int gm = m0 + tm*4 + i;
    if (gm < NTOK){
#pragma unroll
      for (int j=0;j<4;++j){
        int gn = n0 + tn*4 + j;
        float v = acc[i][j] + bias[gn];
        X[(size_t)(1+gm)*DIM + gn] = v>0.f ? v : 0.f;
      }
    }
  }
}

__global__ void k_setcls(float* __restrict__ X, const float* __restrict__ cls){
  int i = blockIdx.x*256 + threadIdx.x;
  if (i < DIM) X[i] = cls[i];
}
__global__ void k_copy(float* __restrict__ d, const float* __restrict__ s, size_t n){
  size_t i = (size_t)blockIdx.x*256 + threadIdx.x;
  if (i<n) d[i]=s[i];
}

// ---------------- layernorm over rows of 512 ----------------
__global__ void k_ln(const float* __restrict__ X, float* __restrict__ Y,
                     const float* __restrict__ w, const float* __restrict__ b)
{
  __shared__ float sb[4];
  const float* x = X + (size_t)blockIdx.x*DIM;
  float* y = Y + (size_t)blockIdx.x*DIM;
  int t = threadIdx.x;
  float a0=x[t], a1=x[t+256];
  float s = blockSum256(a0+a1, sb);
  float q = blockSum256(a0*a0+a1*a1, sb);
  float mean = s*(1.f/512.f);
  float var = q*(1.f/512.f) - mean*mean;
  float rstd = rsqrtf(var+1e-5f);
  y[t]     = (a0-mean)*rstd*w[t]+b[t];
  y[t+256] = (a1-mean)*rstd*w[t+256]+b[t+256];
}

// ---------------- qkv: padded (NPADx512)@(512x1536), scatter to Q/K/V head layout ----------------
__global__ __launch_bounds__(256) void k_qkv(const float* __restrict__ Y, const float* __restrict__ B,
    float* __restrict__ Q, float* __restrict__ K, float* __restrict__ V)
{
  __shared__ float As[16][64];
  __shared__ float Bs[16][64];
  const int tid = threadIdx.x;
  const int m0 = blockIdx.x*64, n0 = blockIdx.y*64;
  const int tm = tid>>4, tn = tid&15;
  const int lr = tid>>2, lk4 = (tid&3)*4;
  const int lbk = tid>>4, lc4 = (tid&15)*4;
  float acc[4][4] = {};
  for (int k0=0;k0<DIM;k0+=16){
    int gm = m0+lr;
    float4 av = (gm>=PADR) ? *(const float4*)(Y + (size_t)(gm-PADR)*DIM + k0 + lk4)
                           : make_float4(0.f,0.f,0.f,0.f);
    As[lk4+0][lr]=av.x; As[lk4+1][lr]=av.y; As[lk4+2][lr]=av.z; As[lk4+3][lr]=av.w;
    float4 bv = *(const float4*)(B + (size_t)(k0+lbk)*1536 + n0 + lc4);
    Bs[lbk][lc4+0]=bv.x; Bs[lbk][lc4+1]=bv.y; Bs[lbk][lc4+2]=bv.z; Bs[lbk][lc4+3]=bv.w;
    __syncthreads();
#pragma unroll
    for (int kk=0;kk<16;++kk){
      float a_[4], b_[4];
#pragma unroll
      for (int i=0;i<4;++i) a_[i]=As[kk][tm*4+i];
#pragma unroll
      for (int j=0;j<4;++j) b_[j]=Bs[kk][tn*4+j];
#pragma unroll
      for (int i=0;i<4;++i)
#pragma unroll
        for (int j=0;j<4;++j) acc[i][j] += a_[i]*b_[j];
    }
    __syncthreads();
  }
  const int bt = blockIdx.y>>3;   // 0=q,1=k,2=v
  const int hh = blockIdx.y&7;
  float* dst = bt==0 ? Q : (bt==1 ? K : V);
  const float sc = bt==0 ? 0.125f : 1.f;
#pragma unroll
  for (int i=0;i<4;++i){
    int gm = m0+tm*4+i;
#pragma unroll
    for (int j=0;j<4;++j){
      int dh = tn*4+j;
      dst[((size_t)hh*NPAD+gm)*DHD + dh] = acc[i][j]*sc;
    }
  }
}

// ---------------- qk head-0 only (cls stage) ----------------
__global__ __launch_bounds__(256) void k_qk0(const float* __restrict__ Y, const float* __restrict__ B,
    float* __restrict__ Q0, float* __restrict__ K0)
{
  __shared__ float As[16][64];
  __shared__ float Bs[16][64];
  const int tid = threadIdx.x;
  const int m0 = blockIdx.x*64;
  const int colbase = (blockIdx.y==0) ? 0 : 512;
  const int tm = tid>>4, tn = tid&15;
  const int lr = tid>>2, lk4 = (tid&3)*4;
  const int lbk = tid>>4, lc4 = (tid&15)*4;
  float acc[4][4] = {};
  for (int k0=0;k0<DIM;k0+=16){
    int gm = m0+lr;
    float4 av = (gm>=PADR) ? *(const float4*)(Y + (size_t)(gm-PADR)*DIM + k0 + lk4)
                           : make_float4(0.f,0.f,0.f,0.f);
    As[lk4+0][lr]=av.x; As[lk4+1][lr]=av.y; As[lk4+2][lr]=av.z; As[lk4+3][lr]=av.w;
    float4 bv = *(const float4*)(B + (size_t)(k0+lbk)*1536 + colbase + lc4);
    Bs[lbk][lc4+0]=bv.x; Bs[lbk][lc4+1]=bv.y; Bs[lbk][lc4+2]=bv.z; Bs[lbk][lc4+3]=bv.w;
    __syncthreads();
#pragma unroll
    for (int kk=0;kk<16;++kk){
      float a_[4], b_[4];
#pragma unroll
      for (int i=0;i<4;++i) a_[i]=As[kk][tm*4+i];
#pragma unroll
      for (int j=0;j<4;++j) b_[j]=Bs[kk][tn*4+j];
#pragma unroll
      for (int i=0;i<4;++i)
#pragma unroll
        for (int j=0;j<4;++j) acc[i][j] += a_[i]*b_[j];
    }
    __syncthreads();
  }
#pragma unroll
  for (int i=0;i<4;++i){
    int gm = m0+tm*4+i;
#pragma unroll
    for (int j=0;j<4;++j){
      int c = tn*4+j;
      if (blockIdx.y==0) Q0[(size_t)gm*DHD+c] = acc[i][j]*0.125f;
      else               K0[(size_t)gm*DHD+c] = acc[i][j];
    }
  }
}

// ---------------- landmarks: mean over 88 contiguous rows ----------------
__global__ void k_landmark(const float* __restrict__ src, float* __restrict__ dst)
{
  int hm = blockIdx.x; int h = hm>>8, m = hm&255; int d = threadIdx.x;
  const float* base = src + ((size_t)h*NPAD + (size_t)m*LLM)*DHD + d;
  float s = 0.f;
  for (int j=0;j<LLM;++j) s += base[(size_t)j*DHD];
  dst[((size_t)h*MM + m)*DHD + d] = s * (1.f/(float)LLM);
}

// ---------------- batched GEMMs (tiles of 64x64, 4x4/thread) ----------------
__global__ __launch_bounds__(256) void k_bgemm_nn(const float* __restrict__ A,
    const float* __restrict__ B, float* __restrict__ C,
    int Kr, int Nr, long sA, long sB, long sC, float alpha)
{
  A += (size_t)blockIdx.z * sA; B += (size_t)blockIdx.z * sB; C += (size_t)blockIdx.z * sC;
  __shared__ float As[16][64];
  __shared__ float Bs[16][64];
  const int tid = threadIdx.x;
  const int m0 = blockIdx.y*64, n0 = blockIdx.x*64;
  const int tm = tid>>4, tn = tid&15;
  const int lr = tid>>2, lk4 = (tid&3)*4;
  const int lbk = tid>>4, lc4 = (tid&15)*4;
  float acc[4][4] = {};
  for (int k0=0;k0<Kr;k0+=16){
    float4 av = *(const float4*)(A + (size_t)(m0+lr)*Kr + k0 + lk4);
    As[lk4+0][lr]=av.x; As[lk4+1][lr]=av.y; As[lk4+2][lr]=av.z; As[lk4+3][lr]=av.w;
    float4 bv = *(const float4*)(B + (size_t)(k0+lbk)*Nr + n0 + lc4);
    Bs[lbk][lc4+0]=bv.x; Bs[lbk][lc4+1]=bv.y; Bs[lbk][lc4+2]=bv.z; Bs[lbk][lc4+3]=bv.w;
    __syncthreads();
#pragma unroll
    for (int kk=0;kk<16;++kk){
      float a_[4], b_[4];
#pragma unroll
      for (int i=0;i<4;++i) a_[i]=As[kk][tm*4+i];
#pragma unroll
      for (int j=0;j<4;++j) b_[j]=Bs[kk][tn*4+j];
#pragma unroll
      for (int i=0;i<4;++i)
#pragma unroll
        for (int j=0;j<4;++j) acc[i][j] += a_[i]*b_[j];
    }
    __syncthreads();
  }
#pragma unroll
  for (int i=0;i<4;++i)
#pragma unroll
    for (int j=0;j<4;++j)
      C[(size_t)(m0+tm*4+i)*Nr + n0+tn*4+j] = alpha*acc[i][j];
}

__global__ __launch_bounds__(256) void k_bgemm_nt(const float* __restrict__ A,
    const float* __restrict__ B, float* __restrict__ C,
    int Kr, int Nr, long sA, long sB, long sC)
{
  A += (size_t)blockIdx.z * sA; B += (size_t)blockIdx.z * sB; C += (size_t)blockIdx.z * sC;
  __shared__ float As[16][64];
  __shared__ float Bs[16][64];
  const int tid = threadIdx.x;
  const int m0 = blockIdx.y*64, n0 = blockIdx.x*64;
  const int tm = tid>>4, tn = tid&15;
  const int lr = tid>>2, lk4 = (tid&3)*4;
  float acc[4][4] = {};
  for (int k0=0;k0<Kr;k0+=16){
    float4 av = *(const float4*)(A + (size_t)(m0+lr)*Kr + k0 + lk4);
    As[lk4+0][lr]=av.x; As[lk4+1][lr]=av.y; As[lk4+2][lr]=av.z; As[lk4+3][lr]=av.w;
    float4 bv = *(const float4*)(B + (size_t)(n0+lr)*Kr + k0 + lk4);
    Bs[lk4+0][lr]=bv.x; Bs[lk4+1][lr]=bv.y; Bs[lk4+2][lr]=bv.z; Bs[lk4+3][lr]=bv.w;
    __syncthreads();
#pragma unroll
    for (int kk=0;kk<16;++kk){
      float a_[4], b_[4];
#pragma unroll
      for (int i=0;i<4;++i) a_[i]=As[kk][tm*4+i];
#pragma unroll
      for (int j=0;j<4;++j) b_[j]=Bs[kk][tn*4+j];
#pragma unroll
      for (int i=0;i<4;++i)
#pragma unroll
        for (int j=0;j<4;++j) acc[i][j] += a_[i]*b_[j];
    }
    __syncthreads();
  }
#pragma unroll
  for (int i=0;i<4;++i)
#pragma unroll
    for (int j=0;j<4;++j)
      C[(size_t)(m0+tm*4+i)*Nr + n0+tn*4+j] = acc[i][j];
}

// ---------------- small elementwise ----------------
__global__ void k_softmax256(float* __restrict__ S)
{
  __shared__ float sb[4];
  float* row = S + ((size_t)blockIdx.x<<8);
  float x = row[threadIdx.x];
  float m = blockMax256(x, sb);
  float e = __expf(x-m);
  float s = blockSum256(e, sb);
  row[threadIdx.x] = e/s;
}
__global__ void k_rcsum(const float* __restrict__ A2, float* __restrict__ sums, int nb)
{
  __shared__ float sb[4];
  int b = blockIdx.x >> 8, r = blockIdx.x & 255;
  const float* Ab = A2 + ((size_t)b<<16);
  float v = (blockIdx.y==0) ? Ab[((size_t)r<<8) + threadIdx.x]
                            : Ab[((size_t)threadIdx.x<<8) + r];
  float s = blockSum256(v, sb);
  if (threadIdx.x==0) sums[(size_t)blockIdx.y*nb + blockIdx.x] = s;
}
__global__ void k_scale(const float* __restrict__ sums, float* __restrict__ scl, int nb)
{
  __shared__ float sb[4];
  float mr=-1e30f, mc=-1e30f;
  for (int i=threadIdx.x;i<nb;i+=256) mr = fmaxf(mr, sums[i]);
  for (int i=threadIdx.x;i<nb;i+=256) mc = fmaxf(mc, sums[nb+i]);
  mr = blockMax256(mr, sb);
  mc = blockMax256(mc, sb);
  if (threadIdx.x==0) scl[0] = 1.f/(mr*mc);
}
__global__ void k_z0(const float* __restrict__ A2, float* __restrict__ Z, const float* __restrict__ scl)
{
  size_t idx = (size_t)blockIdx.x*256 + threadIdx.x;
  size_t b = idx>>16; int i=(int)((idx>>8)&255), j=(int)(idx&255);
  Z[idx] = A2[(b<<16)+((size_t)j<<8)+i] * scl[0];
}
__global__ void k_diagsub(const float* __restrict__ S, float* __restrict__ T, float c)
{
  size_t idx = (size_t)blockIdx.x*256 + threadIdx.x;
  int i=(int)((idx>>8)&255), j=(int)(idx&255);
  T[idx] = ((i==j)? c : 0.f) - S[idx];
}

// ---------------- attn3 flash (landmark queries vs full K, accumulate V) ----------------
__global__ __launch_bounds__(256,1) void k_attn3(const float* __restrict__ QL,
    const float* __restrict__ K, const float* __restrict__ V,
    float* __restrict__ Pmax, float* __restrict__ Psum, float* __restrict__ Pacc)
{
  int h = blockIdx.y, cx = blockIdx.x, tid = threadIdx.x;
  __shared__ float qls[256*65];
  __shared__ float ks[32*64];
  __shared__ float vs[32*64];
  for (int i=tid;i<256*64;i+=256) qls[(i>>6)*65 + (i&63)] = QL[(size_t)h*MM*DHD + i];
  __syncthreads();
  float q[64];
#pragma unroll
  for (int d=0;d<64;++d) q[d] = qls[tid*65+d];
  float mx=-1e30f, se=0.f, acc[64];
#pragma unroll
  for (int d=0;d<64;++d) acc[d]=0.f;
  const size_t kbase = ((size_t)h*NPAD + (size_t)cx*CSZ)*DHD;
  for (int bb=0; bb<CSZ; bb+=32){
    __syncthreads();
    for (int i=tid;i<2048;i+=256){
      ks[i] = K[kbase + ((size_t)bb<<6) + i];
      vs[i] = V[kbase + ((size_t)bb<<6) + i];
    }
    __syncthreads();
    for (int jj=0;jj<32;++jj){
      const float4* kp = (const float4*)(ks + jj*64);
      float d0=0.f,d1=0.f,d2=0.f,d3=0.f;
#pragma unroll
      for (int dq=0;dq<16;++dq){
        float4 kv = kp[dq];
        d0 += q[dq*4+0]*kv.x; d1 += q[dq*4+1]*kv.y;
        d2 += q[dq*4+2]*kv.z; d3 += q[dq*4+3]*kv.w;
      }
      float dot = (d0+d1)+(d2+d3);
      if (dot > mx){
        float f = __expf(mx-dot);
        se *= f;
#pragma unroll
        for (int d=0;d<64;++d) acc[d]*=f;
        mx = dot;
      }
      float pe = __expf(dot-mx);
      se += pe;
      const float4* vp = (const float4*)(vs + jj*64);
#pragma unroll
      for (int dq=0;dq<16;++dq){
        float4 vv = vp[dq];
        acc[dq*4+0]+=pe*vv.x; acc[dq*4+1]+=pe*vv.y;
        acc[dq*4+2]+=pe*vv.z; acc[dq*4+3]+=pe*vv.w;
      }
    }
  }
  size_t pi = ((size_t)h*NCH+cx)*MM + tid;
  Pmax[pi]=mx; Psum[pi]=se;
#pragma unroll
  for (int d=0;d<64;++d) Pacc[pi*DHD+d]=acc[d];
}
__global__ void k_attn3_merge(const float* __restrict__ Pmax, const float* __restrict__ Psum,
    const float* __restrict__ Pacc, float* __restrict__ A3V)
{
  int hm = blockIdx.x; int h = hm>>8, m = hm&255; int d = threadIdx.x;
  float gm = -1e30f;
  for (int c=0;c<NCH;++c) gm = fmaxf(gm, Pmax[((size_t)h*NCH+c)*MM+m]);
  float tot=0.f, acc=0.f;
  for (int c=0;c<NCH;++c){
    size_t pi = ((size_t)h*NCH+c)*MM+m;
    float w = __expf(Pmax[pi]-gm);
    tot += Psum[pi]*w;
    acc += Pacc[pi*DHD+d]*w;
  }
  A3V[((size_t)h*MM+m)*DHD+d] = acc/tot;
}

// ---------------- attn1 fused: softmax(q @ KL^T) @ W ----------------
__global__ __launch_bounds__(256,1) void k_attn1(const float* __restrict__ Q,
    const float* __restrict__ KL, const float* __restrict__ W, float* __restrict__ OH)
{
  int h = blockIdx.y, tid = threadIdx.x;
  size_t p = (size_t)blockIdx.x*256 + tid;
  __shared__ float kls[16384];
  __shared__ float ws[16384];
  size_t hb = (size_t)h*MM*DHD;
  for (int i=tid;i<16384;i+=256){ kls[i]=KL[hb+i]; ws[i]=W[hb+i]; }
  __syncthreads();
  const float* qp = Q + ((size_t)h*NPAD + p)*DHD;
  float q[64];
#pragma unroll
  for (int d=0;d<64;d+=4){
    float4 v4 = *(const float4*)(qp+d);
    q[d]=v4.x; q[d+1]=v4.y; q[d+2]=v4.z; q[d+3]=v4.w;
  }
  float mx=-1e30f, se=0.f, acc[64];
#pragma unroll
  for (int d=0;d<64;++d) acc[d]=0.f;
  for (int j=0;j<256;++j){
    const float4* kp = (const float4*)(kls + j*64);
    float d0=0.f,d1=0.f,d2=0.f,d3=0.f;
#pragma unroll
    for (int dq=0;dq<16;++dq){
      float4 kv = kp[dq];
      d0 += q[dq*4+0]*kv.x; d1 += q[dq*4+1]*kv.y;
      d2 += q[dq*4+2]*kv.z; d3 += q[dq*4+3]*kv.w;
    }
    float dot = (d0+d1)+(d2+d3);
    if (dot > mx){
      float f = __expf(mx-dot);
      se *= f;
#pragma unroll
      for (int d=0;d<64;++d) acc[d]*=f;
      mx = dot;
    }
    float pe = __expf(dot-mx);
    se += pe;
    const float4* wp = (const float4*)(ws + j*64);
#pragma unroll
    for (int dq=0;dq<16;++dq){
      float4 wv = wp[dq];
      acc[dq*4+0]+=pe*wv.x; acc[dq*4+1]+=pe*wv.y;
      acc[dq*4+2]+=pe*wv.z; acc[dq*4+3]+=pe*wv.w;
    }
  }
  float inv = 1.f/se;
  float* op = OH + ((size_t)h*NPAD + p)*DHD;
#pragma unroll
  for (int d=0;d<64;d+=4){
    float4 v4 = make_float4(acc[d]*inv, acc[d+1]*inv, acc[d+2]*inv, acc[d+3]*inv);
    *(float4*)(op+d) = v4;
  }
}

// ---------------- depthwise conv along seq (33 taps), OH += conv(V) ----------------
__global__ void k_seqconv(const float* __restrict__ V, const float* __restrict__ resk,
                          float* __restrict__ OH)
{
  size_t idx = (size_t)blockIdx.x*256 + threadIdx.x;
  int d = (int)(idx & 63);
  size_t t = idx >> 6;
  int pp = (int)(t % NPAD);
  int h  = (int)(t / NPAD);
  const float* kr = resk + h*33;
  float s = 0.f;
#pragma unroll
  for (int r=0;r<33;++r){
    int p2 = pp - 16 + r;
    if (p2 >= 0 && p2 < NPAD) s += V[((size_t)h*NPAD+p2)*DHD + d]*kr[r];
  }
  OH[idx] += s;
}

// ---------------- wout projection + residual: X[m] += gather(OH[pad+m]) @ wout + bout ----------------
__global__ __launch_bounds__(256) void k_wout(const float* __restrict__ OH,
    const float* __restrict__ B, const float* __restrict__ bias, float* __restrict__ X)
{
  __shared__ float As[16][64];
  __shared__ float Bs[16][64];
  const int tid = threadIdx.x;
  const int m0 = blockIdx.x*64, n0 = blockIdx.y*64;
  const int tm = tid>>4, tn = tid&15;
  const int lr = tid>>2, lk4 = (tid&3)*4;
  const int lbk = tid>>4, lc4 = (tid&15)*4;
  float acc[4][4] = {};
  for (int k0=0;k0<DIM;k0+=16){
    int gm = m0+lr;
    int kc = k0 + lk4;
    int head = kc>>6, dh = kc&63;
    float4 av = (gm<N1) ? *(const float4*)(OH + ((size_t)head*NPAD + PADR + gm)*DHD + dh)
                        : make_float4(0.f,0.f,0.f,0.f);
    As[lk4+0][lr]=av.x; As[lk4+1][lr]=av.y; As[lk4+2][lr]=av.z; As[lk4+3][lr]=av.w;
    float4 bv = *(const float4*)(B + (size_t)(k0+lbk)*DIM + n0 + lc4);
    Bs[lbk][lc4+0]=bv.x; Bs[lbk][lc4+1]=bv.y; Bs[lbk][lc4+2]=bv.z; Bs[lbk][lc4+3]=bv.w;
    __syncthreads();
#pragma unroll
    for (int kk=0;kk<16;++kk){
      float a_[4], b_[4];
#pragma unroll
      for (int i=0;i<4;++i) a_[i]=As[kk][tm*4+i];
#pragma unroll
      for (int j=0;j<4;++j) b_[j]=Bs[kk][tn*4+j];
#pragma unroll
      for (int i=0;i<4;++i)
#pragma unroll
        for (int j=0;j<4;++j) acc[i][j] += a_[i]*b_[j];
    }
    __syncthreads();
  }
#pragma unroll
  for (int i=0;i<4;++i){
    int gm = m0+tm*4+i;
    if (gm<N1){
#pragma unroll
      for (int j=0;j<4;++j){
        int gn = n0+tn*4+j;
        X[(size_t)gm*DIM+gn] += acc[i][j] + bias[gn];
      }
    }
  }
}

// ---------------- leff: transposes + channel-major depthwise 7/5/3 ----------------
__global__ void k_tfwd(const float* __restrict__ X, float* __restrict__ T)
{
  __shared__ float tile[32][33];
  int tx = threadIdx.x & 31, ty = threadIdx.x >> 5;
  int s0 = blockIdx.x*32, c0 = blockIdx.y*32;
  for (int yy=0; yy<4; ++yy){
    int s = s0 + ty + yy*8;
    if (s < NTOK) tile[ty+yy*8][tx] = X[(size_t)(1+s)*DIM + c0+tx];
  }
  __syncthreads();
  for (int yy=0; yy<4; ++yy){
    int c = c0 + ty + yy*8;
    int s = s0 + tx;
    if (s < NTOK) T[(size_t)c*NTOK + s] = tile[tx][ty+yy*8];
  }
}
__global__ void k_tbwd(const float* __restrict__ T, float* __restrict__ X)
{
  __shared__ float tile[32][33];
  int tx = threadIdx.x & 31, ty = threadIdx.x >> 5;
  int s0 = blockIdx.x*32, c0 = blockIdx.y*32;
  for (int yy=0; yy<4; ++yy){
    int c = c0 + ty + yy*8, s = s0 + tx;
    if (s < NTOK) tile[ty+yy*8][tx] = T[(size_t)c*NTOK + s];
  }
  __syncthreads();
  for (int yy=0; yy<4; ++yy){
    int s = s0 + ty + yy*8, c = c0 + tx;
    if (s < NTOK) X[(size_t)(1+s)*DIM + c] = tile[tx][ty+yy*8];
  }
}
__global__ __launch_bounds__(256) void k_leff(const float* __restrict__ T,
    const float* __restrict__ k7, const float* __restrict__ b7,
    const float* __restrict__ k5, const float* __restrict__ b5,
    const float* __restrict__ k3, const float* __restrict__ b3,
    float* __restrict__ T2)
{
  __shared__ float tile[21*21];
  int c = blockIdx.y;
  int ti = blockIdx.x/10, tj = blockIdx.x%10;
  int i0 = ti*15-3, j0 = tj*15-3;
  const float* img = T + (size_t)c*NTOK;
  for (int idx=threadIdx.x; idx<441; idx+=256){
    int ii = idx/21, jj = idx%21;
    int gi = i0+ii, gj = j0+jj;
    tile[idx] = (gi>=0 && gi<HSZ && gj>=0 && gj<HSZ) ? img[gi*HSZ+gj] : 0.f;
  }
  __syncthreads();
  if (threadIdx.x < 225){
    int li = threadIdx.x/15, lj = threadIdx.x%15;
    int gi = ti*15+li, gj = tj*15+lj;
    float acc = tile[(li+3)*21 + (lj+3)] + b7[c]+b5[c]+b3[c];
    const float* w7 = k7 + c*49;
#pragma unroll
    for (int a=0;a<7;++a)
#pragma unroll
      for (int bb=0;bb<7;++bb) acc += tile[(li+a)*21 + (lj+bb)]*w7[a*7+bb];
    const float* w5 = k5 + c*25;
#pragma unroll
    for (int a=0;a<5;++a)
#pragma unroll
      for (int bb=0;bb<5;++bb) acc += tile[(li+1+a)*21 + (lj+1+bb)]*w5[a*5+bb];
    const float* w3 = k3 + c*9;
#pragma unroll
    for (int a=0;a<3;++a)
#pragma unroll
      for (int bb=0;bb<3;++bb) acc += tile[(li+2+a)*21 + (lj+2+bb)]*w3[a*3+bb];
    T2[(size_t)c*NTOK + gi*HSZ+gj] = acc;
  }
}

// ---------------- cls-row pieces ----------------
__global__ void k_row1(const float* __restrict__ Q0, const float* __restrict__ KL0,
                       float* __restrict__ row1)
{
  __shared__ float sb[4];
  __shared__ float qv[64];
  int t = threadIdx.x;
  if (t<64) qv[t] = Q0[PADR*DHD + t];
  __syncthreads();
  float l = 0.f;
#pragma unroll
  for (int d=0;d<64;++d) l += qv[d]*KL0[(size_t)t*DHD+d];
  float m = blockMax256(l, sb);
  float e = __expf(l-m);
  float s = blockSum256(e, sb);
  row1[t] = e/s;
}
__global__ void k_rz(const float* __restrict__ row1, const float* __restrict__ Z,
                     float* __restrict__ rz)
{
  __shared__ float r1[256];
  int t = threadIdx.x;
  r1[t] = row1[t];
  __syncthreads();
  float s = 0.f;
  for (int k2=0;k2<256;++k2) s += r1[k2]*Z[(size_t)k2*MM + t];
  rz[t] = s;
}
__global__ void k_rowstat(const float* __restrict__ L0, float* __restrict__ mx, float* __restrict__ se)
{
  __shared__ float sb[4];
  const float* row = L0 + (size_t)blockIdx.x*NPAD;
  float m = -1e30f;
  for (int i=threadIdx.x;i<NPAD;i+=256) m = fmaxf(m, row[i]);
  m = blockMax256(m, sb);
  float s = 0.f;
  for (int i=threadIdx.x;i<NPAD;i+=256) s += __expf(row[i]-m);
  s = blockSum256(s, sb);
  if (threadIdx.x==0){ mx[blockIdx.x]=m; se[blockIdx.x]=s; }
}
__global__ void k_aout(const float* __restrict__ L0, const float* __restrict__ rz,
    const float* __restrict__ mx, const float* __restrict__ se, float* __restrict__ out)
{
  __shared__ float wk[256], mk[256];
  int t = threadIdx.x;
  wk[t] = rz[t]/se[t];
  mk[t] = mx[t];
  __syncthreads();
  int p = blockIdx.x*256 + t;
  if (p >= NTOK) return;
  size_t pp = (size_t)(PADR+1+p);
  float a = 0.f;
  for (int k2=0;k2<256;++k2) a += wk[k2]*__expf(L0[(size_t)k2*NPAD+pp]-mk[k2]);
  out[4+p] = a;
}
__global__ void k_final(const float* __restrict__ H2r, const float* __restrict__ nw,
    const float* __restrict__ nbb, const float* __restrict__ w2, const float* __restrict__ b2,
    float* __restrict__ out)
{
  __shared__ float sb[4];
  __shared__ float hf[512];
  int t = threadIdx.x;
  float x0 = H2r[t], x1 = H2r[256+t];
  float s = blockSum256(x0+x1, sb);
  float q = blockSum256(x0*x0+x1*x1, sb);
  float mean = s*(1.f/512.f);
  float var = q*(1.f/512.f) - mean*mean;
  float rstd = rsqrtf(var+1e-5f);
  hf[t]     = (x0-mean)*rstd*nw[t]+nbb[t];
  hf[256+t] = (x1-mean)*rstd*nw[256+t]+nbb[256+t];
  __syncthreads();
  float p0 = hf[t]*w2[t*2]   + hf[256+t]*w2[(256+t)*2];
  float p1 = hf[t]*w2[t*2+1] + hf[256+t]*w2[(256+t)*2+1];
  p0 = blockSum256(p0, sb);
  p1 = blockSum256(p1, sb);
  if (t==0){
    float l0 = p0+b2[0], l1 = p1+b2[1];
    float m = fmaxf(l0,l1);
    float e0 = __expf(l0-m), e1 = __expf(l1-m), si = 1.f/(e0+e1);
    out[0]=l0; out[1]=l1; out[2]=e0*si; out[3]=e1*si;
  }
}

// ---------------- host orchestration ----------------
struct Bufs {
  float *X,*Y,*Q,*K,*V,*QL,*KL,*A2,*Z0,*Z1,*XZ,*T1,*T2,*A3V,*Wm,*sums,*scl,*Pmax,*Psum,*Pacc;
};

static float* run_pinv(const float* A2, float* Z0, float* Z1, float* XZ, float* T1, float* T2,
                       int batch, hipStream_t st)
{
  dim3 g(4,4,batch);
  int eb = batch*MM*MM/256;
  long s = (long)MM*MM;
  float* Zc = Z0; float* Zn = Z1;
  for (int it=0; it<6; ++it){
    k_bgemm_nn<<<g,256,0,st>>>(A2, Zc, XZ, MM, MM, s,s,s, 1.f);
    k_diagsub<<<eb,256,0,st>>>(XZ, T1, 7.f);
    k_bgemm_nn<<<g,256,0,st>>>(XZ, T1, T2, MM, MM, s,s,s, 1.f);
    k_diagsub<<<eb,256,0,st>>>(T2, T1, 15.f);
    k_bgemm_nn<<<g,256,0,st>>>(XZ, T1, T2, MM, MM, s,s,s, 1.f);
    k_diagsub<<<eb,256,0,st>>>(T2, T1, 13.f);
    k_bgemm_nn<<<g,256,0,st>>>(Zc, T1, Zn, MM, MM, s,s,s, 0.25f);
    float* tt=Zc; Zc=Zn; Zn=tt;
  }
  return Zc;
}

static void nystrom_layer(const Bufs& b, const float* lnw, const float* lnb,
    const float* wqkv, const float* wout, const float* bout, const float* resk, hipStream_t st)
{
  k_ln<<<N1,256,0,st>>>(b.X, b.Y, lnw, lnb);
  k_qkv<<<dim3(NPAD/64,24),256,0,st>>>(b.Y, wqkv, b.Q, b.K, b.V);
  k_landmark<<<NH*MM,64,0,st>>>(b.Q, b.QL);
  k_landmark<<<NH*MM,64,0,st>>>(b.K, b.KL);
  k_bgemm_nt<<<dim3(4,4,NH),256,0,st>>>(b.QL, b.KL, b.A2, DHD, MM,
      (long)MM*DHD,(long)MM*DHD,(long)MM*MM);
  k_softmax256<<<NH*MM,256,0,st>>>(b.A2);
  k_rcsum<<<dim3(NH*MM,2),256,0,st>>>(b.A2, b.sums, NH*MM);
  k_scale<<<1,256,0,st>>>(b.sums, b.scl, NH*MM);
  k_z0<<<NH*MM*MM/256,256,0,st>>>(b.A2, b.Z0, b.scl);
  float* Zc = run_pinv(b.A2, b.Z0, b.Z1, b.XZ, b.T1, b.T2, NH, st);
  k_attn3<<<dim3(NCH,NH),256,0,st>>>(b.QL, b.K, b.V, b.Pmax, b.Psum, b.Pacc);
  k_attn3_merge<<<NH*MM,64,0,st>>>(b.Pmax, b.Psum, b.Pacc, b.A3V);
  k_bgemm_nn<<<dim3(1,4,NH),256,0,st>>>(Zc, b.A3V, b.Wm, MM, DHD,
      (long)MM*MM,(long)MM*DHD,(long)MM*DHD, 1.f);
  k_attn1<<<dim3(NPAD/256,NH),256,0,st>>>(b.Q, b.KL, b.Wm, b.Y);  // OH = Y buffer
  k_seqconv<<<(NH*NPAD*DHD)/256,256,0,st>>>(b.V, resk, b.Y);
  k_wout<<<dim3(352,8),256,0,st>>>(b.Y, wout, bout, b.X);
}

extern "C" void kernel_launch(void* const* d_in, const int* in_sizes, int n_in,
                              void* d_out, int out_size, void* d_ws, size_t ws_size,
                              hipStream_t stream)
{
  (void)n_in; (void)out_size;
  // setup_inputs() dict order; defensive switch in case harness used signature order
  bool sig_order = (in_sizes[10] == 25088);
  int iL2 = sig_order ? 16 : 10;
  int iLf = sig_order ? 10 : 16;

  const float* h       = (const float*)d_in[0];
  const float* fc1_w   = (const float*)d_in[1];
  const float* fc1_b   = (const float*)d_in[2];
  const float* cls_tok = (const float*)d_in[3];
  const float* l1_lnw  = (const float*)d_in[4];
  const float* l1_lnb  = (const float*)d_in[5];
  const float* l1_wqkv = (const float*)d_in[6];
  const float* l1_wout = (const float*)d_in[7];
  const float* l1_bout = (const float*)d_in[8];
  const float* l1_resk = (const float*)d_in[9];
  const float* l2_lnw  = (const float*)d_in[iL2+0];
  const float* l2_lnb  = (const float*)d_in[iL2+1];
  const float* l2_wqkv = (const float*)d_in[iL2+2];
  const float* l2_wout = (const float*)d_in[iL2+3];
  const float* l2_bout = (const float*)d_in[iL2+4];
  const float* l2_resk = (const float*)d_in[iL2+5];
  const float* k7 = (const float*)d_in[iLf+0];
  const float* b7 = (const float*)d_in[iLf+1];
  const float* k5 = (const float*)d_in[iLf+2];
  const float* b5 = (const float*)d_in[iLf+3];
  const float* k3 = (const float*)d_in[iLf+4];
  const float* b3 = (const float*)d_in[iLf+5];
  const float* nw = (const float*)d_in[22];
  const float* nbb= (const float*)d_in[23];
  const float* w2 = (const float*)d_in[24];
  const float* b2 = (const float*)d_in[25];
  float* out = (float*)d_out;

  float* ws = (float*)d_ws;
  const size_t S = (size_t)NPAD*DIM;
  size_t need = 5*S + 4*(size_t)NH*MM*DHD + 6*(size_t)NH*MM*MM + 2*(size_t)NH*MM + 16
              + 2*(size_t)NH*NCH*MM + (size_t)NH*NCH*MM*DHD + 4*256 + 512;
  if (ws_size < need*sizeof(float)) return;  // fail loudly (wrong answer) instead of corrupting

  Bufs b;
  b.X = ws;      ws += S;
  b.Y = ws;      ws += S;
  b.Q = ws;      ws += S;
  b.K = ws;      ws += S;
  b.V = ws;      ws += S;
  b.QL = ws;     ws += (size_t)NH*MM*DHD;
  b.KL = ws;     ws += (size_t)NH*MM*DHD;
  b.A2 = ws;     ws += (size_t)NH*MM*MM;
  b.Z0 = ws;     ws += (size_t)NH*MM*MM;
  b.Z1 = ws;     ws += (size_t)NH*MM*MM;
  b.XZ = ws;     ws += (size_t)NH*MM*MM;
  b.T1 = ws;     ws += (size_t)NH*MM*MM;
  b.T2 = ws;     ws += (size_t)NH*MM*MM;
  b.A3V = ws;    ws += (size_t)NH*MM*DHD;
  b.Wm = ws;     ws += (size_t)NH*MM*DHD;
  b.sums = ws;   ws += 2*(size_t)NH*MM;
  b.scl = ws;    ws += 16;
  b.Pmax = ws;   ws += (size_t)NH*NCH*MM;
  b.Psum = ws;   ws += (size_t)NH*NCH*MM;
  b.Pacc = ws;   ws += (size_t)NH*NCH*MM*DHD;
  float* row1 = ws; ws += 256;
  float* rzv  = ws; ws += 256;
  float* mxv  = ws; ws += 256;
  float* sev  = ws; ws += 256;
  float* h2row= ws; ws += 512;

  // stage 0: fc1 + cls token
  k_fc1<<<dim3(352,8),256,0,stream>>>(h, fc1_w, fc1_b, b.X);
  k_setcls<<<2,256,0,stream>>>(b.X, cls_tok);

  // layer 1 + LeFF
  nystrom_layer(b, l1_lnw, l1_lnb, l1_wqkv, l1_wout, l1_bout, l1_resk, stream);
  k_tfwd<<<dim3(704,16),256,0,stream>>>(b.X, b.Q);
  k_leff<<<dim3(100,512),256,0,stream>>>(b.Q, k7,b7,k5,b5,k3,b3, b.K);
  k_tbwd<<<dim3(704,16),256,0,stream>>>(b.K, b.X);

  // layer 2 (save h2 row 0 for the head)
  nystrom_layer(b, l2_lnw, l2_lnb, l2_wqkv, l2_wout, l2_bout, l2_resk, stream);
  k_copy<<<2,256,0,stream>>>(h2row, b.X, 512);

  // layer 3 -> h3
  nystrom_layer(b, l2_lnw, l2_lnb, l2_wqkv, l2_wout, l2_bout, l2_resk, stream);

  // cls-row stage (head 0, l2 weights, LN(h3))
  k_ln<<<N1,256,0,stream>>>(b.X, b.Y, l2_lnw, l2_lnb);
  k_qk0<<<dim3(352,2),256,0,stream>>>(b.Y, l2_wqkv, b.Q, b.K);
  k_landmark<<<MM,64,0,stream>>>(b.Q, b.QL);
  k_landmark<<<MM,64,0,stream>>>(b.K, b.KL);
  k_bgemm_nt<<<dim3(4,4,1),256,0,stream>>>(b.QL, b.KL, b.A2, DHD, MM, 0,0,0);
  k_softmax256<<<MM,256,0,stream>>>(b.A2);
  k_rcsum<<<dim3(MM,2),256,0,stream>>>(b.A2, b.sums, MM);
  k_scale<<<1,256,0,stream>>>(b.sums, b.scl, MM);
  k_z0<<<MM*MM/256,256,0,stream>>>(b.A2, b.Z0, b.scl);
  float* Zc = run_pinv(b.A2, b.Z0, b.Z1, b.XZ, b.T1, b.T2, 1, stream);
  k_row1<<<1,256,0,stream>>>(b.Q, b.KL, row1);
  k_rz<<<1,256,0,stream>>>(row1, Zc, rzv);
  // L0 = QL0 @ K0^T (256 x NPAD) into V buffer
  k_bgemm_nt<<<dim3(NPAD/64,4,1),256,0,stream>>>(b.QL, b.K, b.V, DHD, NPAD, 0,0,0);
  k_rowstat<<<MM,256,0,stream>>>(b.V, mxv, sev);
  k_aout<<<88,256,0,stream>>>(b.V, rzv, mxv, sev, out);
  k_final<<<1,256,0,stream>>>(h2row, nw, nbb, w2, b2, out);
}

// Round 2
// 5346.455 us; speedup vs baseline: 1.6988x; 1.6988x over previous
//
#include <hip/hip_runtime.h>

#define NTOK 22500
#define N1   22501
#define NPAD 22528
#define PADR 27
#define DIM  512
#define NH   8
#define DHD  64
#define MM   256
#define LLM  88
#define HSZ  150
#define CSZ  256
#define NCH  88   // NPAD / CSZ

typedef short bf16x8 __attribute__((ext_vector_type(8)));
typedef float f32x4  __attribute__((ext_vector_type(4)));

__device__ __forceinline__ unsigned short f2b(float f){
  unsigned int u = __float_as_uint(f);
  unsigned int r = u + 0x7fffu + ((u>>16)&1u);
  return (unsigned short)(r>>16);
}
__device__ __forceinline__ float bf2f(unsigned short u){
  return __uint_as_float(((unsigned int)u)<<16);
}

// ---------------- reduction helpers ----------------
__device__ __forceinline__ float waveSum(float v){
#pragma unroll
  for (int o=32;o>0;o>>=1) v += __shfl_down(v,o);
  return v;
}
__device__ __forceinline__ float waveMax(float v){
#pragma unroll
  for (int o=32;o>0;o>>=1) v = fmaxf(v,__shfl_down(v,o));
  return v;
}
__device__ __forceinline__ float blockSum256(float v, float* sb){
  v = waveSum(v);
  __syncthreads();
  if ((threadIdx.x&63)==0) sb[threadIdx.x>>6]=v;
  __syncthreads();
  return sb[0]+sb[1]+sb[2]+sb[3];
}
__device__ __forceinline__ float blockMax256(float v, float* sb){
  v = waveMax(v);
  __syncthreads();
  if ((threadIdx.x&63)==0) sb[threadIdx.x>>6]=v;
  __syncthreads();
  return fmaxf(fmaxf(sb[0],sb[1]),fmaxf(sb[2],sb[3]));
}

// ---------------- weight transpose+cvt: W fp32 [K][N] -> Bt bf16 [N][K] ----------------
__global__ void k_wT(const float* __restrict__ W, unsigned short* __restrict__ Bt, int K, int N)
{
  __shared__ float tile[32][33];
  int tx = threadIdx.x&31, ty = threadIdx.x>>5;   // 256 threads: ty 0..7
  int k0 = blockIdx.x*32, n0 = blockIdx.y*32;
#pragma unroll
  for (int i=0;i<4;++i){
    int k = k0+ty+i*8;
    if (k<K && n0+tx<N) tile[ty+i*8][tx] = W[(size_t)k*N + n0+tx];
  }
  __syncthreads();
#pragma unroll
  for (int i=0;i<4;++i){
    int n = n0+ty+i*8, k = k0+tx;
    if (n<N && k<K) Bt[(size_t)n*K + k] = f2b(tile[tx][ty+i*8]);
  }
}

// ---------------- MFMA GEMM: C = A(fp32->bf16) @ Bt^T(bf16), modes ----------------
// MODE 0: fc1   A=h[22500][1024]        -> X[(1+m)*512+n] = relu(acc+bias)
// MODE 1: qkv   A=Y row r->r-PADR(0pad) -> Qb/Kb/Vb bf16 head-major (q scaled 0.125)
// MODE 2: wout  A=OH row r->r+PADR      -> X[m*512+n] += acc + bias   (m<N1)
// MODE 3: qk0   A=Y row r->r-PADR, Bt rows {0..63, 512..575} -> Q0(x0.125)/K0 fp32
template<int MODE>
__global__ __launch_bounds__(256) void k_gemm(const float* __restrict__ A,
    const unsigned short* __restrict__ Bt, const float* __restrict__ bias,
    float* __restrict__ Cf, float* __restrict__ C2,
    unsigned short* __restrict__ Q_, unsigned short* __restrict__ K_,
    unsigned short* __restrict__ V_, int Kd)
{
  __shared__ unsigned short As[128*64];
  __shared__ unsigned short Bs[128*64];
  const int tid = threadIdx.x;
  const int m0 = blockIdx.x*128, n0 = blockIdx.y*128;
  const int lane = tid & 63;
  const int wid = tid >> 6;
  const int wm = (wid>>1)*64, wn = (wid&1)*64;
  f32x4 acc[4][4] = {};
  for (int k0=0; k0<Kd; k0+=64){
    __syncthreads();
#pragma unroll
    for (int i=0;i<8;++i){
      int g = i*256 + tid;
      int row = g>>4, k4 = (g&15)*4;
      float4 v = make_float4(0.f,0.f,0.f,0.f);
      int gm = m0 + row;
      if (MODE==0){ if (gm < NTOK) v = *(const float4*)(A + (size_t)gm*Kd + k0 + k4); }
      else if (MODE==1 || MODE==3){ if (gm >= PADR) v = *(const float4*)(A + (size_t)(gm-PADR)*Kd + k0 + k4); }
      else { if (gm < N1) v = *(const float4*)(A + (size_t)(gm+PADR)*Kd + k0 + k4); }
      ushort4 h4;
      h4.x=f2b(v.x); h4.y=f2b(v.y); h4.z=f2b(v.z); h4.w=f2b(v.w);
      *(ushort4*)(&As[row*64 + (k4 ^ ((row&7)<<3))]) = h4;
    }
#pragma unroll
    for (int i=0;i<8;++i){
      int g = i*256 + tid;
      int col = g>>4, k4 = (g&15)*4;
      int vn = n0 + col;
      if (MODE==3) vn = (vn<64) ? vn : vn+448;
      ushort4 h4 = *(const ushort4*)(Bt + (size_t)vn*Kd + k0 + k4);
      *(ushort4*)(&Bs[col*64 + (k4 ^ ((col&7)<<3))]) = h4;
    }
    __syncthreads();
#pragma unroll
    for (int ks=0; ks<2; ++ks){
      const int kk = ks*32 + (lane>>4)*8;
      bf16x8 af[4], bf[4];
#pragma unroll
      for (int t=0;t<4;++t){
        int r = wm + t*16 + (lane&15);
        af[t] = *(bf16x8*)(&As[r*64 + (kk ^ ((r&7)<<3))]);
        int c = wn + t*16 + (lane&15);
        bf[t] = *(bf16x8*)(&Bs[c*64 + (kk ^ ((c&7)<<3))]);
      }
#pragma unroll
      for (int mt=0;mt<4;++mt)
#pragma unroll
        for (int nt=0;nt<4;++nt)
          acc[mt][nt] = __builtin_amdgcn_mfma_f32_16x16x32_bf16(af[mt], bf[nt], acc[mt][nt], 0,0,0);
    }
  }
  const int rbase = (lane>>4)*4;
  const int cl = lane&15;
#pragma unroll
  for (int mt=0;mt<4;++mt){
#pragma unroll
    for (int r=0;r<4;++r){
      int gm = m0 + wm + mt*16 + rbase + r;
#pragma unroll
      for (int nt=0;nt<4;++nt){
        int gn = n0 + wn + nt*16 + cl;
        float v = acc[mt][nt][r];
        if (MODE==0){
          if (gm < NTOK){ float o = v + bias[gn]; Cf[(size_t)(1+gm)*DIM + gn] = o>0.f?o:0.f; }
        } else if (MODE==1){
          int sec = gn>>9, hh=(gn>>6)&7, d=gn&63;
          unsigned short* dst = sec==0?Q_:(sec==1?K_:V_);
          dst[((size_t)hh*NPAD+gm)*DHD + d] = f2b(sec==0 ? v*0.125f : v);
        } else if (MODE==2){
          if (gm < N1) Cf[(size_t)gm*DIM + gn] += v + bias[gn];
        } else {
          if (gn < 64) Cf[(size_t)gm*DHD + gn] = v*0.125f;
          else         C2[(size_t)gm*DHD + (gn-64)] = v;
        }
      }
    }
  }
}

__global__ void k_setcls(float* __restrict__ X, const float* __restrict__ cls){
  int i = blockIdx.x*256 + threadIdx.x;
  if (i < DIM) X[i] = cls[i];
}
__global__ void k_copy(float* __restrict__ d, const float* __restrict__ s, size_t n){
  size_t i = (size_t)blockIdx.x*256 + threadIdx.x;
  if (i<n) d[i]=s[i];
}

// ---------------- layernorm over rows of 512 ----------------
__global__ void k_ln(const float* __restrict__ X, float* __restrict__ Y,
                     const float* __restrict__ w, const float* __restrict__ b)
{
  __shared__ float sb[4];
  const float* x = X + (size_t)blockIdx.x*DIM;
  float* y = Y + (size_t)blockIdx.x*DIM;
  int t = threadIdx.x;
  float a0=x[t], a1=x[t+256];
  float s = blockSum256(a0+a1, sb);
  float q = blockSum256(a0*a0+a1*a1, sb);
  float mean = s*(1.f/512.f);
  float var = q*(1.f/512.f) - mean*mean;
  float rstd = rsqrtf(var+1e-5f);
  y[t]     = (a0-mean)*rstd*w[t]+b[t];
  y[t+256] = (a1-mean)*rstd*w[t+256]+b[t+256];
}

// ---------------- landmarks ----------------
__global__ void k_landmark_b(const unsigned short* __restrict__ src, float* __restrict__ dst)
{
  int hm = blockIdx.x; int h = hm>>8, m = hm&255; int d = threadIdx.x;
  const unsigned short* base = src + ((size_t)h*NPAD + (size_t)m*LLM)*DHD + d;
  float s = 0.f;
  for (int j=0;j<LLM;++j) s += bf2f(base[(size_t)j*DHD]);
  dst[((size_t)h*MM + m)*DHD + d] = s * (1.f/(float)LLM);
}
__global__ void k_landmark(const float* __restrict__ src, float* __restrict__ dst)
{
  int hm = blockIdx.x; int h = hm>>8, m = hm&255; int d = threadIdx.x;
  const float* base = src + ((size_t)h*NPAD + (size_t)m*LLM)*DHD + d;
  float s = 0.f;
  for (int j=0;j<LLM;++j) s += base[(size_t)j*DHD];
  dst[((size_t)h*MM + m)*DHD + d] = s * (1.f/(float)LLM);
}

// ---------------- fp32 batched GEMMs (pinv & small) ----------------
__global__ __launch_bounds__(256) void k_bgemm_nn(const float* __restrict__ A,
    const float* __restrict__ B, float* __restrict__ C,
    int Kr, int Nr, long sA, long sB, long sC, float alpha)
{
  A += (size_t)blockIdx.z * sA; B += (size_t)blockIdx.z * sB; C += (size_t)blockIdx.z * sC;
  __shared__ float As[16][64];
  __shared__ float Bs[16][64];
  const int tid = threadIdx.x;
  const int m0 = blockIdx.y*64, n0 = blockIdx.x*64;
  const int tm = tid>>4, tn = tid&15;
  const int lr = tid>>2, lk4 = (tid&3)*4;
  const int lbk = tid>>4, lc4 = (tid&15)*4;
  float acc[4][4] = {};
  for (int k0=0;k0<Kr;k0+=16){
    float4 av = *(const float4*)(A + (size_t)(m0+lr)*Kr + k0 + lk4);
    As[lk4+0][lr]=av.x; As[lk4+1][lr]=av.y; As[lk4+2][lr]=av.z; As[lk4+3][lr]=av.w;
    float4 bv = *(const float4*)(B + (size_t)(k0+lbk)*Nr + n0 + lc4);
    Bs[lbk][lc4+0]=bv.x; Bs[lbk][lc4+1]=bv.y; Bs[lbk][lc4+2]=bv.z; Bs[lbk][lc4+3]=bv.w;
    __syncthreads();
#pragma unroll
    for (int kk=0;kk<16;++kk){
      float a_[4], b_[4];
#pragma unroll
      for (int i=0;i<4;++i) a_[i]=As[kk][tm*4+i];
#pragma unroll
      for (int j=0;j<4;++j) b_[j]=Bs[kk][tn*4+j];
#pragma unroll
      for (int i=0;i<4;++i)
#pragma unroll
        for (int j=0;j<4;++j) acc[i][j] += a_[i]*b_[j];
    }
    __syncthreads();
  }
#pragma unroll
  for (int i=0;i<4;++i)
#pragma unroll
    for (int j=0;j<4;++j)
      C[(size_t)(m0+tm*4+i)*Nr + n0+tn*4+j] = alpha*acc[i][j];
}

// square-256 fused: C = alpha*(c*A - A@B)
__global__ __launch_bounds__(256) void k_bgemm_diag(const float* __restrict__ A,
    const float* __restrict__ B, float* __restrict__ C,
    long sA, long sB, long sC, float c, float alpha)
{
  A += (size_t)blockIdx.z * sA; B += (size_t)blockIdx.z * sB; C += (size_t)blockIdx.z * sC;
  __shared__ float As[16][64];
  __shared__ float Bs[16][64];
  const int tid = threadIdx.x;
  const int m0 = blockIdx.y*64, n0 = blockIdx.x*64;
  const int tm = tid>>4, tn = tid&15;
  const int lr = tid>>2, lk4 = (tid&3)*4;
  const int lbk = tid>>4, lc4 = (tid&15)*4;
  float acc[4][4] = {};
  for (int k0=0;k0<MM;k0+=16){
    float4 av = *(const float4*)(A + (size_t)(m0+lr)*MM + k0 + lk4);
    As[lk4+0][lr]=av.x; As[lk4+1][lr]=av.y; As[lk4+2][lr]=av.z; As[lk4+3][lr]=av.w;
    float4 bv = *(const float4*)(B + (size_t)(k0+lbk)*MM + n0 + lc4);
    Bs[lbk][lc4+0]=bv.x; Bs[lbk][lc4+1]=bv.y; Bs[lbk][lc4+2]=bv.z; Bs[lbk][lc4+3]=bv.w;
    __syncthreads();
#pragma unroll
    for (int kk=0;kk<16;++kk){
      float a_[4], b_[4];
#pragma unroll
      for (int i=0;i<4;++i) a_[i]=As[kk][tm*4+i];
#pragma unroll
      for (int j=0;j<4;++j) b_[j]=Bs[kk][tn*4+j];
#pragma unroll
      for (int i=0;i<4;++i)
#pragma unroll
        for (int j=0;j<4;++j) acc[i][j] += a_[i]*b_[j];
    }
    __syncthreads();
  }
#pragma unroll
  for (int i=0;i<4;++i){
    int gm = m0+tm*4+i;
#pragma unroll
    for (int j=0;j<4;++j){
      int gn = n0+tn*4+j;
      C[(size_t)gm*MM + gn] = alpha*(c*A[(size_t)gm*MM+gn] - acc[i][j]);
    }
  }
}

__global__ __launch_bounds__(256) void k_bgemm_nt(const float* __restrict__ A,
    const float* __restrict__ B, float* __restrict__ C,
    int Kr, int Nr, long sA, long sB, long sC)
{
  A += (size_t)blockIdx.z * sA; B += (size_t)blockIdx.z * sB; C += (size_t)blockIdx.z * sC;
  __shared__ float As[16][64];
  __shared__ float Bs[16][64];
  const int tid = threadIdx.x;
  const int m0 = blockIdx.y*64, n0 = blockIdx.x*64;
  const int tm = tid>>4, tn = tid&15;
  const int lr = tid>>2, lk4 = (tid&3)*4;
  float acc[4][4] = {};
  for (int k0=0;k0<Kr;k0+=16){
    float4 av = *(const float4*)(A + (size_t)(m0+lr)*Kr + k0 + lk4);
    As[lk4+0][lr]=av.x; As[lk4+1][lr]=av.y; As[lk4+2][lr]=av.z; As[lk4+3][lr]=av.w;
    float4 bv = *(const float4*)(B + (size_t)(n0+lr)*Kr + k0 + lk4);
    Bs[lk4+0][lr]=bv.x; Bs[lk4+1][lr]=bv.y; Bs[lk4+2][lr]=bv.z; Bs[lk4+3][lr]=bv.w;
    __syncthreads();
#pragma unroll
    for (int kk=0;kk<16;++kk){
      float a_[4], b_[4];
#pragma unroll
      for (int i=0;i<4;++i) a_[i]=As[kk][tm*4+i];
#pragma unroll
      for (int j=0;j<4;++j) b_[j]=Bs[kk][tn*4+j];
#pragma unroll
      for (int i=0;i<4;++i)
#pragma unroll
        for (int j=0;j<4;++j) acc[i][j] += a_[i]*b_[j];
    }
    __syncthreads();
  }
#pragma unroll
  for (int i=0;i<4;++i)
#pragma unroll
    for (int j=0;j<4;++j)
      C[(size_t)(m0+tm*4+i)*Nr + n0+tn*4+j] = acc[i][j];
}

// ---------------- small elementwise ----------------
__global__ void k_softmax256(float* __restrict__ S)
{
  __shared__ float sb[4];
  float* row = S + ((size_t)blockIdx.x<<8);
  float x = row[threadIdx.x];
  float m = blockMax256(x, sb);
  float e = __expf(x-m);
  float s = blockSum256(e, sb);
  row[threadIdx.x] = e/s;
}
__global__ void k_rcsum(const float* __restrict__ A2, float* __restrict__ sums, int nb)
{
  __shared__ float sb[4];
  int b = blockIdx.x >> 8, r = blockIdx.x & 255;
  const float* Ab = A2 + ((size_t)b<<16);
  float v = (blockIdx.y==0) ? Ab[((size_t)r<<8) + threadIdx.x]
                            : Ab[((size_t)threadIdx.x<<8) + r];
  float s = blockSum256(v, sb);
  if (threadIdx.x==0) sums[(size_t)blockIdx.y*nb + blockIdx.x] = s;
}
__global__ void k_scale(const float* __restrict__ sums, float* __restrict__ scl, int nb)
{
  __shared__ float sb[4];
  float mr=-1e30f, mc=-1e30f;
  for (int i=threadIdx.x;i<nb;i+=256) mr = fmaxf(mr, sums[i]);
  for (int i=threadIdx.x;i<nb;i+=256) mc = fmaxf(mc, sums[nb+i]);
  mr = blockMax256(mr, sb);
  mc = blockMax256(mc, sb);
  if (threadIdx.x==0) scl[0] = 1.f/(mr*mc);
}
__global__ void k_z0(const float* __restrict__ A2, float* __restrict__ Z, const float* __restrict__ scl)
{
  size_t idx = (size_t)blockIdx.x*256 + threadIdx.x;
  size_t b = idx>>16; int i=(int)((idx>>8)&255), j=(int)(idx&255);
  Z[idx] = A2[(b<<16)+((size_t)j<<8)+i] * scl[0];
}

// ---------------- attn3 flash ----------------
__global__ __launch_bounds__(256) void k_attn3(const float* __restrict__ QL,
    const unsigned short* __restrict__ Kb, const unsigned short* __restrict__ Vb,
    float* __restrict__ Pmax, float* __restrict__ Psum, float* __restrict__ Pacc)
{
  int h = blockIdx.y, cx = blockIdx.x, tid = threadIdx.x;
  __shared__ float ks[2048];
  __shared__ float vs[2048];
  float q[64];
  const float* qp = QL + ((size_t)h*MM + tid)*DHD;
#pragma unroll
  for (int d=0;d<64;d+=4){
    float4 v4 = *(const float4*)(qp+d);
    q[d]=v4.x; q[d+1]=v4.y; q[d+2]=v4.z; q[d+3]=v4.w;
  }
  float mx=-1e30f, se=0.f, acc[64];
#pragma unroll
  for (int d=0;d<64;++d) acc[d]=0.f;
  const size_t kbase = ((size_t)h*NPAD + (size_t)cx*CSZ)*DHD;
  for (int bb=0; bb<CSZ; bb+=32){
    __syncthreads();
    for (int i=tid;i<1024;i+=256){
      ushort2 ku = *(const ushort2*)(Kb + kbase + ((size_t)bb<<6) + 2*i);
      ushort2 vu = *(const ushort2*)(Vb + kbase + ((size_t)bb<<6) + 2*i);
      ks[2*i]=bf2f(ku.x); ks[2*i+1]=bf2f(ku.y);
      vs[2*i]=bf2f(vu.x); vs[2*i+1]=bf2f(vu.y);
    }
    __syncthreads();
    for (int jj=0;jj<32;++jj){
      const float4* kp = (const float4*)(ks + jj*64);
      float d0=0.f,d1=0.f,d2=0.f,d3=0.f;
#pragma unroll
      for (int dq=0;dq<16;++dq){
        float4 kv = kp[dq];
        d0 += q[dq*4+0]*kv.x; d1 += q[dq*4+1]*kv.y;
        d2 += q[dq*4+2]*kv.z; d3 += q[dq*4+3]*kv.w;
      }
      float dot = (d0+d1)+(d2+d3);
      if (dot > mx){
        float f = __expf(mx-dot);
        se *= f;
#pragma unroll
        for (int d=0;d<64;++d) acc[d]*=f;
        mx = dot;
      }
      float pe = __expf(dot-mx);
      se += pe;
      const float4* vp = (const float4*)(vs + jj*64);
#pragma unroll
      for (int dq=0;dq<16;++dq){
        float4 vv = vp[dq];
        acc[dq*4+0]+=pe*vv.x; acc[dq*4+1]+=pe*vv.y;
        acc[dq*4+2]+=pe*vv.z; acc[dq*4+3]+=pe*vv.w;
      }
    }
  }
  size_t pi = ((size_t)h*NCH+cx)*MM + tid;
  Pmax[pi]=mx; Psum[pi]=se;
#pragma unroll
  for (int d=0;d<64;++d) Pacc[pi*DHD+d]=acc[d];
}
__global__ void k_attn3_merge(const float* __restrict__ Pmax, const float* __restrict__ Psum,
    const float* __restrict__ Pacc, float* __restrict__ A3V)
{
  int hm = blockIdx.x; int h = hm>>8, m = hm&255; int d = threadIdx.x;
  float gm = -1e30f;
  for (int c=0;c<NCH;++c) gm = fmaxf(gm, Pmax[((size_t)h*NCH+c)*MM+m]);
  float tot=0.f, acc=0.f;
  for (int c=0;c<NCH;++c){
    size_t pi = ((size_t)h*NCH+c)*MM+m;
    float w = __expf(Pmax[pi]-gm);
    tot += Psum[pi]*w;
    acc += Pacc[pi*DHD+d]*w;
  }
  A3V[((size_t)h*MM+m)*DHD+d] = acc/tot;
}

// ---------------- attn1 fused, chunked staging ----------------
__global__ __launch_bounds__(256) void k_attn1(const unsigned short* __restrict__ Qb,
    const float* __restrict__ KL, const float* __restrict__ W, float* __restrict__ OH)
{
  int h = blockIdx.y, tid = threadIdx.x;
  size_t p = (size_t)blockIdx.x*256 + tid;
  __shared__ float kls[2048];
  __shared__ float wls[2048];
  const unsigned short* qp = Qb + ((size_t)h*NPAD + p)*DHD;
  float q[64];
#pragma unroll
  for (int d=0;d<64;d+=4){
    ushort4 u = *(const ushort4*)(qp+d);
    q[d]=bf2f(u.x); q[d+1]=bf2f(u.y); q[d+2]=bf2f(u.z); q[d+3]=bf2f(u.w);
  }
  float mx=-1e30f, se=0.f, acc[64];
#pragma unroll
  for (int d=0;d<64;++d) acc[d]=0.f;
  size_t hb = (size_t)h*MM*DHD;
  for (int j0=0;j0<256;j0+=32){
    __syncthreads();
    for (int i=tid;i<2048;i+=256){
      kls[i]=KL[hb+((size_t)j0<<6)+i];
      wls[i]=W[hb+((size_t)j0<<6)+i];
    }
    __syncthreads();
    for (int jj=0;jj<32;++jj){
      const float4* kp = (const float4*)(kls + jj*64);
      float d0=0.f,d1=0.f,d2=0.f,d3=0.f;
#pragma unroll
      for (int dq=0;dq<16;++dq){
        float4 kv = kp[dq];
        d0 += q[dq*4+0]*kv.x; d1 += q[dq*4+1]*kv.y;
        d2 += q[dq*4+2]*kv.z; d3 += q[dq*4+3]*kv.w;
      }
      float dot = (d0+d1)+(d2+d3);
      if (dot > mx){
        float f = __expf(mx-dot);
        se *= f;
#pragma unroll
        for (int d=0;d<64;++d) acc[d]*=f;
        mx = dot;
      }
      float pe = __expf(dot-mx);
      se += pe;
      const float4* wp = (const float4*)(wls + jj*64);
#pragma unroll
      for (int dq=0;dq<16;++dq){
        float4 wv = wp[dq];
        acc[dq*4+0]+=pe*wv.x; acc[dq*4+1]+=pe*wv.y;
        acc[dq*4+2]+=pe*wv.z; acc[dq*4+3]+=pe*wv.w;
      }
    }
  }
  float inv = 1.f/se;
  float* op = OH + p*DIM + (size_t)h*DHD;   // token-major
#pragma unroll
  for (int d=0;d<64;d+=4){
    float4 v4 = make_float4(acc[d]*inv, acc[d+1]*inv, acc[d+2]*inv, acc[d+3]*inv);
    *(float4*)(op+d) = v4;
  }
}

// ---------------- depthwise conv along seq (33 taps), token-major OH += conv(V) ----------------
__global__ void k_seqconv(const unsigned short* __restrict__ Vb, const float* __restrict__ resk,
                          float* __restrict__ OH)
{
  size_t idx = (size_t)blockIdx.x*256 + threadIdx.x;
  int c = (int)(idx & 511);
  size_t p = idx >> 9;
  int h = c>>6, d = c&63;
  const float* kr = resk + h*33;
  float s = 0.f;
#pragma unroll
  for (int r=0;r<33;++r){
    long p2 = (long)p - 16 + r;
    if (p2 >= 0 && p2 < NPAD) s += bf2f(Vb[((size_t)h*NPAD+p2)*DHD + d])*kr[r];
  }
  OH[idx] += s;
}

// ---------------- leff ----------------
__global__ void k_tfwd(const float* __restrict__ X, float* __restrict__ T)
{
  __shared__ float tile[32][33];
  int tx = threadIdx.x & 31, ty = threadIdx.x >> 5;
  int s0 = blockIdx.x*32, c0 = blockIdx.y*32;
  for (int yy=0; yy<4; ++yy){
    int s = s0 + ty + yy*8;
    if (s < NTOK) tile[ty+yy*8][tx] = X[(size_t)(1+s)*DIM + c0+tx];
  }
  __syncthreads();
  for (int yy=0; yy<4; ++yy){
    int c = c0 + ty + yy*8;
    int s = s0 + tx;
    if (s < NTOK) T[(size_t)c*NTOK + s] = tile[tx][ty+yy*8];
  }
}
__global__ void k_tbwd(const float* __restrict__ T, float* __restrict__ X)
{
  __shared__ float tile[32][33];
  int tx = threadIdx.x & 31, ty = threadIdx.x >> 5;
  int s0 = blockIdx.x*32, c0 = blockIdx.y*32;
  for (int yy=0; yy<4; ++yy){
    int c = c0 + ty + yy*8, s = s0 + tx;
    if (s < NTOK) tile[ty+yy*8][tx] = T[(size_t)c*NTOK + s];
  }
  __syncthreads();
  for (int yy=0; yy<4; ++yy){
    int s = s0 + ty + yy*8, c = c0 + tx;
    if (s < NTOK) X[(size_t)(1+s)*DIM + c] = tile[tx][ty+yy*8];
  }
}
__global__ __launch_bounds__(256) void k_leff(const float* __restrict__ T,
    const float* __restrict__ k7, const float* __restrict__ b7,
    const float* __restrict__ k5, const float* __restrict__ b5,
    const float* __restrict__ k3, const float* __restrict__ b3,
    float* __restrict__ T2)
{
  __shared__ float tile[21*21];
  int c = blockIdx.y;
  int ti = blockIdx.x/10, tj = blockIdx.x%10;
  int i0 = ti*15-3, j0 = tj*15-3;
  const float* img = T + (size_t)c*NTOK;
  for (int idx=threadIdx.x; idx<441; idx+=256){
    int ii = idx/21, jj = idx%21;
    int gi = i0+ii, gj = j0+jj;
    tile[idx] = (gi>=0 && gi<HSZ && gj>=0 && gj<HSZ) ? img[gi*HSZ+gj] : 0.f;
  }
  __syncthreads();
  if (threadIdx.x < 225){
    int li = threadIdx.x/15, lj = threadIdx.x%15;
    int gi = ti*15+li, gj = tj*15+lj;
    float acc = tile[(li+3)*21 + (lj+3)] + b7[c]+b5[c]+b3[c];
    const float* w7 = k7 + c*49;
#pragma unroll
    for (int a=0;a<7;++a)
#pragma unroll
      for (int bb=0;bb<7;++bb) acc += tile[(li+a)*21 + (lj+bb)]*w7[a*7+bb];
    const float* w5 = k5 + c*25;
#pragma unroll
    for (int a=0;a<5;++a)
#pragma unroll
      for (int bb=0;bb<5;++bb) acc += tile[(li+1+a)*21 + (lj+1+bb)]*w5[a*5+bb];
    const float* w3 = k3 + c*9;
#pragma unroll
    for (int a=0;a<3;++a)
#pragma unroll
      for (int bb=0;bb<3;++bb) acc += tile[(li+2+a)*21 + (lj+2+bb)]*w3[a*3+bb];
    T2[(size_t)c*NTOK + gi*HSZ+gj] = acc;
  }
}

// ---------------- cls-row pieces ----------------
__global__ void k_row1(const float* __restrict__ Q0, const float* __restrict__ KL0,
                       float* __restrict__ row1)
{
  __shared__ float sb[4];
  __shared__ float qv[64];
  int t = threadIdx.x;
  if (t<64) qv[t] = Q0[PADR*DHD + t];
  __syncthreads();
  float l = 0.f;
#pragma unroll
  for (int d=0;d<64;++d) l += qv[d]*KL0[(size_t)t*DHD+d];
  float m = blockMax256(l, sb);
  float e = __expf(l-m);
  float s = blockSum256(e, sb);
  row1[t] = e/s;
}
__global__ void k_rz(const float* __restrict__ row1, const float* __restrict__ Z,
                     float* __restrict__ rz)
{
  __shared__ float r1[256];
  int t = threadIdx.x;
  r1[t] = row1[t];
  __syncthreads();
  float s = 0.f;
  for (int k2=0;k2<256;++k2) s += r1[k2]*Z[(size_t)k2*MM + t];
  rz[t] = s;
}
__global__ void k_rowstat(const float* __restrict__ L0, float* __restrict__ mx, float* __restrict__ se)
{
  __shared__ float sb[4];
  const float* row = L0 + (size_t)blockIdx.x*NPAD;
  float m = -1e30f;
  for (int i=threadIdx.x;i<NPAD;i+=256) m = fmaxf(m, row[i]);
  m = blockMax256(m, sb);
  float s = 0.f;
  for (int i=threadIdx.x;i<NPAD;i+=256) s += __expf(row[i]-m);
  s = blockSum256(s, sb);
  if (threadIdx.x==0){ mx[blockIdx.x]=m; se[blockIdx.x]=s; }
}
__global__ void k_aout(const float* __restrict__ L0, const float* __restrict__ rz,
    const float* __restrict__ mx, const float* __restrict__ se, float* __restrict__ out)
{
  __shared__ float wk[256], mk[256];
  int t = threadIdx.x;
  wk[t] = rz[t]/se[t];
  mk[t] = mx[t];
  __syncthreads();
  int p = blockIdx.x*256 + t;
  if (p >= NTOK) return;
  size_t pp = (size_t)(PADR+1+p);
  float a = 0.f;
  for (int k2=0;k2<256;++k2) a += wk[k2]*__expf(L0[(size_t)k2*NPAD+pp]-mk[k2]);
  out[4+p] = a;
}
__global__ void k_final(const float* __restrict__ H2r, const float* __restrict__ nw,
    const float* __restrict__ nbb, const float* __restrict__ w2, const float* __restrict__ b2,
    float* __restrict__ out)
{
  __shared__ float sb[4];
  __shared__ float hf[512];
  int t = threadIdx.x;
  float x0 = H2r[t], x1 = H2r[256+t];
  float s = blockSum256(x0+x1, sb);
  float q = blockSum256(x0*x0+x1*x1, sb);
  float mean = s*(1.f/512.f);
  float var = q*(1.f/512.f) - mean*mean;
  float rstd = rsqrtf(var+1e-5f);
  hf[t]     = (x0-mean)*rstd*nw[t]+nbb[t];
  hf[256+t] = (x1-mean)*rstd*nw[256+t]+nbb[256+t];
  __syncthreads();
  float p0 = hf[t]*w2[t*2]   + hf[256+t]*w2[(256+t)*2];
  float p1 = hf[t]*w2[t*2+1] + hf[256+t]*w2[(256+t)*2+1];
  p0 = blockSum256(p0, sb);
  p1 = blockSum256(p1, sb);
  if (t==0){
    float l0 = p0+b2[0], l1 = p1+b2[1];
    float m = fmaxf(l0,l1);
    float e0 = __expf(l0-m), e1 = __expf(l1-m), si = 1.f/(e0+e1);
    out[0]=l0; out[1]=l1; out[2]=e0*si; out[3]=e1*si;
  }
}

// ---------------- host orchestration ----------------
struct Bufs {
  float *X,*Y,*QL,*KL,*A2,*Z0,*Z1,*XZ,*T1,*T2,*A3V,*Wm,*sums,*scl,*Pmax,*Psum,*Pacc;
  unsigned short *Qb,*Kb,*Vb;
};

static float* run_pinv(const float* A2, float* Z0, float* Z1, float* XZ, float* T1, float* T2,
                       int batch, hipStream_t st)
{
  dim3 g(4,4,batch);
  long s = (long)MM*MM;
  float* Zc = Z0; float* Zn = Z1;
  for (int it=0; it<6; ++it){
    k_bgemm_nn<<<g,256,0,st>>>(A2, Zc, XZ, MM, MM, s,s,s, 1.f);
    k_bgemm_diag<<<g,256,0,st>>>(XZ, XZ, T1, s,s,s, 7.f, 1.f);
    k_bgemm_diag<<<g,256,0,st>>>(XZ, T1, T2, s,s,s, 15.f, 1.f);
    k_bgemm_diag<<<g,256,0,st>>>(Zc, T2, Zn, s,s,s, 13.f, 0.25f);
    float* tt=Zc; Zc=Zn; Zn=tt;
  }
  return Zc;
}

static void nystrom_layer(const Bufs& b, const float* lnw, const float* lnb,
    const unsigned short* wqkvT, const unsigned short* woutT,
    const float* bout, const float* resk, hipStream_t st)
{
  k_ln<<<N1,256,0,st>>>(b.X, b.Y, lnw, lnb);
  k_gemm<1><<<dim3(NPAD/128,12),256,0,st>>>(b.Y, wqkvT, nullptr, nullptr, nullptr,
      b.Qb, b.Kb, b.Vb, DIM);
  k_landmark_b<<<NH*MM,64,0,st>>>(b.Qb, b.QL);
  k_landmark_b<<<NH*MM,64,0,st>>>(b.Kb, b.KL);
  k_bgemm_nt<<<dim3(4,4,NH),256,0,st>>>(b.QL, b.KL, b.A2, DHD, MM,
      (long)MM*DHD,(long)MM*DHD,(long)MM*MM);
  k_softmax256<<<NH*MM,256,0,st>>>(b.A2);
  k_rcsum<<<dim3(NH*MM,2),256,0,st>>>(b.A2, b.sums, NH*MM);
  k_scale<<<1,256,0,st>>>(b.sums, b.scl, NH*MM);
  k_z0<<<NH*MM*MM/256,256,0,st>>>(b.A2, b.Z0, b.scl);
  float* Zc = run_pinv(b.A2, b.Z0, b.Z1, b.XZ, b.T1, b.T2, NH, st);
  k_attn3<<<dim3(NCH,NH),256,0,st>>>(b.QL, b.Kb, b.Vb, b.Pmax, b.Psum, b.Pacc);
  k_attn3_merge<<<NH*MM,64,0,st>>>(b.Pmax, b.Psum, b.Pacc, b.A3V);
  k_bgemm_nn<<<dim3(1,4,NH),256,0,st>>>(Zc, b.A3V, b.Wm, MM, DHD,
      (long)MM*MM,(long)MM*DHD,(long)MM*DHD, 1.f);
  k_attn1<<<dim3(NPAD/256,NH),256,0,st>>>(b.Qb, b.KL, b.Wm, b.Y);  // OH = Y, token-major
  k_seqconv<<<(NPAD*DIM)/256,256,0,st>>>(b.Vb, resk, b.Y);
  k_gemm<2><<<dim3(176,4),256,0,st>>>(b.Y, woutT, bout, b.X, nullptr,
      nullptr, nullptr, nullptr, DIM);
}

extern "C" void kernel_launch(void* const* d_in, const int* in_sizes, int n_in,
                              void* d_out, int out_size, void* d_ws, size_t ws_size,
                              hipStream_t stream)
{
  (void)n_in; (void)out_size;
  bool sig_order = (in_sizes[10] == 25088);
  int iL2 = sig_order ? 16 : 10;
  int iLf = sig_order ? 10 : 16;

  const float* h       = (const float*)d_in[0];
  const float* fc1_w   = (const float*)d_in[1];
  const float* fc1_b   = (const float*)d_in[2];
  const float* cls_tok = (const float*)d_in[3];
  const float* l1_lnw  = (const float*)d_in[4];
  const float* l1_lnb  = (const float*)d_in[5];
  const float* l1_wqkv = (const float*)d_in[6];
  const float* l1_wout = (const float*)d_in[7];
  const float* l1_bout = (const float*)d_in[8];
  const float* l1_resk = (const float*)d_in[9];
  const float* l2_lnw  = (const float*)d_in[iL2+0];
  const float* l2_lnb  = (const float*)d_in[iL2+1];
  const float* l2_wqkv = (const float*)d_in[iL2+2];
  const float* l2_wout = (const float*)d_in[iL2+3];
  const float* l2_bout = (const float*)d_in[iL2+4];
  const float* l2_resk = (const float*)d_in[iL2+5];
  const float* k7 = (const float*)d_in[iLf+0];
  const float* b7 = (const float*)d_in[iLf+1];
  const float* k5 = (const float*)d_in[iLf+2];
  const float* b5 = (const float*)d_in[iLf+3];
  const float* k3 = (const float*)d_in[iLf+4];
  const float* b3 = (const float*)d_in[iLf+5];
  const float* nw = (const float*)d_in[22];
  const float* nbb= (const float*)d_in[23];
  const float* w2 = (const float*)d_in[24];
  const float* b2 = (const float*)d_in[25];
  float* out = (float*)d_out;

  char* base = (char*)d_ws;
  auto allocF = [&](size_t n)->float*{
    float* p=(float*)base; base += ((n*sizeof(float)+255)&~(size_t)255); return p; };
  auto allocU = [&](size_t n)->unsigned short*{
    unsigned short* p=(unsigned short*)base; base += ((n*sizeof(unsigned short)+255)&~(size_t)255); return p; };

  const size_t S = (size_t)NPAD*DIM;
  Bufs b;
  b.X  = allocF(S);
  b.Y  = allocF(S);
  b.Qb = allocU(S);
  b.Kb = allocU(S);
  b.Vb = allocU(S);
  b.QL = allocF((size_t)NH*MM*DHD);
  b.KL = allocF((size_t)NH*MM*DHD);
  b.A2 = allocF((size_t)NH*MM*MM);
  b.Z0 = allocF((size_t)NH*MM*MM);
  b.Z1 = allocF((size_t)NH*MM*MM);
  b.XZ = allocF((size_t)NH*MM*MM);
  b.T1 = allocF((size_t)NH*MM*MM);
  b.T2 = allocF((size_t)NH*MM*MM);
  b.A3V= allocF((size_t)NH*MM*DHD);
  b.Wm = allocF((size_t)NH*MM*DHD);
  b.sums=allocF(2*(size_t)NH*MM);
  b.scl= allocF(16);
  b.Pmax=allocF((size_t)NH*NCH*MM);
  b.Psum=allocF((size_t)NH*NCH*MM);
  b.Pacc=allocF((size_t)NH*NCH*MM*DHD);
  unsigned short* fc1T   = allocU((size_t)DIM*1024);
  unsigned short* wqkvT1 = allocU((size_t)1536*DIM);
  unsigned short* wqkvT2 = allocU((size_t)1536*DIM);
  unsigned short* woutT1 = allocU((size_t)DIM*DIM);
  unsigned short* woutT2 = allocU((size_t)DIM*DIM);
  float* Q0   = allocF((size_t)NPAD*DHD);
  float* K0   = allocF((size_t)NPAD*DHD);
  float* row1 = allocF(256);
  float* rzv  = allocF(256);
  float* mxv  = allocF(256);
  float* sev  = allocF(256);
  float* h2row= allocF(512);
  if ((size_t)(base - (char*)d_ws) > ws_size) return;  // insufficient scratch

  // weight transposes (fp32 -> bf16 [N][K])
  k_wT<<<dim3(32,16),256,0,stream>>>(fc1_w, fc1T, 1024, DIM);
  k_wT<<<dim3(16,48),256,0,stream>>>(l1_wqkv, wqkvT1, DIM, 1536);
  k_wT<<<dim3(16,48),256,0,stream>>>(l2_wqkv, wqkvT2, DIM, 1536);
  k_wT<<<dim3(16,16),256,0,stream>>>(l1_wout, woutT1, DIM, DIM);
  k_wT<<<dim3(16,16),256,0,stream>>>(l2_wout, woutT2, DIM, DIM);

  // stage 0: fc1 + cls token
  k_gemm<0><<<dim3(176,4),256,0,stream>>>(h, fc1T, fc1_b, b.X, nullptr,
      nullptr, nullptr, nullptr, 1024);
  k_setcls<<<2,256,0,stream>>>(b.X, cls_tok);

  // layer 1 + LeFF
  nystrom_layer(b, l1_lnw, l1_lnb, wqkvT1, woutT1, l1_bout, l1_resk, stream);
  k_tfwd<<<dim3(704,16),256,0,stream>>>(b.X, b.Y);
  k_leff<<<dim3(100,512),256,0,stream>>>(b.Y, k7,b7,k5,b5,k3,b3, b.Pacc);
  k_tbwd<<<dim3(704,16),256,0,stream>>>(b.Pacc, b.X);

  // layer 2 (save h2 row 0 for the head)
  nystrom_layer(b, l2_lnw, l2_lnb, wqkvT2, woutT2, l2_bout, l2_resk, stream);
  k_copy<<<2,256,0,stream>>>(h2row, b.X, 512);

  // layer 3 -> h3
  nystrom_layer(b, l2_lnw, l2_lnb, wqkvT2, woutT2, l2_bout, l2_resk, stream);

  // cls-row stage (head 0, l2 weights, LN(h3))
  k_ln<<<N1,256,0,stream>>>(b.X, b.Y, l2_lnw, l2_lnb);
  k_gemm<3><<<dim3(176,1),256,0,stream>>>(b.Y, wqkvT2, nullptr, Q0, K0,
      nullptr, nullptr, nullptr, DIM);
  k_landmark<<<MM,64,0,stream>>>(Q0, b.QL);
  k_landmark<<<MM,64,0,stream>>>(K0, b.KL);
  k_bgemm_nt<<<dim3(4,4,1),256,0,stream>>>(b.QL, b.KL, b.A2, DHD, MM, 0,0,0);
  k_softmax256<<<MM,256,0,stream>>>(b.A2);
  k_rcsum<<<dim3(MM,2),256,0,stream>>>(b.A2, b.sums, MM);
  k_scale<<<1,256,0,stream>>>(b.sums, b.scl, MM);
  k_z0<<<MM*MM/256,256,0,stream>>>(b.A2, b.Z0, b.scl);
  float* Zc = run_pinv(b.A2, b.Z0, b.Z1, b.XZ, b.T1, b.T2, 1, stream);
  k_row1<<<1,256,0,stream>>>(Q0, b.KL, row1);
  k_rz<<<1,256,0,stream>>>(row1, Zc, rzv);
  // L0 = QL0 @ K0^T (256 x NPAD), into Y
  k_bgemm_nt<<<dim3(NPAD/64,4,1),256,0,stream>>>(b.QL, K0, b.Y, DHD, NPAD, 0,0,0);
  k_rowstat<<<MM,256,0,stream>>>(b.Y, mxv, sev);
  k_aout<<<88,256,0,stream>>>(b.Y, rzv, mxv, sev, out);
  k_final<<<1,256,0,stream>>>(h2row, nw, nbb, w2, b2, out);
}

// Round 3
// 3510.939 us; speedup vs baseline: 2.5870x; 1.5228x over previous
//
#include <hip/hip_runtime.h>

#define NTOK 22500
#define N1   22501
#define NPAD 22528
#define PADR 27
#define DIM  512
#define NH   8
#define DHD  64
#define MM   256
#define LLM  88
#define HSZ  150
#define CSZ  256
#define NCH  88   // NPAD / CSZ

typedef short bf16x8 __attribute__((ext_vector_type(8)));
typedef float f32x4  __attribute__((ext_vector_type(4)));

union U8 { bf16x8 v; unsigned short u[8]; };

__device__ __forceinline__ unsigned short f2b(float f){
  unsigned int u = __float_as_uint(f);
  unsigned int r = u + 0x7fffu + ((u>>16)&1u);
  return (unsigned short)(r>>16);
}
__device__ __forceinline__ float bf2f(unsigned short u){
  return __uint_as_float(((unsigned int)u)<<16);
}
__device__ __forceinline__ bf16x8 cvt8(float4 a, float4 b){
  U8 u;
  u.u[0]=f2b(a.x); u.u[1]=f2b(a.y); u.u[2]=f2b(a.z); u.u[3]=f2b(a.w);
  u.u[4]=f2b(b.x); u.u[5]=f2b(b.y); u.u[6]=f2b(b.z); u.u[7]=f2b(b.w);
  return u.v;
}

// ---------------- reduction helpers ----------------
__device__ __forceinline__ float waveSum(float v){
#pragma unroll
  for (int o=32;o>0;o>>=1) v += __shfl_down(v,o);
  return v;
}
__device__ __forceinline__ float waveMax(float v){
#pragma unroll
  for (int o=32;o>0;o>>=1) v = fmaxf(v,__shfl_down(v,o));
  return v;
}
__device__ __forceinline__ float blockSum256(float v, float* sb){
  v = waveSum(v);
  __syncthreads();
  if ((threadIdx.x&63)==0) sb[threadIdx.x>>6]=v;
  __syncthreads();
  return sb[0]+sb[1]+sb[2]+sb[3];
}
__device__ __forceinline__ float blockMax256(float v, float* sb){
  v = waveMax(v);
  __syncthreads();
  if ((threadIdx.x&63)==0) sb[threadIdx.x>>6]=v;
  __syncthreads();
  return fmaxf(fmaxf(sb[0],sb[1]),fmaxf(sb[2],sb[3]));
}

// ---------------- weight transpose+cvt: W fp32 [K][N] -> Bt bf16 [N][K] ----------------
__global__ void k_wT(const float* __restrict__ W, unsigned short* __restrict__ Bt, int K, int N)
{
  __shared__ float tile[32][33];
  int tx = threadIdx.x&31, ty = threadIdx.x>>5;
  int k0 = blockIdx.x*32, n0 = blockIdx.y*32;
#pragma unroll
  for (int i=0;i<4;++i){
    int k = k0+ty+i*8;
    if (k<K && n0+tx<N) tile[ty+i*8][tx] = W[(size_t)k*N + n0+tx];
  }
  __syncthreads();
#pragma unroll
  for (int i=0;i<4;++i){
    int n = n0+ty+i*8, k = k0+tx;
    if (n<N && k<K) Bt[(size_t)n*K + k] = f2b(tile[tx][ty+i*8]);
  }
}

// ---------------- MFMA GEMM (128x128 tile): C = A(fp32->bf16) @ Bt^T(bf16) ----------------
// MODE 0: fc1   MODE 1: qkv (also writes Vt)   MODE 2: wout(+=)   MODE 3: qk0
template<int MODE>
__global__ __launch_bounds__(256) void k_gemm(const float* __restrict__ A,
    const unsigned short* __restrict__ Bt, const float* __restrict__ bias,
    float* __restrict__ Cf, float* __restrict__ C2,
    unsigned short* __restrict__ Q_, unsigned short* __restrict__ K_,
    unsigned short* __restrict__ V_, unsigned short* __restrict__ Vt_, int Kd)
{
  __shared__ unsigned short As[128*64];
  __shared__ unsigned short Bs[128*64];
  const int tid = threadIdx.x;
  const int m0 = blockIdx.x*128, n0 = blockIdx.y*128;
  const int lane = tid & 63;
  const int wid = tid >> 6;
  const int wm = (wid>>1)*64, wn = (wid&1)*64;
  f32x4 acc[4][4] = {};
  for (int k0=0; k0<Kd; k0+=64){
    __syncthreads();
#pragma unroll
    for (int i=0;i<8;++i){
      int g = i*256 + tid;
      int row = g>>4, k4 = (g&15)*4;
      float4 v = make_float4(0.f,0.f,0.f,0.f);
      int gm = m0 + row;
      if (MODE==0){ if (gm < NTOK) v = *(const float4*)(A + (size_t)gm*Kd + k0 + k4); }
      else if (MODE==1 || MODE==3){ if (gm >= PADR) v = *(const float4*)(A + (size_t)(gm-PADR)*Kd + k0 + k4); }
      else { if (gm < N1) v = *(const float4*)(A + (size_t)(gm+PADR)*Kd + k0 + k4); }
      ushort4 h4;
      h4.x=f2b(v.x); h4.y=f2b(v.y); h4.z=f2b(v.z); h4.w=f2b(v.w);
      *(ushort4*)(&As[row*64 + (k4 ^ ((row&7)<<3))]) = h4;
    }
#pragma unroll
    for (int i=0;i<8;++i){
      int g = i*256 + tid;
      int col = g>>4, k4 = (g&15)*4;
      int vn = n0 + col;
      if (MODE==3) vn = (vn<64) ? vn : vn+448;
      ushort4 h4 = *(const ushort4*)(Bt + (size_t)vn*Kd + k0 + k4);
      *(ushort4*)(&Bs[col*64 + (k4 ^ ((col&7)<<3))]) = h4;
    }
    __syncthreads();
#pragma unroll
    for (int ks=0; ks<2; ++ks){
      const int kk = ks*32 + (lane>>4)*8;
      bf16x8 af[4], bfm[4];
#pragma unroll
      for (int t=0;t<4;++t){
        int r = wm + t*16 + (lane&15);
        af[t] = *(bf16x8*)(&As[r*64 + (kk ^ ((r&7)<<3))]);
        int c = wn + t*16 + (lane&15);
        bfm[t] = *(bf16x8*)(&Bs[c*64 + (kk ^ ((c&7)<<3))]);
      }
#pragma unroll
      for (int mt=0;mt<4;++mt)
#pragma unroll
        for (int nt=0;nt<4;++nt)
          acc[mt][nt] = __builtin_amdgcn_mfma_f32_16x16x32_bf16(af[mt], bfm[nt], acc[mt][nt], 0,0,0);
    }
  }
  const int rbase = (lane>>4)*4;
  const int cl = lane&15;
#pragma unroll
  for (int mt=0;mt<4;++mt){
#pragma unroll
    for (int r=0;r<4;++r){
      int gm = m0 + wm + mt*16 + rbase + r;
#pragma unroll
      for (int nt=0;nt<4;++nt){
        int gn = n0 + wn + nt*16 + cl;
        float v = acc[mt][nt][r];
        if (MODE==0){
          if (gm < NTOK){ float o = v + bias[gn]; Cf[(size_t)(1+gm)*DIM + gn] = o>0.f?o:0.f; }
        } else if (MODE==1){
          int sec = gn>>9, hh=(gn>>6)&7, d=gn&63;
          if (sec==0) Q_[((size_t)hh*NPAD+gm)*DHD + d] = f2b(v*0.125f);
          else if (sec==1) K_[((size_t)hh*NPAD+gm)*DHD + d] = f2b(v);
          else {
            unsigned short bv = f2b(v);
            V_[((size_t)hh*NPAD+gm)*DHD + d] = bv;
            Vt_[((size_t)hh*DHD + d)*NPAD + gm] = bv;
          }
        } else if (MODE==2){
          if (gm < N1) Cf[(size_t)gm*DIM + gn] += v + bias[gn];
        } else {
          if (gn < 64) Cf[(size_t)gm*DHD + gn] = v*0.125f;
          else         C2[(size_t)gm*DHD + (gn-64)] = v;
        }
      }
    }
  }
}

__global__ void k_setcls(float* __restrict__ X, const float* __restrict__ cls){
  int i = blockIdx.x*256 + threadIdx.x;
  if (i < DIM) X[i] = cls[i];
}
__global__ void k_copy(float* __restrict__ d, const float* __restrict__ s, size_t n){
  size_t i = (size_t)blockIdx.x*256 + threadIdx.x;
  if (i<n) d[i]=s[i];
}

// ---------------- layernorm ----------------
__global__ void k_ln(const float* __restrict__ X, float* __restrict__ Y,
                     const float* __restrict__ w, const float* __restrict__ b)
{
  __shared__ float sb[4];
  const float* x = X + (size_t)blockIdx.x*DIM;
  float* y = Y + (size_t)blockIdx.x*DIM;
  int t = threadIdx.x;
  float a0=x[t], a1=x[t+256];
  float s = blockSum256(a0+a1, sb);
  float q = blockSum256(a0*a0+a1*a1, sb);
  float mean = s*(1.f/512.f);
  float var = q*(1.f/512.f) - mean*mean;
  float rstd = rsqrtf(var+1e-5f);
  y[t]     = (a0-mean)*rstd*w[t]+b[t];
  y[t+256] = (a1-mean)*rstd*w[t+256]+b[t+256];
}

// ---------------- landmarks ----------------
__global__ void k_landmark_b(const unsigned short* __restrict__ src, float* __restrict__ dst)
{
  int hm = blockIdx.x; int h = hm>>8, m = hm&255; int d = threadIdx.x;
  const unsigned short* base = src + ((size_t)h*NPAD + (size_t)m*LLM)*DHD + d;
  float s = 0.f;
  for (int j=0;j<LLM;++j) s += bf2f(base[(size_t)j*DHD]);
  dst[((size_t)h*MM + m)*DHD + d] = s * (1.f/(float)LLM);
}
__global__ void k_landmark(const float* __restrict__ src, float* __restrict__ dst)
{
  int hm = blockIdx.x; int h = hm>>8, m = hm&255; int d = threadIdx.x;
  const float* base = src + ((size_t)h*NPAD + (size_t)m*LLM)*DHD + d;
  float s = 0.f;
  for (int j=0;j<LLM;++j) s += base[(size_t)j*DHD];
  dst[((size_t)h*MM + m)*DHD + d] = s * (1.f/(float)LLM);
}

// ---------------- MFMA NT gemm, K=64: C[M x Nr] = A[M][64] @ B[Nr][64]^T ----------------
__global__ __launch_bounds__(64) void k_nt64(const float* __restrict__ A,
    const float* __restrict__ B, float* __restrict__ C,
    long sA, long sB, long sC, int Nr)
{
  int lane = threadIdx.x;
  int n0 = blockIdx.x*64, m0 = blockIdx.y*64;
  A += (size_t)blockIdx.z*sA; B += (size_t)blockIdx.z*sB; C += (size_t)blockIdx.z*sC;
  f32x4 acc[4][4] = {};
#pragma unroll
  for (int ks=0;ks<2;++ks){
    int kk = ks*32 + (lane>>4)*8;
    bf16x8 af[4], bfr[4];
#pragma unroll
    for (int mt=0;mt<4;++mt){
      const float* p = A + (size_t)(m0+mt*16+(lane&15))*64 + kk;
      af[mt] = cvt8(*(const float4*)p, *(const float4*)(p+4));
    }
#pragma unroll
    for (int nt=0;nt<4;++nt){
      const float* p = B + (size_t)(n0+nt*16+(lane&15))*64 + kk;
      bfr[nt] = cvt8(*(const float4*)p, *(const float4*)(p+4));
    }
#pragma unroll
    for (int mt=0;mt<4;++mt)
#pragma unroll
      for (int nt=0;nt<4;++nt)
        acc[mt][nt] = __builtin_amdgcn_mfma_f32_16x16x32_bf16(af[mt], bfr[nt], acc[mt][nt], 0,0,0);
  }
#pragma unroll
  for (int mt=0;mt<4;++mt)
#pragma unroll
    for (int r=0;r<4;++r){
      int row = m0+mt*16+(lane>>4)*4+r;
#pragma unroll
      for (int nt=0;nt<4;++nt){
        int col = n0+nt*16+(lane&15);
        C[(size_t)row*Nr + col] = acc[mt][nt][r];
      }
    }
}

// ---------------- pinv MFMA gemm 256x256(or x64), K=256, direct-from-global ----------------
// PM 0: C=A@B, write C+Ct    PM 1: C=alpha*(dc*A - A@B), write C+Ct    PM 2: write Ct bf16 (N=64)
template<int PM>
__global__ __launch_bounds__(64) void k_pgemm(const float* __restrict__ A,
    const float* __restrict__ Bt, float* __restrict__ C, float* __restrict__ Ct,
    unsigned short* __restrict__ Ctb, float dc, float alpha)
{
  int lane = threadIdx.x;
  int n0 = blockIdx.x*64, m0 = blockIdx.y*64;
  const float* Ab = A + (size_t)blockIdx.z*65536;
  const float* Bb = Bt + (size_t)blockIdx.z*(PM==2?16384:65536);
  f32x4 acc[4][4] = {};
#pragma unroll
  for (int ks=0;ks<8;++ks){
    int kk = ks*32 + (lane>>4)*8;
    bf16x8 af[4], bfr[4];
#pragma unroll
    for (int mt=0;mt<4;++mt){
      const float* p = Ab + (size_t)(m0+mt*16+(lane&15))*256 + kk;
      af[mt] = cvt8(*(const float4*)p, *(const float4*)(p+4));
    }
#pragma unroll
    for (int nt=0;nt<4;++nt){
      const float* p = Bb + (size_t)(n0+nt*16+(lane&15))*256 + kk;
      bfr[nt] = cvt8(*(const float4*)p, *(const float4*)(p+4));
    }
#pragma unroll
    for (int mt=0;mt<4;++mt)
#pragma unroll
      for (int nt=0;nt<4;++nt)
        acc[mt][nt] = __builtin_amdgcn_mfma_f32_16x16x32_bf16(af[mt], bfr[nt], acc[mt][nt], 0,0,0);
  }
#pragma unroll
  for (int mt=0;mt<4;++mt)
#pragma unroll
    for (int r=0;r<4;++r){
      int row = m0+mt*16+(lane>>4)*4+r;
#pragma unroll
      for (int nt=0;nt<4;++nt){
        int col = n0+nt*16+(lane&15);
        float v = acc[mt][nt][r];
        if (PM==1) v = alpha*(dc*Ab[(size_t)row*256+col] - v);
        if (PM==2){
          Ctb[(size_t)blockIdx.z*16384 + (size_t)col*256 + row] = f2b(v);
        } else {
          C [(size_t)blockIdx.z*65536 + (size_t)row*256 + col] = v;
          Ct[(size_t)blockIdx.z*65536 + (size_t)col*256 + row] = v;
        }
      }
    }
}

// ---------------- small elementwise ----------------
__global__ void k_softmax256(float* __restrict__ S)
{
  __shared__ float sb[4];
  float* row = S + ((size_t)blockIdx.x<<8);
  float x = row[threadIdx.x];
  float m = blockMax256(x, sb);
  float e = __expf(x-m);
  float s = blockSum256(e, sb);
  row[threadIdx.x] = e/s;
}
__global__ void k_rcsum(const float* __restrict__ A2, float* __restrict__ sums, int nb)
{
  __shared__ float sb[4];
  int b = blockIdx.x >> 8, r = blockIdx.x & 255;
  const float* Ab = A2 + ((size_t)b<<16);
  float v = (blockIdx.y==0) ? Ab[((size_t)r<<8) + threadIdx.x]
                            : Ab[((size_t)threadIdx.x<<8) + r];
  float s = blockSum256(v, sb);
  if (threadIdx.x==0) sums[(size_t)blockIdx.y*nb + blockIdx.x] = s;
}
__global__ void k_scale(const float* __restrict__ sums, float* __restrict__ scl, int nb)
{
  __shared__ float sb[4];
  float mr=-1e30f, mc=-1e30f;
  for (int i=threadIdx.x;i<nb;i+=256) mr = fmaxf(mr, sums[i]);
  for (int i=threadIdx.x;i<nb;i+=256) mc = fmaxf(mc, sums[nb+i]);
  mr = blockMax256(mr, sb);
  mc = blockMax256(mc, sb);
  if (threadIdx.x==0) scl[0] = 1.f/(mr*mc);
}
__global__ void k_z0(const float* __restrict__ A2, float* __restrict__ Z, float* __restrict__ Zt,
                     const float* __restrict__ scl)
{
  size_t idx = (size_t)blockIdx.x*256 + threadIdx.x;
  size_t b = idx>>16; int i=(int)((idx>>8)&255), j=(int)(idx&255);
  float s = scl[0];
  float v = A2[idx]*s;
  Zt[idx] = v;                              // Zt[b][i][j] = A2[b][i][j]*s
  Z[(b<<16)+((size_t)j<<8)+i] = v;          // Z = A2^T * s
}

// ---------------- attn3: MFMA flash (256 landmark queries vs key chunk) ----------------
__global__ __launch_bounds__(256) void k_attn3(const float* __restrict__ QL,
    const unsigned short* __restrict__ Kb, const unsigned short* __restrict__ Vt,
    float* __restrict__ Pmax, float* __restrict__ Psum, unsigned short* __restrict__ Pacc)
{
  __shared__ unsigned short Ks[64*64];
  __shared__ unsigned short Vs[64*64];
  __shared__ unsigned short Ps[4*64*64];
  int h = blockIdx.y, cx = blockIdx.x;
  int tid = threadIdx.x, wid = tid>>6, lane = tid&63;
  // hoisted QL A-fragments (wave owns rows wid*64 .. wid*64+63)
  bf16x8 aq[4][2];
#pragma unroll
  for (int mt=0;mt<4;++mt){
    const float* qp = QL + ((size_t)h*MM + wid*64 + mt*16 + (lane&15))*DHD;
#pragma unroll
    for (int ks=0;ks<2;++ks){
      int kk = ks*32 + (lane>>4)*8;
      aq[mt][ks] = cvt8(*(const float4*)(qp+kk), *(const float4*)(qp+kk+4));
    }
  }
  float m_[4][4], l_[4][4];
  f32x4 acc[4][4] = {};
#pragma unroll
  for (int mt=0;mt<4;++mt)
#pragma unroll
    for (int r=0;r<4;++r){ m_[mt][r] = -1e30f; l_[mt][r] = 0.f; }

  unsigned short* Pw = &Ps[wid*4096];
  for (int t=0;t<4;++t){
    int kb0 = cx*CSZ + t*64;
    __syncthreads();
    for (int i=tid;i<1024;i+=256){
      int rr = i>>4, c4 = (i&15)*4;
      ushort4 ku = *(const ushort4*)(Kb + ((size_t)h*NPAD + kb0 + rr)*DHD + c4);
      *(ushort4*)(&Ks[rr*64 + (c4 ^ ((rr&7)<<3))]) = ku;
      ushort4 vu = *(const ushort4*)(Vt + ((size_t)h*DHD + rr)*NPAD + kb0 + c4);
      *(ushort4*)(&Vs[rr*64 + (c4 ^ ((rr&7)<<3))]) = vu;
    }
    __syncthreads();
    // S = QL @ K^T  (64 rows x 64 keys per wave)
    f32x4 s[4][4] = {};
#pragma unroll
    for (int ks=0;ks<2;++ks){
      int kk = ks*32 + (lane>>4)*8;
      bf16x8 kbf[4];
#pragma unroll
      for (int nt=0;nt<4;++nt){
        int key = nt*16 + (lane&15);
        kbf[nt] = *(const bf16x8*)(&Ks[key*64 + (kk ^ ((key&7)<<3))]);
      }
#pragma unroll
      for (int mt=0;mt<4;++mt)
#pragma unroll
        for (int nt=0;nt<4;++nt)
          s[mt][nt] = __builtin_amdgcn_mfma_f32_16x16x32_bf16(aq[mt][ks], kbf[nt], s[mt][nt], 0,0,0);
    }
    // online softmax per row-slot
#pragma unroll
    for (int mt=0;mt<4;++mt){
#pragma unroll
      for (int r=0;r<4;++r){
        float mx = fmaxf(fmaxf(s[mt][0][r], s[mt][1][r]), fmaxf(s[mt][2][r], s[mt][3][r]));
#pragma unroll
        for (int off=8;off>=1;off>>=1) mx = fmaxf(mx, __shfl_xor(mx, off));
        float mn = fmaxf(m_[mt][r], mx);
        float f = __expf(m_[mt][r]-mn);
        float la = 0.f;
#pragma unroll
        for (int nt=0;nt<4;++nt){ float p=__expf(s[mt][nt][r]-mn); s[mt][nt][r]=p; la+=p; }
#pragma unroll
        for (int off=8;off>=1;off>>=1) la += __shfl_xor(la, off);
        l_[mt][r] = l_[mt][r]*f + la;
        m_[mt][r] = mn;
#pragma unroll
        for (int dt=0;dt<4;++dt) acc[mt][dt][r] *= f;
      }
    }
    // write P (wave-private)
#pragma unroll
    for (int mt=0;mt<4;++mt)
#pragma unroll
      for (int r=0;r<4;++r){
        int row = mt*16 + (lane>>4)*4 + r;
        int sw = (row&7)<<3;
#pragma unroll
        for (int nt=0;nt<4;++nt){
          int col = nt*16 + (lane&15);
          Pw[row*64 + (col ^ sw)] = f2b(s[mt][nt][r]);
        }
      }
    // acc += P @ V^T(Vs is [d][key])
#pragma unroll
    for (int ks=0;ks<2;++ks){
      int kk = ks*32 + (lane>>4)*8;
      bf16x8 pa[4], vb[4];
#pragma unroll
      for (int mt=0;mt<4;++mt){
        int arow = mt*16 + (lane&15);
        pa[mt] = *(const bf16x8*)(&Pw[arow*64 + (kk ^ ((arow&7)<<3))]);
      }
#pragma unroll
      for (int dt=0;dt<4;++dt){
        int d = dt*16 + (lane&15);
        vb[dt] = *(const bf16x8*)(&Vs[d*64 + (kk ^ ((d&7)<<3))]);
      }
#pragma unroll
      for (int mt=0;mt<4;++mt)
#pragma unroll
        for (int dt=0;dt<4;++dt)
          acc[mt][dt] = __builtin_amdgcn_mfma_f32_16x16x32_bf16(pa[mt], vb[dt], acc[mt][dt], 0,0,0);
    }
  }
  // epilogue
  size_t pbase = ((size_t)h*NCH + cx)*MM;
#pragma unroll
  for (int mt=0;mt<4;++mt)
#pragma unroll
    for (int r=0;r<4;++r){
      int row = wid*64 + mt*16 + (lane>>4)*4 + r;
      if ((lane&15)==0){ Pmax[pbase+row]=m_[mt][r]; Psum[pbase+row]=l_[mt][r]; }
#pragma unroll
      for (int dt=0;dt<4;++dt)
        Pacc[(pbase+row)*DHD + dt*16+(lane&15)] = f2b(acc[mt][dt][r]);
    }
}

__global__ void k_attn3_merge(const float* __restrict__ Pmax, const float* __restrict__ Psum,
    const unsigned short* __restrict__ Pacc, float* __restrict__ A3Vt)
{
  int hm = blockIdx.x; int h = hm>>8, m = hm&255; int d = threadIdx.x;
  float gm = -1e30f;
  for (int c=0;c<NCH;++c) gm = fmaxf(gm, Pmax[((size_t)h*NCH+c)*MM+m]);
  float tot=0.f, acc=0.f;
  for (int c=0;c<NCH;++c){
    size_t pi = ((size_t)h*NCH+c)*MM+m;
    float w = __expf(Pmax[pi]-gm);
    tot += Psum[pi]*w;
    acc += bf2f(Pacc[pi*DHD+d])*w;
  }
  A3Vt[((size_t)h*DHD + d)*MM + m] = acc/tot;
}

// ---------------- attn1: MFMA, exact softmax over 256 landmarks ----------------
__global__ __launch_bounds__(256) void k_attn1(const unsigned short* __restrict__ Qb,
    const float* __restrict__ KL, const unsigned short* __restrict__ WmT,
    float* __restrict__ OH)
{
  __shared__ unsigned short KWs[64*256];   // KL[lm][k] then W^T[d][lm]
  __shared__ unsigned short Ps[64*256];    // P[q][lm]
  int h = blockIdx.y, tid = threadIdx.x;
  int wid = tid>>6, lane = tid&63;
  int q0 = blockIdx.x*64;
  // stage KL -> bf16 [lm][64] swizzled
  for (int i=tid; i<4096; i+=256){
    int lm = i>>4, k4 = (i&15)*4;
    float4 v = *(const float4*)(KL + ((size_t)h*MM + lm)*DHD + k4);
    ushort4 u; u.x=f2b(v.x); u.y=f2b(v.y); u.z=f2b(v.z); u.w=f2b(v.w);
    *(ushort4*)(&KWs[lm*64 + (k4 ^ ((lm&7)<<3))]) = u;
  }
  bf16x8 aq[2];
  const unsigned short* qp = Qb + ((size_t)h*NPAD + q0 + wid*16 + (lane&15))*DHD;
#pragma unroll
  for (int ks=0;ks<2;++ks)
    aq[ks] = *(const bf16x8*)(qp + ks*32 + (lane>>4)*8);
  __syncthreads();
  f32x4 s[16];
#pragma unroll
  for (int nt=0;nt<16;++nt) s[nt] = (f32x4){0.f,0.f,0.f,0.f};
#pragma unroll
  for (int ks=0;ks<2;++ks){
    int kk = ks*32 + (lane>>4)*8;
#pragma unroll
    for (int nt=0;nt<16;++nt){
      int col = nt*16 + (lane&15);
      bf16x8 b = *(const bf16x8*)(&KWs[col*64 + (kk ^ ((col&7)<<3))]);
      s[nt] = __builtin_amdgcn_mfma_f32_16x16x32_bf16(aq[ks], b, s[nt], 0,0,0);
    }
  }
  float rcp[4];
#pragma unroll
  for (int r=0;r<4;++r){
    float m = -1e30f;
#pragma unroll
    for (int nt=0;nt<16;++nt) m = fmaxf(m, s[nt][r]);
#pragma unroll
    for (int off=8;off>=1;off>>=1) m = fmaxf(m, __shfl_xor(m, off));
    float l = 0.f;
#pragma unroll
    for (int nt=0;nt<16;++nt){ float p=__expf(s[nt][r]-m); s[nt][r]=p; l+=p; }
#pragma unroll
    for (int off=8;off>=1;off>>=1) l += __shfl_xor(l, off);
    rcp[r] = 1.f/l;
  }
  int prow_base = wid*16 + (lane>>4)*4;
#pragma unroll
  for (int nt=0;nt<16;++nt){
    int col = nt*16 + (lane&15);
#pragma unroll
    for (int r=0;r<4;++r){
      int row = prow_base + r;
      Ps[row*256 + (col ^ ((row&7)<<3))] = f2b(s[nt][r]);
    }
  }
  __syncthreads();
  // stage W^T -> bf16 [d][256] swizzled (reuse KWs)
  for (int i=tid; i<4096; i+=256){
    int d = i>>6, k4 = (i&63)*4;
    ushort4 u = *(const ushort4*)(WmT + ((size_t)h*DHD + d)*MM + k4);
    *(ushort4*)(&KWs[d*256 + (k4 ^ ((d&7)<<3))]) = u;
  }
  __syncthreads();
  f32x4 acc[4] = {};
  int arow = wid*16 + (lane&15);
#pragma unroll
  for (int ks=0;ks<8;++ks){
    int kk = ks*32 + (lane>>4)*8;
    bf16x8 a = *(const bf16x8*)(&Ps[arow*256 + (kk ^ ((arow&7)<<3))]);
#pragma unroll
    for (int dt=0;dt<4;++dt){
      int d = dt*16 + (lane&15);
      bf16x8 b = *(const bf16x8*)(&KWs[d*256 + (kk ^ ((d&7)<<3))]);
      acc[dt] = __builtin_amdgcn_mfma_f32_16x16x32_bf16(a, b, acc[dt], 0,0,0);
    }
  }
#pragma unroll
  for (int r=0;r<4;++r){
    int row = q0 + prow_base + r;
    float* op = OH + (size_t)row*DIM + h*DHD;
#pragma unroll
    for (int dt=0;dt<4;++dt)
      op[dt*16 + (lane&15)] = acc[dt][r]*rcp[r];
  }
}

// ---------------- depthwise conv along seq, token-major OH += conv(V) ----------------
__global__ void k_seqconv(const unsigned short* __restrict__ Vb, const float* __restrict__ resk,
                          float* __restrict__ OH)
{
  size_t idx = (size_t)blockIdx.x*256 + threadIdx.x;
  int c = (int)(idx & 511);
  size_t p = idx >> 9;
  int h = c>>6, d = c&63;
  const float* kr = resk + h*33;
  float s = 0.f;
#pragma unroll
  for (int r=0;r<33;++r){
    long p2 = (long)p - 16 + r;
    if (p2 >= 0 && p2 < NPAD) s += bf2f(Vb[((size_t)h*NPAD+p2)*DHD + d])*kr[r];
  }
  OH[idx] += s;
}

// ---------------- leff ----------------
__global__ void k_tfwd(const float* __restrict__ X, float* __restrict__ T)
{
  __shared__ float tile[32][33];
  int tx = threadIdx.x & 31, ty = threadIdx.x >> 5;
  int s0 = blockIdx.x*32, c0 = blockIdx.y*32;
  for (int yy=0; yy<4; ++yy){
    int s = s0 + ty + yy*8;
    if (s < NTOK) tile[ty+yy*8][tx] = X[(size_t)(1+s)*DIM + c0+tx];
  }
  __syncthreads();
  for (int yy=0; yy<4; ++yy){
    int c = c0 + ty + yy*8;
    int s = s0 + tx;
    if (s < NTOK) T[(size_t)c*NTOK + s] = tile[tx][ty+yy*8];
  }
}
__global__ void k_tbwd(const float* __restrict__ T, float* __restrict__ X)
{
  __shared__ float tile[32][33];
  int tx = threadIdx.x & 31, ty = threadIdx.x >> 5;
  int s0 = blockIdx.x*32, c0 = blockIdx.y*32;
  for (int yy=0; yy<4; ++yy){
    int c = c0 + ty + yy*8, s = s0 + tx;
    if (s < NTOK) tile[ty+yy*8][tx] = T[(size_t)c*NTOK + s];
  }
  __syncthreads();
  for (int yy=0; yy<4; ++yy){
    int s = s0 + ty + yy*8, c = c0 + tx;
    if (s < NTOK) X[(size_t)(1+s)*DIM + c] = tile[tx][ty+yy*8];
  }
}
__global__ __launch_bounds__(256) void k_leff(const float* __restrict__ T,
    const float* __restrict__ k7, const float* __restrict__ b7,
    const float* __restrict__ k5, const float* __restrict__ b5,
    const float* __restrict__ k3, const float* __restrict__ b3,
    float* __restrict__ T2)
{
  __shared__ float tile[21*21];
  int c = blockIdx.y;
  int ti = blockIdx.x/10, tj = blockIdx.x%10;
  int i0 = ti*15-3, j0 = tj*15-3;
  const float* img = T + (size_t)c*NTOK;
  for (int idx=threadIdx.x; idx<441; idx+=256){
    int ii = idx/21, jj = idx%21;
    int gi = i0+ii, gj = j0+jj;
    tile[idx] = (gi>=0 && gi<HSZ && gj>=0 && gj<HSZ) ? img[gi*HSZ+gj] : 0.f;
  }
  __syncthreads();
  if (threadIdx.x < 225){
    int li = threadIdx.x/15, lj = threadIdx.x%15;
    int gi = ti*15+li, gj = tj*15+lj;
    float acc = tile[(li+3)*21 + (lj+3)] + b7[c]+b5[c]+b3[c];
    const float* w7 = k7 + c*49;
#pragma unroll
    for (int a=0;a<7;++a)
#pragma unroll
      for (int bb=0;bb<7;++bb) acc += tile[(li+a)*21 + (lj+bb)]*w7[a*7+bb];
    const float* w5 = k5 + c*25;
#pragma unroll
    for (int a=0;a<5;++a)
#pragma unroll
      for (int bb=0;bb<5;++bb) acc += tile[(li+1+a)*21 + (lj+1+bb)]*w5[a*5+bb];
    const float* w3 = k3 + c*9;
#pragma unroll
    for (int a=0;a<3;++a)
#pragma unroll
      for (int bb=0;bb<3;++bb) acc += tile[(li+2+a)*21 + (lj+2+bb)]*w3[a*3+bb];
    T2[(size_t)c*NTOK + gi*HSZ+gj] = acc;
  }
}

// ---------------- cls-row pieces ----------------
__global__ void k_row1(const float* __restrict__ Q0, const float* __restrict__ KL0,
                       float* __restrict__ row1)
{
  __shared__ float sb[4];
  __shared__ float qv[64];
  int t = threadIdx.x;
  if (t<64) qv[t] = Q0[PADR*DHD + t];
  __syncthreads();
  float l = 0.f;
#pragma unroll
  for (int d=0;d<64;++d) l += qv[d]*KL0[(size_t)t*DHD+d];
  float m = blockMax256(l, sb);
  float e = __expf(l-m);
  float s = blockSum256(e, sb);
  row1[t] = e/s;
}
__global__ void k_rz(const float* __restrict__ row1, const float* __restrict__ Zt,
                     float* __restrict__ rz)
{
  __shared__ float r1[256];
  int t = threadIdx.x;
  r1[t] = row1[t];
  __syncthreads();
  float s = 0.f;
  for (int k2=0;k2<256;++k2) s += r1[k2]*Zt[(size_t)t*MM + k2];
  rz[t] = s;
}
__global__ void k_rowstat(const float* __restrict__ L0, float* __restrict__ mx, float* __restrict__ se)
{
  __shared__ float sb[4];
  const float* row = L0 + (size_t)blockIdx.x*NPAD;
  float m = -1e30f;
  for (int i=threadIdx.x;i<NPAD;i+=256) m = fmaxf(m, row[i]);
  m = blockMax256(m, sb);
  float s = 0.f;
  for (int i=threadIdx.x;i<NPAD;i+=256) s += __expf(row[i]-m);
  s = blockSum256(s, sb);
  if (threadIdx.x==0){ mx[blockIdx.x]=m; se[blockIdx.x]=s; }
}
__global__ void k_aout(const float* __restrict__ L0, const float* __restrict__ rz,
    const float* __restrict__ mx, const float* __restrict__ se, float* __restrict__ out)
{
  __shared__ float wk[256], mk[256];
  int t = threadIdx.x;
  wk[t] = rz[t]/se[t];
  mk[t] = mx[t];
  __syncthreads();
  int p = blockIdx.x*256 + t;
  if (p >= NTOK) return;
  size_t pp = (size_t)(PADR+1+p);
  float a = 0.f;
  for (int k2=0;k2<256;++k2) a += wk[k2]*__expf(L0[(size_t)k2*NPAD+pp]-mk[k2]);
  out[4+p] = a;
}
__global__ void k_final(const float* __restrict__ H2r, const float* __restrict__ nw,
    const float* __restrict__ nbb, const float* __restrict__ w2, const float* __restrict__ b2,
    float* __restrict__ out)
{
  __shared__ float sb[4];
  __shared__ float hf[512];
  int t = threadIdx.x;
  float x0 = H2r[t], x1 = H2r[256+t];
  float s = blockSum256(x0+x1, sb);
  float q = blockSum256(x0*x0+x1*x1, sb);
  float mean = s*(1.f/512.f);
  float var = q*(1.f/512.f) - mean*mean;
  float rstd = rsqrtf(var+1e-5f);
  hf[t]     = (x0-mean)*rstd*nw[t]+nbb[t];
  hf[256+t] = (x1-mean)*rstd*nw[256+t]+nbb[256+t];
  __syncthreads();
  float p0 = hf[t]*w2[t*2]   + hf[256+t]*w2[(256+t)*2];
  float p1 = hf[t]*w2[t*2+1] + hf[256+t]*w2[(256+t)*2+1];
  p0 = blockSum256(p0, sb);
  p1 = blockSum256(p1, sb);
  if (t==0){
    float l0 = p0+b2[0], l1 = p1+b2[1];
    float m = fmaxf(l0,l1);
    float e0 = __expf(l0-m), e1 = __expf(l1-m), si = 1.f/(e0+e1);
    out[0]=l0; out[1]=l1; out[2]=e0*si; out[3]=e1*si;
  }
}

// ---------------- host orchestration ----------------
struct Bufs {
  float *X,*Y,*QL,*KL,*A2,*Z0,*Z0t,*Z1,*Z1t,*XZ,*XZt,*T1,*T1t,*T2,*T2t;
  float *A3Vt,*sums,*scl,*Pmax,*Psum;
  unsigned short *Qb,*Kb,*Vb,*Vt,*WmT,*Pacc;
};

static void run_pinv(const float* A2, Bufs& b, int NB, hipStream_t st,
                     float** outZ, float** outZt)
{
  dim3 g(4,4,NB);
  float *Zc=b.Z0, *Zct=b.Z0t, *Zn=b.Z1, *Znt=b.Z1t;
  for (int it=0; it<6; ++it){
    k_pgemm<0><<<g,64,0,st>>>(A2, Zct, b.XZ, b.XZt, nullptr, 0.f, 1.f);
    k_pgemm<1><<<g,64,0,st>>>(b.XZ, b.XZt, b.T1, b.T1t, nullptr, 7.f, 1.f);
    k_pgemm<1><<<g,64,0,st>>>(b.XZ, b.T1t, b.T2, b.T2t, nullptr, 15.f, 1.f);
    k_pgemm<1><<<g,64,0,st>>>(Zc, b.T2t, Zn, Znt, nullptr, 13.f, 0.25f);
    float* t1=Zc; Zc=Zn; Zn=t1;
    float* t2=Zct; Zct=Znt; Znt=t2;
  }
  *outZ = Zc; *outZt = Zct;
}

static void nystrom_layer(Bufs& b, const float* lnw, const float* lnb,
    const unsigned short* wqkvT, const unsigned short* woutT,
    const float* bout, const float* resk, hipStream_t st)
{
  k_ln<<<N1,256,0,st>>>(b.X, b.Y, lnw, lnb);
  k_gemm<1><<<dim3(NPAD/128,12),256,0,st>>>(b.Y, wqkvT, nullptr, nullptr, nullptr,
      b.Qb, b.Kb, b.Vb, b.Vt, DIM);
  k_landmark_b<<<NH*MM,64,0,st>>>(b.Qb, b.QL);
  k_landmark_b<<<NH*MM,64,0,st>>>(b.Kb, b.KL);
  k_nt64<<<dim3(4,4,NH),64,0,st>>>(b.QL, b.KL, b.A2,
      (long)MM*DHD,(long)MM*DHD,(long)MM*MM, MM);
  k_softmax256<<<NH*MM,256,0,st>>>(b.A2);
  k_rcsum<<<dim3(NH*MM,2),256,0,st>>>(b.A2, b.sums, NH*MM);
  k_scale<<<1,256,0,st>>>(b.sums, b.scl, NH*MM);
  k_z0<<<NH*MM*MM/256,256,0,st>>>(b.A2, b.Z0, b.Z0t, b.scl);
  float *Zc, *Zct;
  run_pinv(b.A2, b, NH, st, &Zc, &Zct);
  k_attn3<<<dim3(NCH,NH),256,0,st>>>(b.QL, b.Kb, b.Vt, b.Pmax, b.Psum, b.Pacc);
  k_attn3_merge<<<NH*MM,64,0,st>>>(b.Pmax, b.Psum, b.Pacc, b.A3Vt);
  k_pgemm<2><<<dim3(1,4,NH),64,0,st>>>(Zc, b.A3Vt, nullptr, nullptr, b.WmT, 0.f, 1.f);
  k_attn1<<<dim3(NPAD/64,NH),256,0,st>>>(b.Qb, b.KL, b.WmT, b.Y);
  k_seqconv<<<(NPAD*DIM)/256,256,0,st>>>(b.Vb, resk, b.Y);
  k_gemm<2><<<dim3(176,4),256,0,st>>>(b.Y, woutT, bout, b.X, nullptr,
      nullptr, nullptr, nullptr, nullptr, DIM);
}

extern "C" void kernel_launch(void* const* d_in, const int* in_sizes, int n_in,
                              void* d_out, int out_size, void* d_ws, size_t ws_size,
                              hipStream_t stream)
{
  (void)n_in; (void)out_size;
  bool sig_order = (in_sizes[10] == 25088);
  int iL2 = sig_order ? 16 : 10;
  int iLf = sig_order ? 10 : 16;

  const float* h       = (const float*)d_in[0];
  const float* fc1_w   = (const float*)d_in[1];
  const float* fc1_b   = (const float*)d_in[2];
  const float* cls_tok = (const float*)d_in[3];
  const float* l1_lnw  = (const float*)d_in[4];
  const float* l1_lnb  = (const float*)d_in[5];
  const float* l1_wqkv = (const float*)d_in[6];
  const float* l1_wout = (const float*)d_in[7];
  const float* l1_bout = (const float*)d_in[8];
  const float* l1_resk = (const float*)d_in[9];
  const float* l2_lnw  = (const float*)d_in[iL2+0];
  const float* l2_lnb  = (const float*)d_in[iL2+1];
  const float* l2_wqkv = (const float*)d_in[iL2+2];
  const float* l2_wout = (const float*)d_in[iL2+3];
  const float* l2_bout = (const float*)d_in[iL2+4];
  const float* l2_resk = (const float*)d_in[iL2+5];
  const float* k7 = (const float*)d_in[iLf+0];
  const float* b7 = (const float*)d_in[iLf+1];
  const float* k5 = (const float*)d_in[iLf+2];
  const float* b5 = (const float*)d_in[iLf+3];
  const float* k3 = (const float*)d_in[iLf+4];
  const float* b3 = (const float*)d_in[iLf+5];
  const float* nw = (const float*)d_in[22];
  const float* nbb= (const float*)d_in[23];
  const float* w2 = (const float*)d_in[24];
  const float* b2 = (const float*)d_in[25];
  float* out = (float*)d_out;

  char* base = (char*)d_ws;
  auto allocF = [&](size_t n)->float*{
    float* p=(float*)base; base += ((n*sizeof(float)+255)&~(size_t)255); return p; };
  auto allocU = [&](size_t n)->unsigned short*{
    unsigned short* p=(unsigned short*)base; base += ((n*sizeof(unsigned short)+255)&~(size_t)255); return p; };

  const size_t S = (size_t)NPAD*DIM;
  const size_t SQ = (size_t)MM*MM;   // 65536
  Bufs b;
  b.X  = allocF(S);
  b.Y  = allocF(S);
  b.Qb = allocU(S);
  b.Kb = allocU(S);
  b.Vb = allocU(S);
  b.Vt = allocU(S);
  b.QL = allocF((size_t)NH*MM*DHD);
  b.KL = allocF((size_t)NH*MM*DHD);
  b.A2 = allocF((size_t)NH*SQ);
  b.Z0 = allocF((size_t)NH*SQ);  b.Z0t = allocF((size_t)NH*SQ);
  b.Z1 = allocF((size_t)NH*SQ);  b.Z1t = allocF((size_t)NH*SQ);
  b.XZ = allocF((size_t)NH*SQ);  b.XZt = allocF((size_t)NH*SQ);
  b.T1 = allocF((size_t)NH*SQ);  b.T1t = allocF((size_t)NH*SQ);
  b.T2 = allocF((size_t)NH*SQ);  b.T2t = allocF((size_t)NH*SQ);
  b.A3Vt = allocF((size_t)NH*MM*DHD);
  b.WmT  = allocU((size_t)NH*MM*DHD);
  b.sums = allocF(2*(size_t)NH*MM);
  b.scl  = allocF(16);
  b.Pmax = allocF((size_t)NH*NCH*MM);
  b.Psum = allocF((size_t)NH*NCH*MM);
  b.Pacc = allocU((size_t)NH*NCH*MM*DHD);
  unsigned short* fc1T   = allocU((size_t)DIM*1024);
  unsigned short* wqkvT1 = allocU((size_t)1536*DIM);
  unsigned short* wqkvT2 = allocU((size_t)1536*DIM);
  unsigned short* woutT1 = allocU((size_t)DIM*DIM);
  unsigned short* woutT2 = allocU((size_t)DIM*DIM);
  float* Q0   = allocF((size_t)NPAD*DHD);
  float* K0   = allocF((size_t)NPAD*DHD);
  float* row1 = allocF(256);
  float* rzv  = allocF(256);
  float* mxv  = allocF(256);
  float* sev  = allocF(256);
  float* h2row= allocF(512);
  if ((size_t)(base - (char*)d_ws) > ws_size) return;

  // weight transposes (fp32 -> bf16 [N][K])
  k_wT<<<dim3(32,16),256,0,stream>>>(fc1_w, fc1T, 1024, DIM);
  k_wT<<<dim3(16,48),256,0,stream>>>(l1_wqkv, wqkvT1, DIM, 1536);
  k_wT<<<dim3(16,48),256,0,stream>>>(l2_wqkv, wqkvT2, DIM, 1536);
  k_wT<<<dim3(16,16),256,0,stream>>>(l1_wout, woutT1, DIM, DIM);
  k_wT<<<dim3(16,16),256,0,stream>>>(l2_wout, woutT2, DIM, DIM);

  // stage 0: fc1 + cls token
  k_gemm<0><<<dim3(176,4),256,0,stream>>>(h, fc1T, fc1_b, b.X, nullptr,
      nullptr, nullptr, nullptr, nullptr, 1024);
  k_setcls<<<2,256,0,stream>>>(b.X, cls_tok);

  // layer 1 + LeFF
  nystrom_layer(b, l1_lnw, l1_lnb, wqkvT1, woutT1, l1_bout, l1_resk, stream);
  k_tfwd<<<dim3(704,16),256,0,stream>>>(b.X, b.Y);
  k_leff<<<dim3(100,512),256,0,stream>>>(b.Y, k7,b7,k5,b5,k3,b3, (float*)b.Z0);
  k_tbwd<<<dim3(704,16),256,0,stream>>>((float*)b.Z0, b.X);

  // layer 2 (save h2 row 0 for the head)
  nystrom_layer(b, l2_lnw, l2_lnb, wqkvT2, woutT2, l2_bout, l2_resk, stream);
  k_copy<<<2,256,0,stream>>>(h2row, b.X, 512);

  // layer 3 -> h3
  nystrom_layer(b, l2_lnw, l2_lnb, wqkvT2, woutT2, l2_bout, l2_resk, stream);

  // cls-row stage (head 0, l2 weights, LN(h3))
  k_ln<<<N1,256,0,stream>>>(b.X, b.Y, l2_lnw, l2_lnb);
  k_gemm<3><<<dim3(176,1),256,0,stream>>>(b.Y, wqkvT2, nullptr, Q0, K0,
      nullptr, nullptr, nullptr, nullptr, DIM);
  k_landmark<<<MM,64,0,stream>>>(Q0, b.QL);
  k_landmark<<<MM,64,0,stream>>>(K0, b.KL);
  k_nt64<<<dim3(4,4,1),64,0,stream>>>(b.QL, b.KL, b.A2, 0,0,0, MM);
  k_softmax256<<<MM,256,0,stream>>>(b.A2);
  k_rcsum<<<dim3(MM,2),256,0,stream>>>(b.A2, b.sums, MM);
  k_scale<<<1,256,0,stream>>>(b.sums, b.scl, MM);
  k_z0<<<MM*MM/256,256,0,stream>>>(b.A2, b.Z0, b.Z0t, b.scl);
  float *Zc, *Zct;
  run_pinv(b.A2, b, 1, stream, &Zc, &Zct);
  k_row1<<<1,256,0,stream>>>(Q0, b.KL, row1);
  k_rz<<<1,256,0,stream>>>(row1, Zct, rzv);
  // L0 = QL0 @ K0^T (256 x NPAD), into Y
  k_nt64<<<dim3(NPAD/64,4,1),64,0,stream>>>(b.QL, K0, b.Y, 0,0,0, NPAD);
  k_rowstat<<<MM,256,0,stream>>>(b.Y, mxv, sev);
  k_aout<<<88,256,0,stream>>>(b.Y, rzv, mxv, sev, out);
  k_final<<<1,256,0,stream>>>(h2row, nw, nbb, w2, b2, out);
}

// Round 4
// 2740.452 us; speedup vs baseline: 3.3143x; 1.2812x over previous
//
#include <hip/hip_runtime.h>

#define NTOK 22500
#define N1   22501
#define NPAD 22528
#define PADR 27
#define DIM  512
#define NH   8
#define DHD  64
#define MM   256
#define LLM  88
#define HSZ  150
#define CSZ  256
#define NCH  88   // NPAD / CSZ

typedef short bf16x8 __attribute__((ext_vector_type(8)));
typedef float f32x4  __attribute__((ext_vector_type(4)));

union U8 { bf16x8 v; unsigned short u[8]; };

__device__ __forceinline__ unsigned short f2b(float f){
  unsigned int u = __float_as_uint(f);
  unsigned int r = u + 0x7fffu + ((u>>16)&1u);
  return (unsigned short)(r>>16);
}
__device__ __forceinline__ float bf2f(unsigned short u){
  return __uint_as_float(((unsigned int)u)<<16);
}
__device__ __forceinline__ bf16x8 cvt8(float4 a, float4 b){
  U8 u;
  u.u[0]=f2b(a.x); u.u[1]=f2b(a.y); u.u[2]=f2b(a.z); u.u[3]=f2b(a.w);
  u.u[4]=f2b(b.x); u.u[5]=f2b(b.y); u.u[6]=f2b(b.z); u.u[7]=f2b(b.w);
  return u.v;
}

// ---------------- reduction helpers ----------------
__device__ __forceinline__ float waveSum(float v){
#pragma unroll
  for (int o=32;o>0;o>>=1) v += __shfl_down(v,o);
  return v;
}
__device__ __forceinline__ float waveMax(float v){
#pragma unroll
  for (int o=32;o>0;o>>=1) v = fmaxf(v,__shfl_down(v,o));
  return v;
}
__device__ __forceinline__ float blockSum256(float v, float* sb){
  v = waveSum(v);
  __syncthreads();
  if ((threadIdx.x&63)==0) sb[threadIdx.x>>6]=v;
  __syncthreads();
  return sb[0]+sb[1]+sb[2]+sb[3];
}
__device__ __forceinline__ float blockMax256(float v, float* sb){
  v = waveMax(v);
  __syncthreads();
  if ((threadIdx.x&63)==0) sb[threadIdx.x>>6]=v;
  __syncthreads();
  return fmaxf(fmaxf(sb[0],sb[1]),fmaxf(sb[2],sb[3]));
}

// ---------------- weight transpose+cvt: W fp32 [K][N] -> Bt bf16 [N][K] ----------------
__global__ void k_wT(const float* __restrict__ W, unsigned short* __restrict__ Bt, int K, int N)
{
  __shared__ float tile[32][33];
  int tx = threadIdx.x&31, ty = threadIdx.x>>5;
  int k0 = blockIdx.x*32, n0 = blockIdx.y*32;
#pragma unroll
  for (int i=0;i<4;++i){
    int k = k0+ty+i*8;
    if (k<K && n0+tx<N) tile[ty+i*8][tx] = W[(size_t)k*N + n0+tx];
  }
  __syncthreads();
#pragma unroll
  for (int i=0;i<4;++i){
    int n = n0+ty+i*8, k = k0+tx;
    if (n<N && k<K) Bt[(size_t)n*K + k] = f2b(tile[tx][ty+i*8]);
  }
}

// ---------------- MFMA GEMM (128x128 tile): C = A(fp32->bf16) @ Bt^T(bf16) ----------------
// MODE 0: fc1   MODE 1: qkv (also writes Vt)   MODE 2: wout(+=)   MODE 3: qk0
template<int MODE>
__global__ __launch_bounds__(256) void k_gemm(const float* __restrict__ A,
    const unsigned short* __restrict__ Bt, const float* __restrict__ bias,
    float* __restrict__ Cf, float* __restrict__ C2,
    unsigned short* __restrict__ Q_, unsigned short* __restrict__ K_,
    unsigned short* __restrict__ V_, unsigned short* __restrict__ Vt_, int Kd)
{
  __shared__ unsigned short As[128*64];
  __shared__ unsigned short Bs[128*64];
  const int tid = threadIdx.x;
  const int m0 = blockIdx.x*128, n0 = blockIdx.y*128;
  const int lane = tid & 63;
  const int wid = tid >> 6;
  const int wm = (wid>>1)*64, wn = (wid&1)*64;
  f32x4 acc[4][4] = {};
  for (int k0=0; k0<Kd; k0+=64){
    __syncthreads();
#pragma unroll
    for (int i=0;i<8;++i){
      int g = i*256 + tid;
      int row = g>>4, k4 = (g&15)*4;
      float4 v = make_float4(0.f,0.f,0.f,0.f);
      int gm = m0 + row;
      if (MODE==0){ if (gm < NTOK) v = *(const float4*)(A + (size_t)gm*Kd + k0 + k4); }
      else if (MODE==1 || MODE==3){ if (gm >= PADR) v = *(const float4*)(A + (size_t)(gm-PADR)*Kd + k0 + k4); }
      else { if (gm < N1) v = *(const float4*)(A + (size_t)(gm+PADR)*Kd + k0 + k4); }
      ushort4 h4;
      h4.x=f2b(v.x); h4.y=f2b(v.y); h4.z=f2b(v.z); h4.w=f2b(v.w);
      *(ushort4*)(&As[row*64 + (k4 ^ ((row&7)<<3))]) = h4;
    }
#pragma unroll
    for (int i=0;i<8;++i){
      int g = i*256 + tid;
      int col = g>>4, k4 = (g&15)*4;
      int vn = n0 + col;
      if (MODE==3) vn = (vn<64) ? vn : vn+448;
      ushort4 h4 = *(const ushort4*)(Bt + (size_t)vn*Kd + k0 + k4);
      *(ushort4*)(&Bs[col*64 + (k4 ^ ((col&7)<<3))]) = h4;
    }
    __syncthreads();
#pragma unroll
    for (int ks=0; ks<2; ++ks){
      const int kk = ks*32 + (lane>>4)*8;
      bf16x8 af[4], bfm[4];
#pragma unroll
      for (int t=0;t<4;++t){
        int r = wm + t*16 + (lane&15);
        af[t] = *(bf16x8*)(&As[r*64 + (kk ^ ((r&7)<<3))]);
        int c = wn + t*16 + (lane&15);
        bfm[t] = *(bf16x8*)(&Bs[c*64 + (kk ^ ((c&7)<<3))]);
      }
#pragma unroll
      for (int mt=0;mt<4;++mt)
#pragma unroll
        for (int nt=0;nt<4;++nt)
          acc[mt][nt] = __builtin_amdgcn_mfma_f32_16x16x32_bf16(af[mt], bfm[nt], acc[mt][nt], 0,0,0);
    }
  }
  const int rbase = (lane>>4)*4;
  const int cl = lane&15;
#pragma unroll
  for (int mt=0;mt<4;++mt){
#pragma unroll
    for (int r=0;r<4;++r){
      int gm = m0 + wm + mt*16 + rbase + r;
#pragma unroll
      for (int nt=0;nt<4;++nt){
        int gn = n0 + wn + nt*16 + cl;
        float v = acc[mt][nt][r];
        if (MODE==0){
          if (gm < NTOK){ float o = v + bias[gn]; Cf[(size_t)(1+gm)*DIM + gn] = o>0.f?o:0.f; }
        } else if (MODE==1){
          int sec = gn>>9, hh=(gn>>6)&7, d=gn&63;
          if (sec==0) Q_[((size_t)hh*NPAD+gm)*DHD + d] = f2b(v*0.125f);
          else if (sec==1) K_[((size_t)hh*NPAD+gm)*DHD + d] = f2b(v);
          else {
            unsigned short bv = f2b(v);
            V_[((size_t)hh*NPAD+gm)*DHD + d] = bv;
            Vt_[((size_t)hh*DHD + d)*NPAD + gm] = bv;
          }
        } else if (MODE==2){
          if (gm < N1) Cf[(size_t)gm*DIM + gn] += v + bias[gn];
        } else {
          if (gn < 64) Cf[(size_t)gm*DHD + gn] = v*0.125f;
          else         C2[(size_t)gm*DHD + (gn-64)] = v;
        }
      }
    }
  }
}

__global__ void k_setcls(float* __restrict__ X, const float* __restrict__ cls){
  int i = blockIdx.x*256 + threadIdx.x;
  if (i < DIM) X[i] = cls[i];
}
__global__ void k_copy(float* __restrict__ d, const float* __restrict__ s, size_t n){
  size_t i = (size_t)blockIdx.x*256 + threadIdx.x;
  if (i<n) d[i]=s[i];
}

// ---------------- layernorm ----------------
__global__ void k_ln(const float* __restrict__ X, float* __restrict__ Y,
                     const float* __restrict__ w, const float* __restrict__ b)
{
  __shared__ float sb[4];
  const float* x = X + (size_t)blockIdx.x*DIM;
  float* y = Y + (size_t)blockIdx.x*DIM;
  int t = threadIdx.x;
  float a0=x[t], a1=x[t+256];
  float s = blockSum256(a0+a1, sb);
  float q = blockSum256(a0*a0+a1*a1, sb);
  float mean = s*(1.f/512.f);
  float var = q*(1.f/512.f) - mean*mean;
  float rstd = rsqrtf(var+1e-5f);
  y[t]     = (a0-mean)*rstd*w[t]+b[t];
  y[t+256] = (a1-mean)*rstd*w[t+256]+b[t+256];
}

// ---------------- landmarks ----------------
__global__ void k_landmark_b(const unsigned short* __restrict__ src, float* __restrict__ dst)
{
  int hm = blockIdx.x; int h = hm>>8, m = hm&255; int d = threadIdx.x;
  const unsigned short* base = src + ((size_t)h*NPAD + (size_t)m*LLM)*DHD + d;
  float s = 0.f;
  for (int j=0;j<LLM;++j) s += bf2f(base[(size_t)j*DHD]);
  dst[((size_t)h*MM + m)*DHD + d] = s * (1.f/(float)LLM);
}
__global__ void k_landmark(const float* __restrict__ src, float* __restrict__ dst)
{
  int hm = blockIdx.x; int h = hm>>8, m = hm&255; int d = threadIdx.x;
  const float* base = src + ((size_t)h*NPAD + (size_t)m*LLM)*DHD + d;
  float s = 0.f;
  for (int j=0;j<LLM;++j) s += base[(size_t)j*DHD];
  dst[((size_t)h*MM + m)*DHD + d] = s * (1.f/(float)LLM);
}

// ---------------- MFMA NT gemm, K=64: C[M x Nr] = A[M][64] @ B[Nr][64]^T ----------------
__global__ __launch_bounds__(64) void k_nt64(const float* __restrict__ A,
    const float* __restrict__ B, float* __restrict__ C,
    long sA, long sB, long sC, int Nr)
{
  int lane = threadIdx.x;
  int n0 = blockIdx.x*64, m0 = blockIdx.y*64;
  A += (size_t)blockIdx.z*sA; B += (size_t)blockIdx.z*sB; C += (size_t)blockIdx.z*sC;
  f32x4 acc[4][4] = {};
#pragma unroll
  for (int ks=0;ks<2;++ks){
    int kk = ks*32 + (lane>>4)*8;
    bf16x8 af[4], bfr[4];
#pragma unroll
    for (int mt=0;mt<4;++mt){
      const float* p = A + (size_t)(m0+mt*16+(lane&15))*64 + kk;
      af[mt] = cvt8(*(const float4*)p, *(const float4*)(p+4));
    }
#pragma unroll
    for (int nt=0;nt<4;++nt){
      const float* p = B + (size_t)(n0+nt*16+(lane&15))*64 + kk;
      bfr[nt] = cvt8(*(const float4*)p, *(const float4*)(p+4));
    }
#pragma unroll
    for (int mt=0;mt<4;++mt)
#pragma unroll
      for (int nt=0;nt<4;++nt)
        acc[mt][nt] = __builtin_amdgcn_mfma_f32_16x16x32_bf16(af[mt], bfr[nt], acc[mt][nt], 0,0,0);
  }
#pragma unroll
  for (int mt=0;mt<4;++mt)
#pragma unroll
    for (int r=0;r<4;++r){
      int row = m0+mt*16+(lane>>4)*4+r;
#pragma unroll
      for (int nt=0;nt<4;++nt){
        int col = n0+nt*16+(lane&15);
        C[(size_t)row*Nr + col] = acc[mt][nt][r];
      }
    }
}

// ---------------- pinv MFMA gemm: 256 threads, 64x64 tile, LDS-staged panels ----------------
// PM 0: C=A@B, write C+Ct    PM 1: C=alpha*(dc*A - A@B), write C+Ct    PM 2: write Ct bf16 (N=64)
template<int PM>
__global__ __launch_bounds__(256) void k_pgemm(const float* __restrict__ A,
    const float* __restrict__ Bt, float* __restrict__ C, float* __restrict__ Ct,
    unsigned short* __restrict__ Ctb, float dc, float alpha)
{
  __shared__ unsigned short As[64*256];
  __shared__ unsigned short Bs[64*256];
  const int tid = threadIdx.x, lane = tid&63, wid = tid>>6;
  const int n0 = blockIdx.x*64, m0 = blockIdx.y*64;
  const float* Ab = A + (size_t)blockIdx.z*65536;
  const float* Bb = Bt + (size_t)blockIdx.z*(PM==2?16384:65536);
  for (int i=tid; i<4096; i+=256){
    int r = i>>6, c4 = (i&63)*4;
    float4 va = *(const float4*)(Ab + (size_t)(m0+r)*256 + c4);
    ushort4 ua; ua.x=f2b(va.x); ua.y=f2b(va.y); ua.z=f2b(va.z); ua.w=f2b(va.w);
    *(ushort4*)(&As[r*256 + (c4 ^ ((r&7)<<3))]) = ua;
    float4 vb = *(const float4*)(Bb + (size_t)(n0+r)*256 + c4);
    ushort4 ub; ub.x=f2b(vb.x); ub.y=f2b(vb.y); ub.z=f2b(vb.z); ub.w=f2b(vb.w);
    *(ushort4*)(&Bs[r*256 + (c4 ^ ((r&7)<<3))]) = ub;
  }
  __syncthreads();
  const int wm = (wid>>1)*32, wn = (wid&1)*32;
  f32x4 acc[2][2] = {};
#pragma unroll
  for (int ks=0;ks<8;++ks){
    int kk = ks*32 + (lane>>4)*8;
    bf16x8 af[2], bfr[2];
#pragma unroll
    for (int t=0;t<2;++t){
      int rr = wm + t*16 + (lane&15);
      af[t] = *(const bf16x8*)(&As[rr*256 + (kk ^ ((rr&7)<<3))]);
      int cc = wn + t*16 + (lane&15);
      bfr[t] = *(const bf16x8*)(&Bs[cc*256 + (kk ^ ((cc&7)<<3))]);
    }
#pragma unroll
    for (int mt=0;mt<2;++mt)
#pragma unroll
      for (int nt=0;nt<2;++nt)
        acc[mt][nt] = __builtin_amdgcn_mfma_f32_16x16x32_bf16(af[mt], bfr[nt], acc[mt][nt], 0,0,0);
  }
#pragma unroll
  for (int mt=0;mt<2;++mt)
#pragma unroll
    for (int r=0;r<4;++r){
      int row = m0 + wm + mt*16 + (lane>>4)*4 + r;
#pragma unroll
      for (int nt=0;nt<2;++nt){
        int col = n0 + wn + nt*16 + (lane&15);
        float v = acc[mt][nt][r];
        if (PM==1) v = alpha*(dc*Ab[(size_t)row*256+col] - v);
        if (PM==2){
          Ctb[(size_t)blockIdx.z*16384 + (size_t)col*256 + row] = f2b(v);
        } else {
          C [(size_t)blockIdx.z*65536 + (size_t)row*256 + col] = v;
          Ct[(size_t)blockIdx.z*65536 + (size_t)col*256 + row] = v;
        }
      }
    }
}

// ---------------- small elementwise ----------------
__global__ void k_softmax256(float* __restrict__ S)
{
  __shared__ float sb[4];
  float* row = S + ((size_t)blockIdx.x<<8);
  float x = row[threadIdx.x];
  float m = blockMax256(x, sb);
  float e = __expf(x-m);
  float s = blockSum256(e, sb);
  row[threadIdx.x] = e/s;
}
__global__ void k_rcsum(const float* __restrict__ A2, float* __restrict__ sums, int nb)
{
  __shared__ float sb[4];
  int b = blockIdx.x >> 8, r = blockIdx.x & 255;
  const float* Ab = A2 + ((size_t)b<<16);
  float v = (blockIdx.y==0) ? Ab[((size_t)r<<8) + threadIdx.x]
                            : Ab[((size_t)threadIdx.x<<8) + r];
  float s = blockSum256(v, sb);
  if (threadIdx.x==0) sums[(size_t)blockIdx.y*nb + blockIdx.x] = s;
}
__global__ void k_scale(const float* __restrict__ sums, float* __restrict__ scl, int nb)
{
  __shared__ float sb[4];
  float mr=-1e30f, mc=-1e30f;
  for (int i=threadIdx.x;i<nb;i+=256) mr = fmaxf(mr, sums[i]);
  for (int i=threadIdx.x;i<nb;i+=256) mc = fmaxf(mc, sums[nb+i]);
  mr = blockMax256(mr, sb);
  mc = blockMax256(mc, sb);
  if (threadIdx.x==0) scl[0] = 1.f/(mr*mc);
}
__global__ void k_z0(const float* __restrict__ A2, float* __restrict__ Z, float* __restrict__ Zt,
                     const float* __restrict__ scl)
{
  size_t idx = (size_t)blockIdx.x*256 + threadIdx.x;
  size_t b = idx>>16; int i=(int)((idx>>8)&255), j=(int)(idx&255);
  float s = scl[0];
  float v = A2[idx]*s;
  Zt[idx] = v;                              // Zt[b][i][j] = A2[b][i][j]*s
  Z[(b<<16)+((size_t)j<<8)+i] = v;          // Z = A2^T * s
}

// ---------------- attn3: MFMA flash (256 landmark queries vs key chunk) ----------------
__global__ __launch_bounds__(256) void k_attn3(const float* __restrict__ QL,
    const unsigned short* __restrict__ Kb, const unsigned short* __restrict__ Vt,
    float* __restrict__ Pmax, float* __restrict__ Psum, unsigned short* __restrict__ Pacc)
{
  __shared__ unsigned short Ks[64*64];
  __shared__ unsigned short Vs[64*64];
  __shared__ unsigned short Ps[4*64*64];
  int h = blockIdx.y, cx = blockIdx.x;
  int tid = threadIdx.x, wid = tid>>6, lane = tid&63;
  // hoisted QL A-fragments (wave owns rows wid*64 .. wid*64+63)
  bf16x8 aq[4][2];
#pragma unroll
  for (int mt=0;mt<4;++mt){
    const float* qp = QL + ((size_t)h*MM + wid*64 + mt*16 + (lane&15))*DHD;
#pragma unroll
    for (int ks=0;ks<2;++ks){
      int kk = ks*32 + (lane>>4)*8;
      aq[mt][ks] = cvt8(*(const float4*)(qp+kk), *(const float4*)(qp+kk+4));
    }
  }
  float m_[4][4], l_[4][4];
  f32x4 acc[4][4] = {};
#pragma unroll
  for (int mt=0;mt<4;++mt)
#pragma unroll
    for (int r=0;r<4;++r){ m_[mt][r] = -1e30f; l_[mt][r] = 0.f; }

  unsigned short* Pw = &Ps[wid*4096];
  for (int t=0;t<4;++t){
    int kb0 = cx*CSZ + t*64;
    __syncthreads();
    for (int i=tid;i<1024;i+=256){
      int rr = i>>4, c4 = (i&15)*4;
      ushort4 ku = *(const ushort4*)(Kb + ((size_t)h*NPAD + kb0 + rr)*DHD + c4);
      *(ushort4*)(&Ks[rr*64 + (c4 ^ ((rr&7)<<3))]) = ku;
      ushort4 vu = *(const ushort4*)(Vt + ((size_t)h*DHD + rr)*NPAD + kb0 + c4);
      *(ushort4*)(&Vs[rr*64 + (c4 ^ ((rr&7)<<3))]) = vu;
    }
    __syncthreads();
    // S = QL @ K^T  (64 rows x 64 keys per wave)
    f32x4 s[4][4] = {};
#pragma unroll
    for (int ks=0;ks<2;++ks){
      int kk = ks*32 + (lane>>4)*8;
      bf16x8 kbf[4];
#pragma unroll
      for (int nt=0;nt<4;++nt){
        int key = nt*16 + (lane&15);
        kbf[nt] = *(const bf16x8*)(&Ks[key*64 + (kk ^ ((key&7)<<3))]);
      }
#pragma unroll
      for (int mt=0;mt<4;++mt)
#pragma unroll
        for (int nt=0;nt<4;++nt)
          s[mt][nt] = __builtin_amdgcn_mfma_f32_16x16x32_bf16(aq[mt][ks], kbf[nt], s[mt][nt], 0,0,0);
    }
    // online softmax per row-slot
#pragma unroll
    for (int mt=0;mt<4;++mt){
#pragma unroll
      for (int r=0;r<4;++r){
        float mx = fmaxf(fmaxf(s[mt][0][r], s[mt][1][r]), fmaxf(s[mt][2][r], s[mt][3][r]));
#pragma unroll
        for (int off=8;off>=1;off>>=1) mx = fmaxf(mx, __shfl_xor(mx, off));
        float mn = fmaxf(m_[mt][r], mx);
        float f = __expf(m_[mt][r]-mn);
        float la = 0.f;
#pragma unroll
        for (int nt=0;nt<4;++nt){ float p=__expf(s[mt][nt][r]-mn); s[mt][nt][r]=p; la+=p; }
#pragma unroll
        for (int off=8;off>=1;off>>=1) la += __shfl_xor(la, off);
        l_[mt][r] = l_[mt][r]*f + la;
        m_[mt][r] = mn;
#pragma unroll
        for (int dt=0;dt<4;++dt) acc[mt][dt][r] *= f;
      }
    }
    // write P (wave-private)
#pragma unroll
    for (int mt=0;mt<4;++mt)
#pragma unroll
      for (int r=0;r<4;++r){
        int row = mt*16 + (lane>>4)*4 + r;
        int sw = (row&7)<<3;
#pragma unroll
        for (int nt=0;nt<4;++nt){
          int col = nt*16 + (lane&15);
          Pw[row*64 + (col ^ sw)] = f2b(s[mt][nt][r]);
        }
      }
    // acc += P @ V^T(Vs is [d][key])
#pragma unroll
    for (int ks=0;ks<2;++ks){
      int kk = ks*32 + (lane>>4)*8;
      bf16x8 pa[4], vb[4];
#pragma unroll
      for (int mt=0;mt<4;++mt){
        int arow = mt*16 + (lane&15);
        pa[mt] = *(const bf16x8*)(&Pw[arow*64 + (kk ^ ((arow&7)<<3))]);
      }
#pragma unroll
      for (int dt=0;dt<4;++dt){
        int d = dt*16 + (lane&15);
        vb[dt] = *(const bf16x8*)(&Vs[d*64 + (kk ^ ((d&7)<<3))]);
      }
#pragma unroll
      for (int mt=0;mt<4;++mt)
#pragma unroll
        for (int dt=0;dt<4;++dt)
          acc[mt][dt] = __builtin_amdgcn_mfma_f32_16x16x32_bf16(pa[mt], vb[dt], acc[mt][dt], 0,0,0);
    }
  }
  // epilogue
  size_t pbase = ((size_t)h*NCH + cx)*MM;
#pragma unroll
  for (int mt=0;mt<4;++mt)
#pragma unroll
    for (int r=0;r<4;++r){
      int row = wid*64 + mt*16 + (lane>>4)*4 + r;
      if ((lane&15)==0){ Pmax[pbase+row]=m_[mt][r]; Psum[pbase+row]=l_[mt][r]; }
#pragma unroll
      for (int dt=0;dt<4;++dt)
        Pacc[(pbase+row)*DHD + dt*16+(lane&15)] = f2b(acc[mt][dt][r]);
    }
}

__global__ void k_attn3_merge(const float* __restrict__ Pmax, const float* __restrict__ Psum,
    const unsigned short* __restrict__ Pacc, float* __restrict__ A3Vt)
{
  int hm = blockIdx.x; int h = hm>>8, m = hm&255; int d = threadIdx.x;
  float gm = -1e30f;
  for (int c=0;c<NCH;++c) gm = fmaxf(gm, Pmax[((size_t)h*NCH+c)*MM+m]);
  float tot=0.f, acc=0.f;
  for (int c=0;c<NCH;++c){
    size_t pi = ((size_t)h*NCH+c)*MM+m;
    float w = __expf(Pmax[pi]-gm);
    tot += Psum[pi]*w;
    acc += bf2f(Pacc[pi*DHD+d])*w;
  }
  A3Vt[((size_t)h*DHD + d)*MM + m] = acc/tot;
}

// ---------------- attn1: MFMA, exact softmax over 256 landmarks ----------------
__global__ __launch_bounds__(256) void k_attn1(const unsigned short* __restrict__ Qb,
    const float* __restrict__ KL, const unsigned short* __restrict__ WmT,
    float* __restrict__ OH)
{
  __shared__ unsigned short KWs[64*256];   // KL[lm][k] then W^T[d][lm]
  __shared__ unsigned short Ps[64*256];    // P[q][lm]
  int h = blockIdx.y, tid = threadIdx.x;
  int wid = tid>>6, lane = tid&63;
  int q0 = blockIdx.x*64;
  // stage KL -> bf16 [lm][64] swizzled
  for (int i=tid; i<4096; i+=256){
    int lm = i>>4, k4 = (i&15)*4;
    float4 v = *(const float4*)(KL + ((size_t)h*MM + lm)*DHD + k4);
    ushort4 u; u.x=f2b(v.x); u.y=f2b(v.y); u.z=f2b(v.z); u.w=f2b(v.w);
    *(ushort4*)(&KWs[lm*64 + (k4 ^ ((lm&7)<<3))]) = u;
  }
  bf16x8 aq[2];
  const unsigned short* qp = Qb + ((size_t)h*NPAD + q0 + wid*16 + (lane&15))*DHD;
#pragma unroll
  for (int ks=0;ks<2;++ks)
    aq[ks] = *(const bf16x8*)(qp + ks*32 + (lane>>4)*8);
  __syncthreads();
  f32x4 s[16];
#pragma unroll
  for (int nt=0;nt<16;++nt) s[nt] = (f32x4){0.f,0.f,0.f,0.f};
#pragma unroll
  for (int ks=0;ks<2;++ks){
    int kk = ks*32 + (lane>>4)*8;
#pragma unroll
    for (int nt=0;nt<16;++nt){
      int col = nt*16 + (lane&15);
      bf16x8 b = *(const bf16x8*)(&KWs[col*64 + (kk ^ ((col&7)<<3))]);
      s[nt] = __builtin_amdgcn_mfma_f32_16x16x32_bf16(aq[ks], b, s[nt], 0,0,0);
    }
  }
  float rcp[4];
#pragma unroll
  for (int r=0;r<4;++r){
    float m = -1e30f;
#pragma unroll
    for (int nt=0;nt<16;++nt) m = fmaxf(m, s[nt][r]);
#pragma unroll
    for (int off=8;off>=1;off>>=1) m = fmaxf(m, __shfl_xor(m, off));
    float l = 0.f;
#pragma unroll
    for (int nt=0;nt<16;++nt){ float p=__expf(s[nt][r]-m); s[nt][r]=p; l+=p; }
#pragma unroll
    for (int off=8;off>=1;off>>=1) l += __shfl_xor(l, off);
    rcp[r] = 1.f/l;
  }
  int prow_base = wid*16 + (lane>>4)*4;
#pragma unroll
  for (int nt=0;nt<16;++nt){
    int col = nt*16 + (lane&15);
#pragma unroll
    for (int r=0;r<4;++r){
      int row = prow_base + r;
      Ps[row*256 + (col ^ ((row&7)<<3))] = f2b(s[nt][r]);
    }
  }
  __syncthreads();
  // stage W^T -> bf16 [d][256] swizzled (reuse KWs)
  for (int i=tid; i<4096; i+=256){
    int d = i>>6, k4 = (i&63)*4;
    ushort4 u = *(const ushort4*)(WmT + ((size_t)h*DHD + d)*MM + k4);
    *(ushort4*)(&KWs[d*256 + (k4 ^ ((d&7)<<3))]) = u;
  }
  __syncthreads();
  f32x4 acc[4] = {};
  int arow = wid*16 + (lane&15);
#pragma unroll
  for (int ks=0;ks<8;++ks){
    int kk = ks*32 + (lane>>4)*8;
    bf16x8 a = *(const bf16x8*)(&Ps[arow*256 + (kk ^ ((arow&7)<<3))]);
#pragma unroll
    for (int dt=0;dt<4;++dt){
      int d = dt*16 + (lane&15);
      bf16x8 b = *(const bf16x8*)(&KWs[d*256 + (kk ^ ((d&7)<<3))]);
      acc[dt] = __builtin_amdgcn_mfma_f32_16x16x32_bf16(a, b, acc[dt], 0,0,0);
    }
  }
#pragma unroll
  for (int r=0;r<4;++r){
    int row = q0 + prow_base + r;
    float* op = OH + (size_t)row*DIM + h*DHD;
#pragma unroll
    for (int dt=0;dt<4;++dt)
      op[dt*16 + (lane&15)] = acc[dt][r]*rcp[r];
  }
}

// ---------------- depthwise conv along seq, LDS-staged strip, token-major OH += conv(V) ----------------
#define SCBLK 32
__global__ __launch_bounds__(256) void k_seqconv(const unsigned short* __restrict__ Vb,
    const float* __restrict__ resk, float* __restrict__ OH)
{
  __shared__ unsigned short Vs[64*512];   // [pl][c], 64 KB
  int tid = threadIdx.x;
  int p0 = blockIdx.x*SCBLK;
  for (int i=tid; i<16384; i+=256){      // ushort2 units
    int pl = i>>8, c2 = i&255;
    int gp = p0 - 16 + pl;
    int hh = c2>>5, d2 = (c2&31)*2;
    ushort2 v = make_ushort2(0,0);
    if (gp>=0 && gp<NPAD) v = *(const ushort2*)(Vb + ((size_t)hh*NPAD+gp)*DHD + d2);
    *(ushort2*)(&Vs[pl*512 + c2*2]) = v;
  }
  __syncthreads();
  int h = tid>>5;
  float kr[33];
#pragma unroll
  for (int r=0;r<33;++r) kr[r] = resk[h*33+r];
  for (int pl=0; pl<SCBLK; ++pl){
    float s0=0.f, s1=0.f;
#pragma unroll
    for (int r=0;r<33;++r){
      ushort2 v = *(const ushort2*)(&Vs[(pl+r)*512 + tid*2]);
      s0 += bf2f(v.x)*kr[r];
      s1 += bf2f(v.y)*kr[r];
    }
    size_t o = (size_t)(p0+pl)*DIM + tid*2;
    float2 cur = *(float2*)(OH + o);
    cur.x += s0; cur.y += s1;
    *(float2*)(OH + o) = cur;
  }
}

// ---------------- leff ----------------
__global__ void k_tfwd(const float* __restrict__ X, float* __restrict__ T)
{
  __shared__ float tile[32][33];
  int tx = threadIdx.x & 31, ty = threadIdx.x >> 5;
  int s0 = blockIdx.x*32, c0 = blockIdx.y*32;
  for (int yy=0; yy<4; ++yy){
    int s = s0 + ty + yy*8;
    if (s < NTOK) tile[ty+yy*8][tx] = X[(size_t)(1+s)*DIM + c0+tx];
  }
  __syncthreads();
  for (int yy=0; yy<4; ++yy){
    int c = c0 + ty + yy*8;
    int s = s0 + tx;
    if (s < NTOK) T[(size_t)c*NTOK + s] = tile[tx][ty+yy*8];
  }
}
__global__ void k_tbwd(const float* __restrict__ T, float* __restrict__ X)
{
  __shared__ float tile[32][33];
  int tx = threadIdx.x & 31, ty = threadIdx.x >> 5;
  int s0 = blockIdx.x*32, c0 = blockIdx.y*32;
  for (int yy=0; yy<4; ++yy){
    int c = c0 + ty + yy*8, s = s0 + tx;
    if (s < NTOK) tile[ty+yy*8][tx] = T[(size_t)c*NTOK + s];
  }
  __syncthreads();
  for (int yy=0; yy<4; ++yy){
    int s = s0 + ty + yy*8, c = c0 + tx;
    if (s < NTOK) X[(size_t)(1+s)*DIM + c] = tile[tx][ty+yy*8];
  }
}
__global__ __launch_bounds__(256) void k_leff(const float* __restrict__ T,
    const float* __restrict__ k7, const float* __restrict__ b7,
    const float* __restrict__ k5, const float* __restrict__ b5,
    const float* __restrict__ k3, const float* __restrict__ b3,
    float* __restrict__ T2)
{
  __shared__ float tile[21*21];
  int c = blockIdx.y;
  int ti = blockIdx.x/10, tj = blockIdx.x%10;
  int i0 = ti*15-3, j0 = tj*15-3;
  const float* img = T + (size_t)c*NTOK;
  for (int idx=threadIdx.x; idx<441; idx+=256){
    int ii = idx/21, jj = idx%21;
    int gi = i0+ii, gj = j0+jj;
    tile[idx] = (gi>=0 && gi<HSZ && gj>=0 && gj<HSZ) ? img[gi*HSZ+gj] : 0.f;
  }
  __syncthreads();
  if (threadIdx.x < 225){
    int li = threadIdx.x/15, lj = threadIdx.x%15;
    int gi = ti*15+li, gj = tj*15+lj;
    float acc = tile[(li+3)*21 + (lj+3)] + b7[c]+b5[c]+b3[c];
    const float* w7 = k7 + c*49;
#pragma unroll
    for (int a=0;a<7;++a)
#pragma unroll
      for (int bb=0;bb<7;++bb) acc += tile[(li+a)*21 + (lj+bb)]*w7[a*7+bb];
    const float* w5 = k5 + c*25;
#pragma unroll
    for (int a=0;a<5;++a)
#pragma unroll
      for (int bb=0;bb<5;++bb) acc += tile[(li+1+a)*21 + (lj+1+bb)]*w5[a*5+bb];
    const float* w3 = k3 + c*9;
#pragma unroll
    for (int a=0;a<3;++a)
#pragma unroll
      for (int bb=0;bb<3;++bb) acc += tile[(li+2+a)*21 + (lj+2+bb)]*w3[a*3+bb];
    T2[(size_t)c*NTOK + gi*HSZ+gj] = acc;
  }
}

// ---------------- cls-row pieces ----------------
__global__ void k_row1(const float* __restrict__ Q0, const float* __restrict__ KL0,
                       float* __restrict__ row1)
{
  __shared__ float sb[4];
  __shared__ float qv[64];
  int t = threadIdx.x;
  if (t<64) qv[t] = Q0[PADR*DHD + t];
  __syncthreads();
  float l = 0.f;
#pragma unroll
  for (int d=0;d<64;++d) l += qv[d]*KL0[(size_t)t*DHD+d];
  float m = blockMax256(l, sb);
  float e = __expf(l-m);
  float s = blockSum256(e, sb);
  row1[t] = e/s;
}
__global__ void k_rz(const float* __restrict__ row1, const float* __restrict__ Zt,
                     float* __restrict__ rz)
{
  __shared__ float r1[256];
  int t = threadIdx.x;
  r1[t] = row1[t];
  __syncthreads();
  float s = 0.f;
  for (int k2=0;k2<256;++k2) s += r1[k2]*Zt[(size_t)t*MM + k2];
  rz[t] = s;
}
__global__ void k_rowstat(const float* __restrict__ L0, float* __restrict__ mx, float* __restrict__ se)
{
  __shared__ float sb[4];
  const float* row = L0 + (size_t)blockIdx.x*NPAD;
  float m = -1e30f;
  for (int i=threadIdx.x;i<NPAD;i+=256) m = fmaxf(m, row[i]);
  m = blockMax256(m, sb);
  float s = 0.f;
  for (int i=threadIdx.x;i<NPAD;i+=256) s += __expf(row[i]-m);
  s = blockSum256(s, sb);
  if (threadIdx.x==0){ mx[blockIdx.x]=m; se[blockIdx.x]=s; }
}
__global__ void k_aout(const float* __restrict__ L0, const float* __restrict__ rz,
    const float* __restrict__ mx, const float* __restrict__ se, float* __restrict__ out)
{
  __shared__ float wk[256], mk[256];
  int t = threadIdx.x;
  wk[t] = rz[t]/se[t];
  mk[t] = mx[t];
  __syncthreads();
  int p = blockIdx.x*256 + t;
  if (p >= NTOK) return;
  size_t pp = (size_t)(PADR+1+p);
  float a = 0.f;
  for (int k2=0;k2<256;++k2) a += wk[k2]*__expf(L0[(size_t)k2*NPAD+pp]-mk[k2]);
  out[4+p] = a;
}
__global__ void k_final(const float* __restrict__ H2r, const float* __restrict__ nw,
    const float* __restrict__ nbb, const float* __restrict__ w2, const float* __restrict__ b2,
    float* __restrict__ out)
{
  __shared__ float sb[4];
  __shared__ float hf[512];
  int t = threadIdx.x;
  float x0 = H2r[t], x1 = H2r[256+t];
  float s = blockSum256(x0+x1, sb);
  float q = blockSum256(x0*x0+x1*x1, sb);
  float mean = s*(1.f/512.f);
  float var = q*(1.f/512.f) - mean*mean;
  float rstd = rsqrtf(var+1e-5f);
  hf[t]     = (x0-mean)*rstd*nw[t]+nbb[t];
  hf[256+t] = (x1-mean)*rstd*nw[256+t]+nbb[256+t];
  __syncthreads();
  float p0 = hf[t]*w2[t*2]   + hf[256+t]*w2[(256+t)*2];
  float p1 = hf[t]*w2[t*2+1] + hf[256+t]*w2[(256+t)*2+1];
  p0 = blockSum256(p0, sb);
  p1 = blockSum256(p1, sb);
  if (t==0){
    float l0 = p0+b2[0], l1 = p1+b2[1];
    float m = fmaxf(l0,l1);
    float e0 = __expf(l0-m), e1 = __expf(l1-m), si = 1.f/(e0+e1);
    out[0]=l0; out[1]=l1; out[2]=e0*si; out[3]=e1*si;
  }
}

// ---------------- host orchestration ----------------
struct Bufs {
  float *X,*Y,*QL,*KL,*A2,*Z0,*Z0t,*Z1,*Z1t,*XZ,*XZt,*T1,*T1t,*T2,*T2t;
  float *A3Vt,*sums,*scl,*Pmax,*Psum;
  unsigned short *Qb,*Kb,*Vb,*Vt,*WmT,*Pacc;
};

static void run_pinv(const float* A2, Bufs& b, int NB, hipStream_t st,
                     float** outZ, float** outZt)
{
  dim3 g(4,4,NB);
  float *Zc=b.Z0, *Zct=b.Z0t, *Zn=b.Z1, *Znt=b.Z1t;
  for (int it=0; it<6; ++it){
    k_pgemm<0><<<g,256,0,st>>>(A2, Zct, b.XZ, b.XZt, nullptr, 0.f, 1.f);
    k_pgemm<1><<<g,256,0,st>>>(b.XZ, b.XZt, b.T1, b.T1t, nullptr, 7.f, 1.f);
    k_pgemm<1><<<g,256,0,st>>>(b.XZ, b.T1t, b.T2, b.T2t, nullptr, 15.f, 1.f);
    k_pgemm<1><<<g,256,0,st>>>(Zc, b.T2t, Zn, Znt, nullptr, 13.f, 0.25f);
    float* t1=Zc; Zc=Zn; Zn=t1;
    float* t2=Zct; Zct=Znt; Znt=t2;
  }
  *outZ = Zc; *outZt = Zct;
}

static void nystrom_layer(Bufs& b, const float* lnw, const float* lnb,
    const unsigned short* wqkvT, const unsigned short* woutT,
    const float* bout, const float* resk, hipStream_t st)
{
  k_ln<<<N1,256,0,st>>>(b.X, b.Y, lnw, lnb);
  k_gemm<1><<<dim3(NPAD/128,12),256,0,st>>>(b.Y, wqkvT, nullptr, nullptr, nullptr,
      b.Qb, b.Kb, b.Vb, b.Vt, DIM);
  k_landmark_b<<<NH*MM,64,0,st>>>(b.Qb, b.QL);
  k_landmark_b<<<NH*MM,64,0,st>>>(b.Kb, b.KL);
  k_nt64<<<dim3(4,4,NH),64,0,st>>>(b.QL, b.KL, b.A2,
      (long)MM*DHD,(long)MM*DHD,(long)MM*MM, MM);
  k_softmax256<<<NH*MM,256,0,st>>>(b.A2);
  k_rcsum<<<dim3(NH*MM,2),256,0,st>>>(b.A2, b.sums, NH*MM);
  k_scale<<<1,256,0,st>>>(b.sums, b.scl, NH*MM);
  k_z0<<<NH*MM*MM/256,256,0,st>>>(b.A2, b.Z0, b.Z0t, b.scl);
  float *Zc, *Zct;
  run_pinv(b.A2, b, NH, st, &Zc, &Zct);
  k_attn3<<<dim3(NCH,NH),256,0,st>>>(b.QL, b.Kb, b.Vt, b.Pmax, b.Psum, b.Pacc);
  k_attn3_merge<<<NH*MM,64,0,st>>>(b.Pmax, b.Psum, b.Pacc, b.A3Vt);
  k_pgemm<2><<<dim3(1,4,NH),256,0,st>>>(Zc, b.A3Vt, nullptr, nullptr, b.WmT, 0.f, 1.f);
  k_attn1<<<dim3(NPAD/64,NH),256,0,st>>>(b.Qb, b.KL, b.WmT, b.Y);
  k_seqconv<<<NPAD/SCBLK,256,0,st>>>(b.Vb, resk, b.Y);
  k_gemm<2><<<dim3(176,4),256,0,st>>>(b.Y, woutT, bout, b.X, nullptr,
      nullptr, nullptr, nullptr, nullptr, DIM);
}

extern "C" void kernel_launch(void* const* d_in, const int* in_sizes, int n_in,
                              void* d_out, int out_size, void* d_ws, size_t ws_size,
                              hipStream_t stream)
{
  (void)n_in; (void)out_size;
  bool sig_order = (in_sizes[10] == 25088);
  int iL2 = sig_order ? 16 : 10;
  int iLf = sig_order ? 10 : 16;

  const float* h       = (const float*)d_in[0];
  const float* fc1_w   = (const float*)d_in[1];
  const float* fc1_b   = (const float*)d_in[2];
  const float* cls_tok = (const float*)d_in[3];
  const float* l1_lnw  = (const float*)d_in[4];
  const float* l1_lnb  = (const float*)d_in[5];
  const float* l1_wqkv = (const float*)d_in[6];
  const float* l1_wout = (const float*)d_in[7];
  const float* l1_bout = (const float*)d_in[8];
  const float* l1_resk = (const float*)d_in[9];
  const float* l2_lnw  = (const float*)d_in[iL2+0];
  const float* l2_lnb  = (const float*)d_in[iL2+1];
  const float* l2_wqkv = (const float*)d_in[iL2+2];
  const float* l2_wout = (const float*)d_in[iL2+3];
  const float* l2_bout = (const float*)d_in[iL2+4];
  const float* l2_resk = (const float*)d_in[iL2+5];
  const float* k7 = (const float*)d_in[iLf+0];
  const float* b7 = (const float*)d_in[iLf+1];
  const float* k5 = (const float*)d_in[iLf+2];
  const float* b5 = (const float*)d_in[iLf+3];
  const float* k3 = (const float*)d_in[iLf+4];
  const float* b3 = (const float*)d_in[iLf+5];
  const float* nw = (const float*)d_in[22];
  const float* nbb= (const float*)d_in[23];
  const float* w2 = (const float*)d_in[24];
  const float* b2 = (const float*)d_in[25];
  float* out = (float*)d_out;

  char* base = (char*)d_ws;
  auto allocF = [&](size_t n)->float*{
    float* p=(float*)base; base += ((n*sizeof(float)+255)&~(size_t)255); return p; };
  auto allocU = [&](size_t n)->unsigned short*{
    unsigned short* p=(unsigned short*)base; base += ((n*sizeof(unsigned short)+255)&~(size_t)255); return p; };

  const size_t S = (size_t)NPAD*DIM;
  const size_t SQ = (size_t)MM*MM;   // 65536
  Bufs b;
  b.X  = allocF(S);
  b.Y  = allocF(S);
  b.Qb = allocU(S);
  b.Kb = allocU(S);
  b.Vb = allocU(S);
  b.Vt = allocU(S);
  b.QL = allocF((size_t)NH*MM*DHD);
  b.KL = allocF((size_t)NH*MM*DHD);
  b.A2 = allocF((size_t)NH*SQ);
  b.Z0 = allocF((size_t)NH*SQ);  b.Z0t = allocF((size_t)NH*SQ);
  b.Z1 = allocF((size_t)NH*SQ);  b.Z1t = allocF((size_t)NH*SQ);
  b.XZ = allocF((size_t)NH*SQ);  b.XZt = allocF((size_t)NH*SQ);
  b.T1 = allocF((size_t)NH*SQ);  b.T1t = allocF((size_t)NH*SQ);
  b.T2 = allocF((size_t)NH*SQ);  b.T2t = allocF((size_t)NH*SQ);
  b.A3Vt = allocF((size_t)NH*MM*DHD);
  b.WmT  = allocU((size_t)NH*MM*DHD);
  b.sums = allocF(2*(size_t)NH*MM);
  b.scl  = allocF(16);
  b.Pmax = allocF((size_t)NH*NCH*MM);
  b.Psum = allocF((size_t)NH*NCH*MM);
  b.Pacc = allocU((size_t)NH*NCH*MM*DHD);
  unsigned short* fc1T   = allocU((size_t)DIM*1024);
  unsigned short* wqkvT1 = allocU((size_t)1536*DIM);
  unsigned short* wqkvT2 = allocU((size_t)1536*DIM);
  unsigned short* woutT1 = allocU((size_t)DIM*DIM);
  unsigned short* woutT2 = allocU((size_t)DIM*DIM);
  float* Q0   = allocF((size_t)NPAD*DHD);
  float* K0   = allocF((size_t)NPAD*DHD);
  float* row1 = allocF(256);
  float* rzv  = allocF(256);
  float* mxv  = allocF(256);
  float* sev  = allocF(256);
  float* h2row= allocF(512);
  if ((size_t)(base - (char*)d_ws) > ws_size) return;

  // weight transposes (fp32 -> bf16 [N][K])
  k_wT<<<dim3(32,16),256,0,stream>>>(fc1_w, fc1T, 1024, DIM);
  k_wT<<<dim3(16,48),256,0,stream>>>(l1_wqkv, wqkvT1, DIM, 1536);
  k_wT<<<dim3(16,48),256,0,stream>>>(l2_wqkv, wqkvT2, DIM, 1536);
  k_wT<<<dim3(16,16),256,0,stream>>>(l1_wout, woutT1, DIM, DIM);
  k_wT<<<dim3(16,16),256,0,stream>>>(l2_wout, woutT2, DIM, DIM);

  // stage 0: fc1 + cls token
  k_gemm<0><<<dim3(176,4),256,0,stream>>>(h, fc1T, fc1_b, b.X, nullptr,
      nullptr, nullptr, nullptr, nullptr, 1024);
  k_setcls<<<2,256,0,stream>>>(b.X, cls_tok);

  // layer 1 + LeFF
  nystrom_layer(b, l1_lnw, l1_lnb, wqkvT1, woutT1, l1_bout, l1_resk, stream);
  k_tfwd<<<dim3(704,16),256,0,stream>>>(b.X, b.Y);
  k_leff<<<dim3(100,512),256,0,stream>>>(b.Y, k7,b7,k5,b5,k3,b3, (float*)b.Z0);
  k_tbwd<<<dim3(704,16),256,0,stream>>>((float*)b.Z0, b.X);

  // layer 2 (save h2 row 0 for the head)
  nystrom_layer(b, l2_lnw, l2_lnb, wqkvT2, woutT2, l2_bout, l2_resk, stream);
  k_copy<<<2,256,0,stream>>>(h2row, b.X, 512);

  // layer 3 -> h3
  nystrom_layer(b, l2_lnw, l2_lnb, wqkvT2, woutT2, l2_bout, l2_resk, stream);

  // cls-row stage (head 0, l2 weights, LN(h3))
  k_ln<<<N1,256,0,stream>>>(b.X, b.Y, l2_lnw, l2_lnb);
  k_gemm<3><<<dim3(176,1),256,0,stream>>>(b.Y, wqkvT2, nullptr, Q0, K0,
      nullptr, nullptr, nullptr, nullptr, DIM);
  k_landmark<<<MM,64,0,stream>>>(Q0, b.QL);
  k_landmark<<<MM,64,0,stream>>>(K0, b.KL);
  k_nt64<<<dim3(4,4,1),64,0,stream>>>(b.QL, b.KL, b.A2, 0,0,0, MM);
  k_softmax256<<<MM,256,0,stream>>>(b.A2);
  k_rcsum<<<dim3(MM,2),256,0,stream>>>(b.A2, b.sums, MM);
  k_scale<<<1,256,0,stream>>>(b.sums, b.scl, MM);
  k_z0<<<MM*MM/256,256,0,stream>>>(b.A2, b.Z0, b.Z0t, b.scl);
  float *Zc, *Zct;
  run_pinv(b.A2, b, 1, stream, &Zc, &Zct);
  k_row1<<<1,256,0,stream>>>(Q0, b.KL, row1);
  k_rz<<<1,256,0,stream>>>(row1, Zct, rzv);
  // L0 = QL0 @ K0^T (256 x NPAD), into Y
  k_nt64<<<dim3(NPAD/64,4,1),64,0,stream>>>(b.QL, K0, b.Y, 0,0,0, NPAD);
  k_rowstat<<<MM,256,0,stream>>>(b.Y, mxv, sev);
  k_aout<<<88,256,0,stream>>>(b.Y, rzv, mxv, sev, out);
  k_final<<<1,256,0,stream>>>(h2row, nw, nbb, w2, b2, out);
}

// Round 5
// 2640.482 us; speedup vs baseline: 3.4398x; 1.0379x over previous
//
#include <hip/hip_runtime.h>

#define NTOK 22500
#define N1   22501
#define NPAD 22528
#define PADR 27
#define DIM  512
#define NH   8
#define DHD  64
#define MM   256
#define LLM  88
#define HSZ  150
#define CSZ  256
#define NCH  88   // NPAD / CSZ

typedef short bf16x8 __attribute__((ext_vector_type(8)));
typedef float f32x4  __attribute__((ext_vector_type(4)));
typedef unsigned short us;

union U8 { bf16x8 v; unsigned short u[8]; };

__device__ __forceinline__ unsigned short f2b(float f){
  unsigned int u = __float_as_uint(f);
  unsigned int r = u + 0x7fffu + ((u>>16)&1u);
  return (unsigned short)(r>>16);
}
__device__ __forceinline__ float bf2f(unsigned short u){
  return __uint_as_float(((unsigned int)u)<<16);
}
__device__ __forceinline__ bf16x8 cvt8(float4 a, float4 b){
  U8 u;
  u.u[0]=f2b(a.x); u.u[1]=f2b(a.y); u.u[2]=f2b(a.z); u.u[3]=f2b(a.w);
  u.u[4]=f2b(b.x); u.u[5]=f2b(b.y); u.u[6]=f2b(b.z); u.u[7]=f2b(b.w);
  return u.v;
}

// ---------------- reduction helpers ----------------
__device__ __forceinline__ float waveSum(float v){
#pragma unroll
  for (int o=32;o>0;o>>=1) v += __shfl_down(v,o);
  return v;
}
__device__ __forceinline__ float waveMax(float v){
#pragma unroll
  for (int o=32;o>0;o>>=1) v = fmaxf(v,__shfl_down(v,o));
  return v;
}
__device__ __forceinline__ float blockSum256(float v, float* sb){
  v = waveSum(v);
  __syncthreads();
  if ((threadIdx.x&63)==0) sb[threadIdx.x>>6]=v;
  __syncthreads();
  return sb[0]+sb[1]+sb[2]+sb[3];
}
__device__ __forceinline__ float blockMax256(float v, float* sb){
  v = waveMax(v);
  __syncthreads();
  if ((threadIdx.x&63)==0) sb[threadIdx.x>>6]=v;
  __syncthreads();
  return fmaxf(fmaxf(sb[0],sb[1]),fmaxf(sb[2],sb[3]));
}

// ---------------- weight transpose+cvt: W fp32 [K][N] -> Bt bf16 [N][K] ----------------
__global__ void k_wT(const float* __restrict__ W, us* __restrict__ Bt, int K, int N)
{
  __shared__ float tile[32][33];
  int tx = threadIdx.x&31, ty = threadIdx.x>>5;
  int k0 = blockIdx.x*32, n0 = blockIdx.y*32;
#pragma unroll
  for (int i=0;i<4;++i){
    int k = k0+ty+i*8;
    if (k<K && n0+tx<N) tile[ty+i*8][tx] = W[(size_t)k*N + n0+tx];
  }
  __syncthreads();
#pragma unroll
  for (int i=0;i<4;++i){
    int n = n0+ty+i*8, k = k0+tx;
    if (n<N && k<K) Bt[(size_t)n*K + k] = f2b(tile[tx][ty+i*8]);
  }
}

// ---------------- V transpose: Vb [h][p][d] -> Vtb [h][d][p] (bf16, coalesced) ----------------
__global__ void k_vT(const us* __restrict__ V, us* __restrict__ Vt)
{
  __shared__ us tile[32][33];
  int tx = threadIdx.x&31, ty = threadIdx.x>>5;
  int p0 = blockIdx.x*32;
  int h = blockIdx.y>>1, d0 = (blockIdx.y&1)*32;
#pragma unroll
  for (int i=0;i<4;++i){
    int p = p0+ty+i*8;
    tile[ty+i*8][tx] = V[((size_t)h*NPAD+p)*DHD + d0+tx];
  }
  __syncthreads();
#pragma unroll
  for (int i=0;i<4;++i){
    int d = d0+ty+i*8;
    Vt[((size_t)h*DHD+d)*NPAD + p0+tx] = tile[tx][ty+i*8];
  }
}

// ---------------- MFMA GEMM (128x128 tile) ----------------
// MODE 0: fc1 (A fp32)   MODE 1: qkv (A=Yb bf16, LDS-relayout epilogue)
// MODE 2: wout (A=OHb bf16, +=)   MODE 3: qk0 (A=Yb bf16)
template<int MODE>
__global__ __launch_bounds__(256) void k_gemm(const float* __restrict__ Af,
    const us* __restrict__ Ab, const us* __restrict__ Bt, const float* __restrict__ bias,
    float* __restrict__ Cf, float* __restrict__ C2,
    us* __restrict__ Q_, us* __restrict__ K_, us* __restrict__ V_, int Kd)
{
  __shared__ us SM[16384];     // As = SM[0..8191], Bs = SM[8192..16383]
  us* As = SM;
  us* Bs = SM + 8192;
  const int tid = threadIdx.x;
  const int m0 = blockIdx.x*128, n0 = blockIdx.y*128;
  const int lane = tid & 63;
  const int wid = tid >> 6;
  const int wm = (wid>>1)*64, wn = (wid&1)*64;
  f32x4 acc[4][4] = {};
  for (int k0=0; k0<Kd; k0+=64){
    __syncthreads();
#pragma unroll
    for (int i=0;i<8;++i){
      int g = i*256 + tid;
      int row = g>>4, k4 = (g&15)*4;
      int gm = m0 + row;
      ushort4 h4 = make_ushort4(0,0,0,0);
      if (MODE==0){
        if (gm < NTOK){
          float4 v = *(const float4*)(Af + (size_t)gm*Kd + k0 + k4);
          h4.x=f2b(v.x); h4.y=f2b(v.y); h4.z=f2b(v.z); h4.w=f2b(v.w);
        }
      } else if (MODE==1 || MODE==3){
        if (gm >= PADR) h4 = *(const ushort4*)(Ab + (size_t)(gm-PADR)*Kd + k0 + k4);
      } else {
        if (gm < N1) h4 = *(const ushort4*)(Ab + (size_t)(gm+PADR)*Kd + k0 + k4);
      }
      *(ushort4*)(&As[row*64 + (k4 ^ ((row&7)<<3))]) = h4;
    }
#pragma unroll
    for (int i=0;i<8;++i){
      int g = i*256 + tid;
      int col = g>>4, k4 = (g&15)*4;
      int vn = n0 + col;
      if (MODE==3) vn = (vn<64) ? vn : vn+448;
      ushort4 h4 = *(const ushort4*)(Bt + (size_t)vn*Kd + k0 + k4);
      *(ushort4*)(&Bs[col*64 + (k4 ^ ((col&7)<<3))]) = h4;
    }
    __syncthreads();
#pragma unroll
    for (int ks=0; ks<2; ++ks){
      const int kk = ks*32 + (lane>>4)*8;
      bf16x8 af[4], bfm[4];
#pragma unroll
      for (int t=0;t<4;++t){
        int r = wm + t*16 + (lane&15);
        af[t] = *(bf16x8*)(&As[r*64 + (kk ^ ((r&7)<<3))]);
        int c = wn + t*16 + (lane&15);
        bfm[t] = *(bf16x8*)(&Bs[c*64 + (kk ^ ((c&7)<<3))]);
      }
#pragma unroll
      for (int mt=0;mt<4;++mt)
#pragma unroll
        for (int nt=0;nt<4;++nt)
          acc[mt][nt] = __builtin_amdgcn_mfma_f32_16x16x32_bf16(af[mt], bfm[nt], acc[mt][nt], 0,0,0);
    }
  }
  const int rbase = (lane>>4)*4;
  const int cl = lane&15;
  if (MODE==1){
    const int sec = blockIdx.y>>2;
    const float sc = sec==0 ? 0.125f : 1.f;
    __syncthreads();
#pragma unroll
    for (int mt=0;mt<4;++mt)
#pragma unroll
      for (int r=0;r<4;++r){
        int row = wm + mt*16 + rbase + r;
#pragma unroll
        for (int nt=0;nt<4;++nt){
          int col = wn + nt*16 + cl;
          SM[row*128 + col] = f2b(acc[mt][nt][r]*sc);
        }
      }
    __syncthreads();
    us* dst = sec==0 ? Q_ : (sec==1 ? K_ : V_);
#pragma unroll
    for (int i=0;i<8;++i){
      int v8 = i*256 + tid;
      int row = v8>>4, c8 = (v8&15)*8;
      int gm = m0 + row, gn = n0 + c8;
      int hh = (gn>>6)&7, d = gn&63;
      *(bf16x8*)(dst + ((size_t)hh*NPAD+gm)*DHD + d) = *(bf16x8*)(&SM[row*128 + c8]);
    }
  } else {
#pragma unroll
    for (int mt=0;mt<4;++mt){
#pragma unroll
      for (int r=0;r<4;++r){
        int gm = m0 + wm + mt*16 + rbase + r;
#pragma unroll
        for (int nt=0;nt<4;++nt){
          int gn = n0 + wn + nt*16 + cl;
          float v = acc[mt][nt][r];
          if (MODE==0){
            if (gm < NTOK){ float o = v + bias[gn]; Cf[(size_t)(1+gm)*DIM + gn] = o>0.f?o:0.f; }
          } else if (MODE==2){
            if (gm < N1) Cf[(size_t)gm*DIM + gn] += v + bias[gn];
          } else {
            if (gn < 64) Cf[(size_t)gm*DHD + gn] = v*0.125f;
            else         C2[(size_t)gm*DHD + (gn-64)] = v;
          }
        }
      }
    }
  }
}

__global__ void k_setcls(float* __restrict__ X, const float* __restrict__ cls){
  int i = blockIdx.x*256 + threadIdx.x;
  if (i < DIM) X[i] = cls[i];
}
__global__ void k_copy(float* __restrict__ d, const float* __restrict__ s, size_t n){
  size_t i = (size_t)blockIdx.x*256 + threadIdx.x;
  if (i<n) d[i]=s[i];
}

// ---------------- layernorm: fp32 in -> bf16 out ----------------
__global__ void k_ln(const float* __restrict__ X, us* __restrict__ Y,
                     const float* __restrict__ w, const float* __restrict__ b)
{
  __shared__ float sb[4];
  const float* x = X + (size_t)blockIdx.x*DIM;
  us* y = Y + (size_t)blockIdx.x*DIM;
  int t = threadIdx.x;
  float a0=x[t], a1=x[t+256];
  float s = blockSum256(a0+a1, sb);
  float q = blockSum256(a0*a0+a1*a1, sb);
  float mean = s*(1.f/512.f);
  float var = q*(1.f/512.f) - mean*mean;
  float rstd = rsqrtf(var+1e-5f);
  y[t]     = f2b((a0-mean)*rstd*w[t]+b[t]);
  y[t+256] = f2b((a1-mean)*rstd*w[t+256]+b[t+256]);
}

// ---------------- landmarks ----------------
__global__ void k_landmark_b(const us* __restrict__ src, us* __restrict__ dst)
{
  int hm = blockIdx.x; int h = hm>>8, m = hm&255; int d = threadIdx.x;
  const us* base = src + ((size_t)h*NPAD + (size_t)m*LLM)*DHD + d;
  float s = 0.f;
  for (int j=0;j<LLM;++j) s += bf2f(base[(size_t)j*DHD]);
  dst[((size_t)h*MM + m)*DHD + d] = f2b(s * (1.f/(float)LLM));
}
__global__ void k_landmark(const float* __restrict__ src, float* __restrict__ dst)
{
  int hm = blockIdx.x; int h = hm>>8, m = hm&255; int d = threadIdx.x;
  const float* base = src + ((size_t)h*NPAD + (size_t)m*LLM)*DHD + d;
  float s = 0.f;
  for (int j=0;j<LLM;++j) s += base[(size_t)j*DHD];
  dst[((size_t)h*MM + m)*DHD + d] = s * (1.f/(float)LLM);
}

// ---------------- MFMA NT gemm K=64, fp32 inputs ----------------
__global__ __launch_bounds__(64) void k_nt64(const float* __restrict__ A,
    const float* __restrict__ B, float* __restrict__ C,
    long sA, long sB, long sC, int Nr)
{
  int lane = threadIdx.x;
  int n0 = blockIdx.x*64, m0 = blockIdx.y*64;
  A += (size_t)blockIdx.z*sA; B += (size_t)blockIdx.z*sB; C += (size_t)blockIdx.z*sC;
  f32x4 acc[4][4] = {};
#pragma unroll
  for (int ks=0;ks<2;++ks){
    int kk = ks*32 + (lane>>4)*8;
    bf16x8 af[4], bfr[4];
#pragma unroll
    for (int mt=0;mt<4;++mt){
      const float* p = A + (size_t)(m0+mt*16+(lane&15))*64 + kk;
      af[mt] = cvt8(*(const float4*)p, *(const float4*)(p+4));
    }
#pragma unroll
    for (int nt=0;nt<4;++nt){
      const float* p = B + (size_t)(n0+nt*16+(lane&15))*64 + kk;
      bfr[nt] = cvt8(*(const float4*)p, *(const float4*)(p+4));
    }
#pragma unroll
    for (int mt=0;mt<4;++mt)
#pragma unroll
      for (int nt=0;nt<4;++nt)
        acc[mt][nt] = __builtin_amdgcn_mfma_f32_16x16x32_bf16(af[mt], bfr[nt], acc[mt][nt], 0,0,0);
  }
#pragma unroll
  for (int mt=0;mt<4;++mt)
#pragma unroll
    for (int r=0;r<4;++r){
      int row = m0+mt*16+(lane>>4)*4+r;
#pragma unroll
      for (int nt=0;nt<4;++nt){
        int col = n0+nt*16+(lane&15);
        C[(size_t)row*Nr + col] = acc[mt][nt][r];
      }
    }
}

// ---------------- MFMA NT gemm K=64, bf16 inputs (attn2 logits) ----------------
__global__ __launch_bounds__(64) void k_nt64b(const us* __restrict__ A,
    const us* __restrict__ B, float* __restrict__ C,
    long sA, long sB, long sC, int Nr)
{
  int lane = threadIdx.x;
  int n0 = blockIdx.x*64, m0 = blockIdx.y*64;
  A += (size_t)blockIdx.z*sA; B += (size_t)blockIdx.z*sB; C += (size_t)blockIdx.z*sC;
  f32x4 acc[4][4] = {};
#pragma unroll
  for (int ks=0;ks<2;++ks){
    int kk = ks*32 + (lane>>4)*8;
    bf16x8 af[4], bfr[4];
#pragma unroll
    for (int mt=0;mt<4;++mt)
      af[mt] = *(const bf16x8*)(A + (size_t)(m0+mt*16+(lane&15))*64 + kk);
#pragma unroll
    for (int nt=0;nt<4;++nt)
      bfr[nt] = *(const bf16x8*)(B + (size_t)(n0+nt*16+(lane&15))*64 + kk);
#pragma unroll
    for (int mt=0;mt<4;++mt)
#pragma unroll
      for (int nt=0;nt<4;++nt)
        acc[mt][nt] = __builtin_amdgcn_mfma_f32_16x16x32_bf16(af[mt], bfr[nt], acc[mt][nt], 0,0,0);
  }
#pragma unroll
  for (int mt=0;mt<4;++mt)
#pragma unroll
    for (int r=0;r<4;++r){
      int row = m0+mt*16+(lane>>4)*4+r;
#pragma unroll
      for (int nt=0;nt<4;++nt){
        int col = n0+nt*16+(lane&15);
        C[(size_t)row*Nr + col] = acc[mt][nt][r];
      }
    }
}

// ---------------- pinv MFMA gemm, all-bf16 ----------------
// PM 0: C=A@B (write C+Ct)   PM 1: C=alpha*(dc*A - A@B) (write Ct, C if writeC)
// PM 2: Wm^T only (N=64)
template<int PM>
__global__ __launch_bounds__(256) void k_pgemm(const us* __restrict__ A,
    const us* __restrict__ Bt, us* __restrict__ C, us* __restrict__ Ct,
    float dc, float alpha, int writeC)
{
  __shared__ us As[64*256];
  __shared__ us Bs[64*256];
  const int tid = threadIdx.x, lane = tid&63, wid = tid>>6;
  const int n0 = blockIdx.x*64, m0 = blockIdx.y*64;
  const us* Ab = A + (size_t)blockIdx.z*65536;
  const us* Bb = Bt + (size_t)blockIdx.z*(PM==2?16384:65536);
  for (int i=tid; i<4096; i+=256){
    int r = i>>6, c4 = (i&63)*4;
    *(ushort4*)(&As[r*256 + (c4 ^ ((r&7)<<3))]) = *(const ushort4*)(Ab + (size_t)(m0+r)*256 + c4);
    *(ushort4*)(&Bs[r*256 + (c4 ^ ((r&7)<<3))]) = *(const ushort4*)(Bb + (size_t)(n0+r)*256 + c4);
  }
  __syncthreads();
  const int wm = (wid>>1)*32, wn = (wid&1)*32;
  f32x4 acc[2][2] = {};
#pragma unroll
  for (int ks=0;ks<8;++ks){
    int kk = ks*32 + (lane>>4)*8;
    bf16x8 af[2], bfr[2];
#pragma unroll
    for (int t=0;t<2;++t){
      int rr = wm + t*16 + (lane&15);
      af[t] = *(const bf16x8*)(&As[rr*256 + (kk ^ ((rr&7)<<3))]);
      int cc = wn + t*16 + (lane&15);
      bfr[t] = *(const bf16x8*)(&Bs[cc*256 + (kk ^ ((cc&7)<<3))]);
    }
#pragma unroll
    for (int mt=0;mt<2;++mt)
#pragma unroll
      for (int nt=0;nt<2;++nt)
        acc[mt][nt] = __builtin_amdgcn_mfma_f32_16x16x32_bf16(af[mt], bfr[nt], acc[mt][nt], 0,0,0);
  }
#pragma unroll
  for (int mt=0;mt<2;++mt)
#pragma unroll
    for (int r=0;r<4;++r){
      int row = m0 + wm + mt*16 + (lane>>4)*4 + r;
#pragma unroll
      for (int nt=0;nt<2;++nt){
        int col = n0 + wn + nt*16 + (lane&15);
        float v = acc[mt][nt][r];
        if (PM==1) v = alpha*(dc*bf2f(Ab[(size_t)row*256+col]) - v);
        if (PM==2){
          Ct[(size_t)blockIdx.z*16384 + (size_t)col*256 + row] = f2b(v);
        } else {
          us bv = f2b(v);
          if (PM==0 || writeC) C[(size_t)blockIdx.z*65536 + (size_t)row*256 + col] = bv;
          Ct[(size_t)blockIdx.z*65536 + (size_t)col*256 + row] = bv;
        }
      }
    }
}

// ---------------- small elementwise ----------------
__global__ void k_softmax256(float* __restrict__ S, us* __restrict__ Sb)
{
  __shared__ float sb[4];
  float* row = S + ((size_t)blockIdx.x<<8);
  float x = row[threadIdx.x];
  float m = blockMax256(x, sb);
  float e = __expf(x-m);
  float s = blockSum256(e, sb);
  float p = e/s;
  row[threadIdx.x] = p;
  Sb[((size_t)blockIdx.x<<8) + threadIdx.x] = f2b(p);
}
__global__ void k_rcsum(const float* __restrict__ A2, float* __restrict__ sums, int nb)
{
  __shared__ float sb[4];
  int b = blockIdx.x >> 8, r = blockIdx.x & 255;
  const float* Ab = A2 + ((size_t)b<<16);
  float v = (blockIdx.y==0) ? Ab[((size_t)r<<8) + threadIdx.x]
                            : Ab[((size_t)threadIdx.x<<8) + r];
  float s = blockSum256(v, sb);
  if (threadIdx.x==0) sums[(size_t)blockIdx.y*nb + blockIdx.x] = s;
}
__global__ void k_scale(const float* __restrict__ sums, float* __restrict__ scl, int nb)
{
  __shared__ float sb[4];
  float mr=-1e30f, mc=-1e30f;
  for (int i=threadIdx.x;i<nb;i+=256) mr = fmaxf(mr, sums[i]);
  for (int i=threadIdx.x;i<nb;i+=256) mc = fmaxf(mc, sums[nb+i]);
  mr = blockMax256(mr, sb);
  mc = blockMax256(mc, sb);
  if (threadIdx.x==0) scl[0] = 1.f/(mr*mc);
}
__global__ void k_z0(const float* __restrict__ A2, us* __restrict__ Z, us* __restrict__ Zt,
                     const float* __restrict__ scl)
{
  size_t idx = (size_t)blockIdx.x*256 + threadIdx.x;
  size_t b = idx>>16; int i=(int)((idx>>8)&255), j=(int)(idx&255);
  float v = A2[idx]*scl[0];
  us bv = f2b(v);
  Zt[idx] = bv;                              // Z^T (row-major of A2)
  Z[(b<<16)+((size_t)j<<8)+i] = bv;          // Z = A2^T * s
}

// ---------------- attn3: MFMA flash ----------------
__global__ __launch_bounds__(256) void k_attn3(const us* __restrict__ QLb,
    const us* __restrict__ Kb, const us* __restrict__ Vt,
    float* __restrict__ Pmax, float* __restrict__ Psum, us* __restrict__ Pacc)
{
  __shared__ us Ks[64*64];
  __shared__ us Vs[64*64];
  __shared__ us Ps[4*64*64];
  int h = blockIdx.y, cx = blockIdx.x;
  int tid = threadIdx.x, wid = tid>>6, lane = tid&63;
  bf16x8 aq[4][2];
#pragma unroll
  for (int mt=0;mt<4;++mt){
    const us* qp = QLb + ((size_t)h*MM + wid*64 + mt*16 + (lane&15))*DHD;
#pragma unroll
    for (int ks=0;ks<2;++ks)
      aq[mt][ks] = *(const bf16x8*)(qp + ks*32 + (lane>>4)*8);
  }
  float m_[4][4], l_[4][4];
  f32x4 acc[4][4] = {};
#pragma unroll
  for (int mt=0;mt<4;++mt)
#pragma unroll
    for (int r=0;r<4;++r){ m_[mt][r] = -1e30f; l_[mt][r] = 0.f; }

  us* Pw = &Ps[wid*4096];
  for (int t=0;t<4;++t){
    int kb0 = cx*CSZ + t*64;
    __syncthreads();
    for (int i=tid;i<1024;i+=256){
      int rr = i>>4, c4 = (i&15)*4;
      ushort4 ku = *(const ushort4*)(Kb + ((size_t)h*NPAD + kb0 + rr)*DHD + c4);
      *(ushort4*)(&Ks[rr*64 + (c4 ^ ((rr&7)<<3))]) = ku;
      ushort4 vu = *(const ushort4*)(Vt + ((size_t)h*DHD + rr)*NPAD + kb0 + c4);
      *(ushort4*)(&Vs[rr*64 + (c4 ^ ((rr&7)<<3))]) = vu;
    }
    __syncthreads();
    f32x4 s[4][4] = {};
#pragma unroll
    for (int ks=0;ks<2;++ks){
      int kk = ks*32 + (lane>>4)*8;
      bf16x8 kbf[4];
#pragma unroll
      for (int nt=0;nt<4;++nt){
        int key = nt*16 + (lane&15);
        kbf[nt] = *(const bf16x8*)(&Ks[key*64 + (kk ^ ((key&7)<<3))]);
      }
#pragma unroll
      for (int mt=0;mt<4;++mt)
#pragma unroll
        for (int nt=0;nt<4;++nt)
          s[mt][nt] = __builtin_amdgcn_mfma_f32_16x16x32_bf16(aq[mt][ks], kbf[nt], s[mt][nt], 0,0,0);
    }
#pragma unroll
    for (int mt=0;mt<4;++mt){
#pragma unroll
      for (int r=0;r<4;++r){
        float mx = fmaxf(fmaxf(s[mt][0][r], s[mt][1][r]), fmaxf(s[mt][2][r], s[mt][3][r]));
#pragma unroll
        for (int off=8;off>=1;off>>=1) mx = fmaxf(mx, __shfl_xor(mx, off));
        float mn = fmaxf(m_[mt][r], mx);
        float f = __expf(m_[mt][r]-mn);
        float la = 0.f;
#pragma unroll
        for (int nt=0;nt<4;++nt){ float p=__expf(s[mt][nt][r]-mn); s[mt][nt][r]=p; la+=p; }
#pragma unroll
        for (int off=8;off>=1;off>>=1) la += __shfl_xor(la, off);
        l_[mt][r] = l_[mt][r]*f + la;
        m_[mt][r] = mn;
#pragma unroll
        for (int dt=0;dt<4;++dt) acc[mt][dt][r] *= f;
      }
    }
#pragma unroll
    for (int mt=0;mt<4;++mt)
#pragma unroll
      for (int r=0;r<4;++r){
        int row = mt*16 + (lane>>4)*4 + r;
        int sw = (row&7)<<3;
#pragma unroll
        for (int nt=0;nt<4;++nt){
          int col = nt*16 + (lane&15);
          Pw[row*64 + (col ^ sw)] = f2b(s[mt][nt][r]);
        }
      }
#pragma unroll
    for (int ks=0;ks<2;++ks){
      int kk = ks*32 + (lane>>4)*8;
      bf16x8 pa[4], vb[4];
#pragma unroll
      for (int mt=0;mt<4;++mt){
        int arow = mt*16 + (lane&15);
        pa[mt] = *(const bf16x8*)(&Pw[arow*64 + (kk ^ ((arow&7)<<3))]);
      }
#pragma unroll
      for (int dt=0;dt<4;++dt){
        int d = dt*16 + (lane&15);
        vb[dt] = *(const bf16x8*)(&Vs[d*64 + (kk ^ ((d&7)<<3))]);
      }
#pragma unroll
      for (int mt=0;mt<4;++mt)
#pragma unroll
        for (int dt=0;dt<4;++dt)
          acc[mt][dt] = __builtin_amdgcn_mfma_f32_16x16x32_bf16(pa[mt], vb[dt], acc[mt][dt], 0,0,0);
    }
  }
  size_t pbase = ((size_t)h*NCH + cx)*MM;
#pragma unroll
  for (int mt=0;mt<4;++mt)
#pragma unroll
    for (int r=0;r<4;++r){
      int row = wid*64 + mt*16 + (lane>>4)*4 + r;
      if ((lane&15)==0){ Pmax[pbase+row]=m_[mt][r]; Psum[pbase+row]=l_[mt][r]; }
#pragma unroll
      for (int dt=0;dt<4;++dt)
        Pacc[(pbase+row)*DHD + dt*16+(lane&15)] = f2b(acc[mt][dt][r]);
    }
}

__global__ void k_attn3_merge(const float* __restrict__ Pmax, const float* __restrict__ Psum,
    const us* __restrict__ Pacc, us* __restrict__ A3Vtb)
{
  int hm = blockIdx.x; int h = hm>>8, m = hm&255; int d = threadIdx.x;
  float gm = -1e30f;
  for (int c=0;c<NCH;++c) gm = fmaxf(gm, Pmax[((size_t)h*NCH+c)*MM+m]);
  float tot=0.f, acc=0.f;
  for (int c=0;c<NCH;++c){
    size_t pi = ((size_t)h*NCH+c)*MM+m;
    float w = __expf(Pmax[pi]-gm);
    tot += Psum[pi]*w;
    acc += bf2f(Pacc[pi*DHD+d])*w;
  }
  A3Vtb[((size_t)h*DHD + d)*MM + m] = f2b(acc/tot);
}

// ---------------- attn1: MFMA, exact softmax over 256 landmarks ----------------
__global__ __launch_bounds__(256) void k_attn1(const us* __restrict__ Qb,
    const us* __restrict__ KLb, const us* __restrict__ WmT,
    us* __restrict__ OH)
{
  __shared__ us KWs[64*256];
  __shared__ us Ps[64*256];
  int h = blockIdx.y, tid = threadIdx.x;
  int wid = tid>>6, lane = tid&63;
  int q0 = blockIdx.x*64;
  for (int i=tid; i<4096; i+=256){
    int lm = i>>4, k4 = (i&15)*4;
    *(ushort4*)(&KWs[lm*64 + (k4 ^ ((lm&7)<<3))]) =
        *(const ushort4*)(KLb + ((size_t)h*MM + lm)*DHD + k4);
  }
  bf16x8 aq[2];
  const us* qp = Qb + ((size_t)h*NPAD + q0 + wid*16 + (lane&15))*DHD;
#pragma unroll
  for (int ks=0;ks<2;++ks)
    aq[ks] = *(const bf16x8*)(qp + ks*32 + (lane>>4)*8);
  __syncthreads();
  f32x4 s[16];
#pragma unroll
  for (int nt=0;nt<16;++nt) s[nt] = (f32x4){0.f,0.f,0.f,0.f};
#pragma unroll
  for (int ks=0;ks<2;++ks){
    int kk = ks*32 + (lane>>4)*8;
#pragma unroll
    for (int nt=0;nt<16;++nt){
      int col = nt*16 + (lane&15);
      bf16x8 b = *(const bf16x8*)(&KWs[col*64 + (kk ^ ((col&7)<<3))]);
      s[nt] = __builtin_amdgcn_mfma_f32_16x16x32_bf16(aq[ks], b, s[nt], 0,0,0);
    }
  }
  float rcp[4];
#pragma unroll
  for (int r=0;r<4;++r){
    float m = -1e30f;
#pragma unroll
    for (int nt=0;nt<16;++nt) m = fmaxf(m, s[nt][r]);
#pragma unroll
    for (int off=8;off>=1;off>>=1) m = fmaxf(m, __shfl_xor(m, off));
    float l = 0.f;
#pragma unroll
    for (int nt=0;nt<16;++nt){ float p=__expf(s[nt][r]-m); s[nt][r]=p; l+=p; }
#pragma unroll
    for (int off=8;off>=1;off>>=1) l += __shfl_xor(l, off);
    rcp[r] = 1.f/l;
  }
  int prow_base = wid*16 + (lane>>4)*4;
#pragma unroll
  for (int nt=0;nt<16;++nt){
    int col = nt*16 + (lane&15);
#pragma unroll
    for (int r=0;r<4;++r){
      int row = prow_base + r;
      Ps[row*256 + (col ^ ((row&7)<<3))] = f2b(s[nt][r]);
    }
  }
  __syncthreads();
  for (int i=tid; i<4096; i+=256){
    int d = i>>6, k4 = (i&63)*4;
    ushort4 u = *(const ushort4*)(WmT + ((size_t)h*DHD + d)*MM + k4);
    *(ushort4*)(&KWs[d*256 + (k4 ^ ((d&7)<<3))]) = u;
  }
  __syncthreads();
  f32x4 acc[4] = {};
  int arow = wid*16 + (lane&15);
#pragma unroll
  for (int ks=0;ks<8;++ks){
    int kk = ks*32 + (lane>>4)*8;
    bf16x8 a = *(const bf16x8*)(&Ps[arow*256 + (kk ^ ((arow&7)<<3))]);
#pragma unroll
    for (int dt=0;dt<4;++dt){
      int d = dt*16 + (lane&15);
      bf16x8 b = *(const bf16x8*)(&KWs[d*256 + (kk ^ ((d&7)<<3))]);
      acc[dt] = __builtin_amdgcn_mfma_f32_16x16x32_bf16(a, b, acc[dt], 0,0,0);
    }
  }
#pragma unroll
  for (int r=0;r<4;++r){
    int row = q0 + prow_base + r;
    us* op = OH + (size_t)row*DIM + h*DHD;
#pragma unroll
    for (int dt=0;dt<4;++dt)
      op[dt*16 + (lane&15)] = f2b(acc[dt][r]*rcp[r]);
  }
}

// ---------------- depthwise conv along seq, bf16 RMW ----------------
#define SCBLK 32
__global__ __launch_bounds__(256) void k_seqconv(const us* __restrict__ Vb,
    const float* __restrict__ resk, us* __restrict__ OH)
{
  __shared__ us Vs[64*512];
  int tid = threadIdx.x;
  int p0 = blockIdx.x*SCBLK;
  for (int i=tid; i<16384; i+=256){
    int pl = i>>8, c2 = i&255;
    int gp = p0 - 16 + pl;
    int hh = c2>>5, d2 = (c2&31)*2;
    ushort2 v = make_ushort2(0,0);
    if (gp>=0 && gp<NPAD) v = *(const ushort2*)(Vb + ((size_t)hh*NPAD+gp)*DHD + d2);
    *(ushort2*)(&Vs[pl*512 + c2*2]) = v;
  }
  __syncthreads();
  int h = tid>>5;
  float kr[33];
#pragma unroll
  for (int r=0;r<33;++r) kr[r] = resk[h*33+r];
  for (int pl=0; pl<SCBLK; ++pl){
    float s0=0.f, s1=0.f;
#pragma unroll
    for (int r=0;r<33;++r){
      ushort2 v = *(const ushort2*)(&Vs[(pl+r)*512 + tid*2]);
      s0 += bf2f(v.x)*kr[r];
      s1 += bf2f(v.y)*kr[r];
    }
    size_t o = (size_t)(p0+pl)*DIM + tid*2;
    ushort2 cur = *(ushort2*)(OH + o);
    *(ushort2*)(OH + o) = make_ushort2(f2b(bf2f(cur.x)+s0), f2b(bf2f(cur.y)+s1));
  }
}

// ---------------- leff (bf16 transposed planes) ----------------
__global__ void k_tfwd(const float* __restrict__ X, us* __restrict__ T)
{
  __shared__ float tile[32][33];
  int tx = threadIdx.x & 31, ty = threadIdx.x >> 5;
  int s0 = blockIdx.x*32, c0 = blockIdx.y*32;
  for (int yy=0; yy<4; ++yy){
    int s = s0 + ty + yy*8;
    if (s < NTOK) tile[ty+yy*8][tx] = X[(size_t)(1+s)*DIM + c0+tx];
  }
  __syncthreads();
  for (int yy=0; yy<4; ++yy){
    int c = c0 + ty + yy*8;
    int s = s0 + tx;
    if (s < NTOK) T[(size_t)c*NTOK + s] = f2b(tile[tx][ty+yy*8]);
  }
}
__global__ void k_tbwd(const us* __restrict__ T, float* __restrict__ X)
{
  __shared__ float tile[32][33];
  int tx = threadIdx.x & 31, ty = threadIdx.x >> 5;
  int s0 = blockIdx.x*32, c0 = blockIdx.y*32;
  for (int yy=0; yy<4; ++yy){
    int c = c0 + ty + yy*8, s = s0 + tx;
    if (s < NTOK) tile[ty+yy*8][tx] = bf2f(T[(size_t)c*NTOK + s]);
  }
  __syncthreads();
  for (int yy=0; yy<4; ++yy){
    int s = s0 + ty + yy*8, c = c0 + tx;
    if (s < NTOK) X[(size_t)(1+s)*DIM + c] = tile[tx][ty+yy*8];
  }
}
__global__ __launch_bounds__(256) void k_leff(const us* __restrict__ T,
    const float* __restrict__ k7, const float* __restrict__ b7,
    const float* __restrict__ k5, const float* __restrict__ b5,
    const float* __restrict__ k3, const float* __restrict__ b3,
    us* __restrict__ T2)
{
  __shared__ float tile[21*21];
  int c = blockIdx.y;
  int ti = blockIdx.x/10, tj = blockIdx.x%10;
  int i0 = ti*15-3, j0 = tj*15-3;
  const us* img = T + (size_t)c*NTOK;
  for (int idx=threadIdx.x; idx<441; idx+=256){
    int ii = idx/21, jj = idx%21;
    int gi = i0+ii, gj = j0+jj;
    tile[idx] = (gi>=0 && gi<HSZ && gj>=0 && gj<HSZ) ? bf2f(img[gi*HSZ+gj]) : 0.f;
  }
  __syncthreads();
  if (threadIdx.x < 225){
    int li = threadIdx.x/15, lj = threadIdx.x%15;
    int gi = ti*15+li, gj = tj*15+lj;
    float acc = tile[(li+3)*21 + (lj+3)] + b7[c]+b5[c]+b3[c];
    const float* w7 = k7 + c*49;
#pragma unroll
    for (int a=0;a<7;++a)
#pragma unroll
      for (int bb=0;bb<7;++bb) acc += tile[(li+a)*21 + (lj+bb)]*w7[a*7+bb];
    const float* w5 = k5 + c*25;
#pragma unroll
    for (int a=0;a<5;++a)
#pragma unroll
      for (int bb=0;bb<5;++bb) acc += tile[(li+1+a)*21 + (lj+1+bb)]*w5[a*5+bb];
    const float* w3 = k3 + c*9;
#pragma unroll
    for (int a=0;a<3;++a)
#pragma unroll
      for (int bb=0;bb<3;++bb) acc += tile[(li+2+a)*21 + (lj+2+bb)]*w3[a*3+bb];
    T2[(size_t)c*NTOK + gi*HSZ+gj] = f2b(acc);
  }
}

// ---------------- cls-row pieces ----------------
__global__ void k_row1(const float* __restrict__ Q0, const float* __restrict__ KL0,
                       float* __restrict__ row1)
{
  __shared__ float sb[4];
  __shared__ float qv[64];
  int t = threadIdx.x;
  if (t<64) qv[t] = Q0[PADR*DHD + t];
  __syncthreads();
  float l = 0.f;
#pragma unroll
  for (int d=0;d<64;++d) l += qv[d]*KL0[(size_t)t*DHD+d];
  float m = blockMax256(l, sb);
  float e = __expf(l-m);
  float s = blockSum256(e, sb);
  row1[t] = e/s;
}
__global__ void k_rz(const float* __restrict__ row1, const us* __restrict__ Zt,
                     float* __restrict__ rz)
{
  __shared__ float r1[256];
  int t = threadIdx.x;
  r1[t] = row1[t];
  __syncthreads();
  float s = 0.f;
  for (int k2=0;k2<256;++k2) s += r1[k2]*bf2f(Zt[(size_t)t*MM + k2]);
  rz[t] = s;
}
__global__ void k_rowstat(const float* __restrict__ L0, float* __restrict__ mx, float* __restrict__ se)
{
  __shared__ float sb[4];
  const float* row = L0 + (size_t)blockIdx.x*NPAD;
  float m = -1e30f;
  for (int i=threadIdx.x;i<NPAD;i+=256) m = fmaxf(m, row[i]);
  m = blockMax256(m, sb);
  float s = 0.f;
  for (int i=threadIdx.x;i<NPAD;i+=256) s += __expf(row[i]-m);
  s = blockSum256(s, sb);
  if (threadIdx.x==0){ mx[blockIdx.x]=m; se[blockIdx.x]=s; }
}
__global__ void k_aout(const float* __restrict__ L0, const float* __restrict__ rz,
    const float* __restrict__ mx, const float* __restrict__ se, float* __restrict__ out)
{
  __shared__ float wk[256], mk[256];
  int t = threadIdx.x;
  wk[t] = rz[t]/se[t];
  mk[t] = mx[t];
  __syncthreads();
  int p = blockIdx.x*256 + t;
  if (p >= NTOK) return;
  size_t pp = (size_t)(PADR+1+p);
  float a = 0.f;
  for (int k2=0;k2<256;++k2) a += wk[k2]*__expf(L0[(size_t)k2*NPAD+pp]-mk[k2]);
  out[4+p] = a;
}
__global__ void k_final(const float* __restrict__ H2r, const float* __restrict__ nw,
    const float* __restrict__ nbb, const float* __restrict__ w2, const float* __restrict__ b2,
    float* __restrict__ out)
{
  __shared__ float sb[4];
  __shared__ float hf[512];
  int t = threadIdx.x;
  float x0 = H2r[t], x1 = H2r[256+t];
  float s = blockSum256(x0+x1, sb);
  float q = blockSum256(x0*x0+x1*x1, sb);
  float mean = s*(1.f/512.f);
  float var = q*(1.f/512.f) - mean*mean;
  float rstd = rsqrtf(var+1e-5f);
  hf[t]     = (x0-mean)*rstd*nw[t]+nbb[t];
  hf[256+t] = (x1-mean)*rstd*nw[256+t]+nbb[256+t];
  __syncthreads();
  float p0 = hf[t]*w2[t*2]   + hf[256+t]*w2[(256+t)*2];
  float p1 = hf[t]*w2[t*2+1] + hf[256+t]*w2[(256+t)*2+1];
  p0 = blockSum256(p0, sb);
  p1 = blockSum256(p1, sb);
  if (t==0){
    float l0 = p0+b2[0], l1 = p1+b2[1];
    float m = fmaxf(l0,l1);
    float e0 = __expf(l0-m), e1 = __expf(l1-m), si = 1.f/(e0+e1);
    out[0]=l0; out[1]=l1; out[2]=e0*si; out[3]=e1*si;
  }
}

// ---------------- host orchestration ----------------
struct Bufs {
  float *X,*A2,*sums,*scl,*Pmax,*Psum;
  us *Yb,*OHb,*Qb,*Kb,*Vb,*Vtb,*QLb,*KLb,*A2b;
  us *Z0b,*Z0tb,*Z1b,*Z1tb,*XZb,*XZtb,*T1tb,*T2tb;
  us *A3Vtb,*WmT,*Pacc;
};

static void run_pinv(const us* A2b, Bufs& b, int NB, hipStream_t st,
                     us** outZ, us** outZt)
{
  dim3 g(4,4,NB);
  us *Zc=b.Z0b, *Zct=b.Z0tb, *Zn=b.Z1b, *Znt=b.Z1tb;
  for (int it=0; it<6; ++it){
    k_pgemm<0><<<g,256,0,st>>>(A2b, Zct, b.XZb, b.XZtb, 0.f, 1.f, 1);
    k_pgemm<1><<<g,256,0,st>>>(b.XZb, b.XZtb, nullptr, b.T1tb, 7.f, 1.f, 0);
    k_pgemm<1><<<g,256,0,st>>>(b.XZb, b.T1tb, nullptr, b.T2tb, 15.f, 1.f, 0);
    k_pgemm<1><<<g,256,0,st>>>(Zc, b.T2tb, Zn, Znt, 13.f, 0.25f, 1);
    us* t1=Zc; Zc=Zn; Zn=t1;
    us* t2=Zct; Zct=Znt; Znt=t2;
  }
  *outZ = Zc; *outZt = Zct;
}

static void nystrom_layer(Bufs& b, const float* lnw, const float* lnb,
    const us* wqkvT, const us* woutT,
    const float* bout, const float* resk, hipStream_t st)
{
  k_ln<<<N1,256,0,st>>>(b.X, b.Yb, lnw, lnb);
  k_gemm<1><<<dim3(NPAD/128,12),256,0,st>>>(nullptr, b.Yb, wqkvT, nullptr,
      nullptr, nullptr, b.Qb, b.Kb, b.Vb, DIM);
  k_vT<<<dim3(NPAD/32,16),256,0,st>>>(b.Vb, b.Vtb);
  k_landmark_b<<<NH*MM,64,0,st>>>(b.Qb, b.QLb);
  k_landmark_b<<<NH*MM,64,0,st>>>(b.Kb, b.KLb);
  k_nt64b<<<dim3(4,4,NH),64,0,st>>>(b.QLb, b.KLb, b.A2,
      (long)MM*DHD,(long)MM*DHD,(long)MM*MM, MM);
  k_softmax256<<<NH*MM,256,0,st>>>(b.A2, b.A2b);
  k_rcsum<<<dim3(NH*MM,2),256,0,st>>>(b.A2, b.sums, NH*MM);
  k_scale<<<1,256,0,st>>>(b.sums, b.scl, NH*MM);
  k_z0<<<NH*MM*MM/256,256,0,st>>>(b.A2, b.Z0b, b.Z0tb, b.scl);
  us *Zc, *Zct;
  run_pinv(b.A2b, b, NH, st, &Zc, &Zct);
  k_attn3<<<dim3(NCH,NH),256,0,st>>>(b.QLb, b.Kb, b.Vtb, b.Pmax, b.Psum, b.Pacc);
  k_attn3_merge<<<NH*MM,64,0,st>>>(b.Pmax, b.Psum, b.Pacc, b.A3Vtb);
  k_pgemm<2><<<dim3(1,4,NH),256,0,st>>>(Zc, b.A3Vtb, nullptr, b.WmT, 0.f, 1.f, 0);
  k_attn1<<<dim3(NPAD/64,NH),256,0,st>>>(b.Qb, b.KLb, b.WmT, b.OHb);
  k_seqconv<<<NPAD/SCBLK,256,0,st>>>(b.Vb, resk, b.OHb);
  k_gemm<2><<<dim3(176,4),256,0,st>>>(nullptr, b.OHb, woutT, bout,
      b.X, nullptr, nullptr, nullptr, nullptr, DIM);
}

extern "C" void kernel_launch(void* const* d_in, const int* in_sizes, int n_in,
                              void* d_out, int out_size, void* d_ws, size_t ws_size,
                              hipStream_t stream)
{
  (void)n_in; (void)out_size;
  bool sig_order = (in_sizes[10] == 25088);
  int iL2 = sig_order ? 16 : 10;
  int iLf = sig_order ? 10 : 16;

  const float* h       = (const float*)d_in[0];
  const float* fc1_w   = (const float*)d_in[1];
  const float* fc1_b   = (const float*)d_in[2];
  const float* cls_tok = (const float*)d_in[3];
  const float* l1_lnw  = (const float*)d_in[4];
  const float* l1_lnb  = (const float*)d_in[5];
  const float* l1_wqkv = (const float*)d_in[6];
  const float* l1_wout = (const float*)d_in[7];
  const float* l1_bout = (const float*)d_in[8];
  const float* l1_resk = (const float*)d_in[9];
  const float* l2_lnw  = (const float*)d_in[iL2+0];
  const float* l2_lnb  = (const float*)d_in[iL2+1];
  const float* l2_wqkv = (const float*)d_in[iL2+2];
  const float* l2_wout = (const float*)d_in[iL2+3];
  const float* l2_bout = (const float*)d_in[iL2+4];
  const float* l2_resk = (const float*)d_in[iL2+5];
  const float* k7 = (const float*)d_in[iLf+0];
  const float* b7 = (const float*)d_in[iLf+1];
  const float* k5 = (const float*)d_in[iLf+2];
  const float* b5 = (const float*)d_in[iLf+3];
  const float* k3 = (const float*)d_in[iLf+4];
  const float* b3 = (const float*)d_in[iLf+5];
  const float* nw = (const float*)d_in[22];
  const float* nbb= (const float*)d_in[23];
  const float* w2 = (const float*)d_in[24];
  const float* b2 = (const float*)d_in[25];
  float* out = (float*)d_out;

  char* base = (char*)d_ws;
  auto allocF = [&](size_t n)->float*{
    float* p=(float*)base; base += ((n*sizeof(float)+255)&~(size_t)255); return p; };
  auto allocU = [&](size_t n)->us*{
    us* p=(us*)base; base += ((n*sizeof(us)+255)&~(size_t)255); return p; };

  const size_t S = (size_t)NPAD*DIM;
  const size_t SQ = (size_t)MM*MM;
  Bufs b;
  b.X   = allocF(S);
  b.Yb  = allocU(S);
  b.OHb = allocU(S);
  b.Qb  = allocU(S);
  b.Kb  = allocU(S);
  b.Vb  = allocU(S);
  b.Vtb = allocU(S);
  b.QLb = allocU((size_t)NH*MM*DHD);
  b.KLb = allocU((size_t)NH*MM*DHD);
  b.A2  = allocF((size_t)NH*SQ);
  b.A2b = allocU((size_t)NH*SQ);
  b.Z0b = allocU((size_t)NH*SQ);  b.Z0tb = allocU((size_t)NH*SQ);
  b.Z1b = allocU((size_t)NH*SQ);  b.Z1tb = allocU((size_t)NH*SQ);
  b.XZb = allocU((size_t)NH*SQ);  b.XZtb = allocU((size_t)NH*SQ);
  b.T1tb= allocU((size_t)NH*SQ);
  b.T2tb= allocU((size_t)NH*SQ);
  b.A3Vtb = allocU((size_t)NH*MM*DHD);
  b.WmT   = allocU((size_t)NH*MM*DHD);
  b.sums  = allocF(2*(size_t)NH*MM);
  b.scl   = allocF(16);
  b.Pmax  = allocF((size_t)NH*NCH*MM);
  b.Psum  = allocF((size_t)NH*NCH*MM);
  b.Pacc  = allocU((size_t)NH*NCH*MM*DHD);
  us* fc1T   = allocU((size_t)DIM*1024);
  us* wqkvT1 = allocU((size_t)1536*DIM);
  us* wqkvT2 = allocU((size_t)1536*DIM);
  us* woutT1 = allocU((size_t)DIM*DIM);
  us* woutT2 = allocU((size_t)DIM*DIM);
  float* Q0   = allocF((size_t)NPAD*DHD);
  float* K0   = allocF((size_t)NPAD*DHD);
  float* QL0f = allocF((size_t)MM*DHD);
  float* KL0f = allocF((size_t)MM*DHD);
  float* row1 = allocF(256);
  float* rzv  = allocF(256);
  float* mxv  = allocF(256);
  float* sev  = allocF(256);
  float* h2row= allocF(512);
  if ((size_t)(base - (char*)d_ws) > ws_size) return;

  // weight transposes (fp32 -> bf16 [N][K])
  k_wT<<<dim3(32,16),256,0,stream>>>(fc1_w, fc1T, 1024, DIM);
  k_wT<<<dim3(16,48),256,0,stream>>>(l1_wqkv, wqkvT1, DIM, 1536);
  k_wT<<<dim3(16,48),256,0,stream>>>(l2_wqkv, wqkvT2, DIM, 1536);
  k_wT<<<dim3(16,16),256,0,stream>>>(l1_wout, woutT1, DIM, DIM);
  k_wT<<<dim3(16,16),256,0,stream>>>(l2_wout, woutT2, DIM, DIM);

  // stage 0: fc1 + cls token
  k_gemm<0><<<dim3(176,4),256,0,stream>>>(h, nullptr, fc1T, fc1_b,
      b.X, nullptr, nullptr, nullptr, nullptr, 1024);
  k_setcls<<<2,256,0,stream>>>(b.X, cls_tok);

  // layer 1 + LeFF (leff reuses OHb/Qb as bf16 planes)
  nystrom_layer(b, l1_lnw, l1_lnb, wqkvT1, woutT1, l1_bout, l1_resk, stream);
  k_tfwd<<<dim3(704,16),256,0,stream>>>(b.X, b.OHb);
  k_leff<<<dim3(100,512),256,0,stream>>>(b.OHb, k7,b7,k5,b5,k3,b3, b.Qb);
  k_tbwd<<<dim3(704,16),256,0,stream>>>(b.Qb, b.X);

  // layer 2 (save h2 row 0)
  nystrom_layer(b, l2_lnw, l2_lnb, wqkvT2, woutT2, l2_bout, l2_resk, stream);
  k_copy<<<2,256,0,stream>>>(h2row, b.X, 512);

  // layer 3 -> h3
  nystrom_layer(b, l2_lnw, l2_lnb, wqkvT2, woutT2, l2_bout, l2_resk, stream);

  // cls-row stage (head 0, l2 weights, LN(h3))
  k_ln<<<N1,256,0,stream>>>(b.X, b.Yb, l2_lnw, l2_lnb);
  k_gemm<3><<<dim3(176,1),256,0,stream>>>(nullptr, b.Yb, wqkvT2, nullptr,
      Q0, K0, nullptr, nullptr, nullptr, DIM);
  k_landmark<<<MM,64,0,stream>>>(Q0, QL0f);
  k_landmark<<<MM,64,0,stream>>>(K0, KL0f);
  k_nt64<<<dim3(4,4,1),64,0,stream>>>(QL0f, KL0f, b.A2, 0,0,0, MM);
  k_softmax256<<<MM,256,0,stream>>>(b.A2, b.A2b);
  k_rcsum<<<dim3(MM,2),256,0,stream>>>(b.A2, b.sums, MM);
  k_scale<<<1,256,0,stream>>>(b.sums, b.scl, MM);
  k_z0<<<MM*MM/256,256,0,stream>>>(b.A2, b.Z0b, b.Z0tb, b.scl);
  us *Zc, *Zct;
  run_pinv(b.A2b, b, 1, stream, &Zc, &Zct);
  k_row1<<<1,256,0,stream>>>(Q0, KL0f, row1);
  k_rz<<<1,256,0,stream>>>(row1, Zct, rzv);
  // L0 = QL0 @ K0^T (256 x NPAD), into Yb's storage (exactly NPAD*256 floats)
  float* L0 = (float*)b.Yb;
  k_nt64<<<dim3(NPAD/64,4,1),64,0,stream>>>(QL0f, K0, L0, 0,0,0, NPAD);
  k_rowstat<<<MM,256,0,stream>>>(L0, mxv, sev);
  k_aout<<<88,256,0,stream>>>(L0, rzv, mxv, sev, out);
  k_final<<<1,256,0,stream>>>(h2row, nw, nbb, w2, b2, out);
}

// Round 6
// 2487.372 us; speedup vs baseline: 3.6516x; 1.0616x over previous
//
#include <hip/hip_runtime.h>

#define NTOK 22500
#define N1   22501
#define NPAD 22528
#define PADR 27
#define DIM  512
#define NH   8
#define DHD  64
#define MM   256
#define LLM  88
#define HSZ  150
#define CSZ  256
#define NCH  88   // NPAD / CSZ

typedef short bf16x8 __attribute__((ext_vector_type(8)));
typedef float f32x4  __attribute__((ext_vector_type(4)));
typedef unsigned short us;

union U8 { bf16x8 v; unsigned short u[8]; };

__device__ __forceinline__ unsigned short f2b(float f){
  unsigned int u = __float_as_uint(f);
  unsigned int r = u + 0x7fffu + ((u>>16)&1u);
  return (unsigned short)(r>>16);
}
__device__ __forceinline__ float bf2f(unsigned short u){
  return __uint_as_float(((unsigned int)u)<<16);
}
__device__ __forceinline__ bf16x8 cvt8(float4 a, float4 b){
  U8 u;
  u.u[0]=f2b(a.x); u.u[1]=f2b(a.y); u.u[2]=f2b(a.z); u.u[3]=f2b(a.w);
  u.u[4]=f2b(b.x); u.u[5]=f2b(b.y); u.u[6]=f2b(b.z); u.u[7]=f2b(b.w);
  return u.v;
}
// async global->LDS, 16B per lane; lds dest = wave-uniform base + lane*16
__device__ __forceinline__ void gld16(const void* g, void* l){
  __builtin_amdgcn_global_load_lds(
      (const __attribute__((address_space(1))) void*)g,
      (__attribute__((address_space(3))) void*)l, 16, 0, 0);
}

// ---------------- reduction helpers ----------------
__device__ __forceinline__ float waveSum(float v){
#pragma unroll
  for (int o=32;o>0;o>>=1) v += __shfl_down(v,o);
  return v;
}
__device__ __forceinline__ float waveMax(float v){
#pragma unroll
  for (int o=32;o>0;o>>=1) v = fmaxf(v,__shfl_down(v,o));
  return v;
}
__device__ __forceinline__ float blockSum256(float v, float* sb){
  v = waveSum(v);
  __syncthreads();
  if ((threadIdx.x&63)==0) sb[threadIdx.x>>6]=v;
  __syncthreads();
  return sb[0]+sb[1]+sb[2]+sb[3];
}
__device__ __forceinline__ float blockMax256(float v, float* sb){
  v = waveMax(v);
  __syncthreads();
  if ((threadIdx.x&63)==0) sb[threadIdx.x>>6]=v;
  __syncthreads();
  return fmaxf(fmaxf(sb[0],sb[1]),fmaxf(sb[2],sb[3]));
}

// ---------------- weight transpose+cvt: W fp32 [K][N] -> Bt bf16 [N][K] ----------------
__global__ void k_wT(const float* __restrict__ W, us* __restrict__ Bt, int K, int N)
{
  __shared__ float tile[32][33];
  int tx = threadIdx.x&31, ty = threadIdx.x>>5;
  int k0 = blockIdx.x*32, n0 = blockIdx.y*32;
#pragma unroll
  for (int i=0;i<4;++i){
    int k = k0+ty+i*8;
    if (k<K && n0+tx<N) tile[ty+i*8][tx] = W[(size_t)k*N + n0+tx];
  }
  __syncthreads();
#pragma unroll
  for (int i=0;i<4;++i){
    int n = n0+ty+i*8, k = k0+tx;
    if (n<N && k<K) Bt[(size_t)n*K + k] = f2b(tile[tx][ty+i*8]);
  }
}

// ---------------- V transpose: Vb [h][p][d] -> Vtb [h][d][p] ----------------
__global__ void k_vT(const us* __restrict__ V, us* __restrict__ Vt)
{
  __shared__ us tile[32][33];
  int tx = threadIdx.x&31, ty = threadIdx.x>>5;
  int p0 = blockIdx.x*32;
  int h = blockIdx.y>>1, d0 = (blockIdx.y&1)*32;
#pragma unroll
  for (int i=0;i<4;++i){
    int p = p0+ty+i*8;
    tile[ty+i*8][tx] = V[((size_t)h*NPAD+p)*DHD + d0+tx];
  }
  __syncthreads();
#pragma unroll
  for (int i=0;i<4;++i){
    int d = d0+ty+i*8;
    Vt[((size_t)h*DHD+d)*NPAD + p0+tx] = tile[tx][ty+i*8];
  }
}

// ---------------- MFMA GEMM (128x128 tile), global_load_lds staging ----------------
// MODE 0: fc1 (A fp32 -> X bf16 relu)   MODE 1: qkv (A=Yb bf16 -> Qb/Kb/Vb)
// MODE 2: wout (A=OHb bf16, X bf16 +=)  MODE 3: qk0 (A=Yb bf16 -> Q0/K0 fp32)
template<int MODE>
__global__ __launch_bounds__(256) void k_gemm(const float* __restrict__ Af,
    const us* __restrict__ Ab, const us* __restrict__ Bt, const float* __restrict__ bias,
    us* __restrict__ Xb, float* __restrict__ Cf, float* __restrict__ C2,
    us* __restrict__ Q_, us* __restrict__ K_, us* __restrict__ V_,
    const us* __restrict__ zpg, int Kd)
{
  __shared__ us SM[16384];     // As = SM[0..8191], Bs = SM[8192..16383]
  us* As = SM;
  us* Bs = SM + 8192;
  const int tid = threadIdx.x;
  const int m0 = blockIdx.x*128, n0 = blockIdx.y*128;
  const int lane = tid & 63;
  const int wid = tid >> 6;
  const int wm = (wid>>1)*64, wn = (wid&1)*64;
  f32x4 acc[4][4] = {};
  for (int k0=0; k0<Kd; k0+=64){
    __syncthreads();
    if (MODE==0){
#pragma unroll
      for (int i=0;i<8;++i){
        int g = i*256 + tid;
        int row = g>>4, k4 = (g&15)*4;
        int gm = m0 + row;
        ushort4 h4 = make_ushort4(0,0,0,0);
        if (gm < NTOK){
          float4 v = *(const float4*)(Af + (size_t)gm*Kd + k0 + k4);
          h4.x=f2b(v.x); h4.y=f2b(v.y); h4.z=f2b(v.z); h4.w=f2b(v.w);
        }
        *(ushort4*)(&As[row*64 + (k4 ^ ((row&7)<<3))]) = h4;
      }
    } else {
#pragma unroll
      for (int i=0;i<4;++i){
        int c = wid*4+i;
        int row = c*8 + (lane>>3);
        int scol8 = ((lane&7) ^ (row&7))*8;
        int gm = m0+row;
        const us* ga;
        if (MODE==2) ga = Ab + ((size_t)((gm<N1?gm:0)+PADR))*Kd + k0 + scol8;
        else ga = (gm>=PADR) ? Ab + (size_t)(gm-PADR)*Kd + k0 + scol8 : zpg + scol8;
        gld16(ga, &As[c*512]);
      }
    }
#pragma unroll
    for (int i=0;i<4;++i){
      int c = wid*4+i;
      int row = c*8 + (lane>>3);
      int scol8 = ((lane&7) ^ (row&7))*8;
      int vn = n0+row;
      if (MODE==3) vn = (vn<64)? vn : vn+448;
      gld16(Bt + (size_t)vn*Kd + k0 + scol8, &Bs[c*512]);
    }
    __syncthreads();
#pragma unroll
    for (int ks=0; ks<2; ++ks){
      const int kk = ks*32 + (lane>>4)*8;
      bf16x8 af[4], bfm[4];
#pragma unroll
      for (int t=0;t<4;++t){
        int r = wm + t*16 + (lane&15);
        af[t] = *(bf16x8*)(&As[r*64 + (kk ^ ((r&7)<<3))]);
        int c = wn + t*16 + (lane&15);
        bfm[t] = *(bf16x8*)(&Bs[c*64 + (kk ^ ((c&7)<<3))]);
      }
#pragma unroll
      for (int mt=0;mt<4;++mt)
#pragma unroll
        for (int nt=0;nt<4;++nt)
          acc[mt][nt] = __builtin_amdgcn_mfma_f32_16x16x32_bf16(af[mt], bfm[nt], acc[mt][nt], 0,0,0);
    }
  }
  const int rbase = (lane>>4)*4;
  const int cl = lane&15;
  if (MODE==3){
#pragma unroll
    for (int mt=0;mt<4;++mt)
#pragma unroll
      for (int r=0;r<4;++r){
        int gm = m0 + wm + mt*16 + rbase + r;
#pragma unroll
        for (int nt=0;nt<4;++nt){
          int gn = n0 + wn + nt*16 + cl;
          float v = acc[mt][nt][r];
          if (gn < 64) Cf[(size_t)gm*DHD + gn] = v*0.125f;
          else         C2[(size_t)gm*DHD + (gn-64)] = v;
        }
      }
    return;
  }
  // LDS relayout epilogues (coalesced 16B bf16 stores)
  const float sc1 = (MODE==1 && (blockIdx.y>>2)==0) ? 0.125f : 1.f;
  __syncthreads();
#pragma unroll
  for (int mt=0;mt<4;++mt)
#pragma unroll
    for (int r=0;r<4;++r){
      int row = wm + mt*16 + rbase + r;
#pragma unroll
      for (int nt=0;nt<4;++nt){
        int col = wn + nt*16 + cl;
        float v = acc[mt][nt][r];
        if (MODE==0){ v += bias[n0+col]; v = v>0.f?v:0.f; }
        else if (MODE==2){ v += bias[n0+col]; }
        else v *= sc1;
        SM[row*128 + col] = f2b(v);
      }
    }
  __syncthreads();
  if (MODE==1){
    const int sec = blockIdx.y>>2;
    us* dst = sec==0 ? Q_ : (sec==1 ? K_ : V_);
#pragma unroll
    for (int i=0;i<8;++i){
      int v8 = i*256 + tid;
      int row = v8>>4, c8 = (v8&15)*8;
      int gm = m0 + row, gn = n0 + c8;
      int hh = (gn>>6)&7, d = gn&63;
      *(bf16x8*)(dst + ((size_t)hh*NPAD+gm)*DHD + d) = *(bf16x8*)(&SM[row*128 + c8]);
    }
  } else if (MODE==0){
#pragma unroll
    for (int i=0;i<8;++i){
      int v8 = i*256 + tid;
      int row = v8>>4, c8 = (v8&15)*8;
      int gm = m0 + row;
      if (gm < NTOK)
        *(bf16x8*)(Xb + (size_t)(1+gm)*DIM + n0 + c8) = *(bf16x8*)(&SM[row*128 + c8]);
    }
  } else {  // MODE 2: bf16 RMW on X
#pragma unroll
    for (int i=0;i<8;++i){
      int v8 = i*256 + tid;
      int row = v8>>4, c8 = (v8&15)*8;
      int gm = m0 + row;
      if (gm < N1){
        us* p = Xb + (size_t)gm*DIM + n0 + c8;
        U8 xo, ad, o;
        xo.v = *(bf16x8*)p;
        ad.v = *(bf16x8*)(&SM[row*128 + c8]);
#pragma unroll
        for (int j=0;j<8;++j) o.u[j] = f2b(bf2f(xo.u[j]) + bf2f(ad.u[j]));
        *(bf16x8*)p = o.v;
      }
    }
  }
}

__global__ void k_setcls(us* __restrict__ X, const float* __restrict__ cls){
  int i = blockIdx.x*256 + threadIdx.x;
  if (i < DIM) X[i] = f2b(cls[i]);
}
__global__ void k_copyu(us* __restrict__ d, const us* __restrict__ s, size_t n){
  size_t i = (size_t)blockIdx.x*256 + threadIdx.x;
  if (i<n) d[i]=s[i];
}

// ---------------- layernorm: bf16 in -> bf16 out ----------------
__global__ void k_ln(const us* __restrict__ X, us* __restrict__ Y,
                     const float* __restrict__ w, const float* __restrict__ b)
{
  __shared__ float sb[4];
  const us* x = X + (size_t)blockIdx.x*DIM;
  us* y = Y + (size_t)blockIdx.x*DIM;
  int t = threadIdx.x;
  ushort2 xv = *(const ushort2*)(x + 2*t);
  float a0=bf2f(xv.x), a1=bf2f(xv.y);
  float s = blockSum256(a0+a1, sb);
  float q = blockSum256(a0*a0+a1*a1, sb);
  float mean = s*(1.f/512.f);
  float var = q*(1.f/512.f) - mean*mean;
  float rstd = rsqrtf(var+1e-5f);
  float2 wv = *(const float2*)(w + 2*t);
  float2 bv = *(const float2*)(b + 2*t);
  ushort2 o;
  o.x = f2b((a0-mean)*rstd*wv.x+bv.x);
  o.y = f2b((a1-mean)*rstd*wv.y+bv.y);
  *(ushort2*)(y + 2*t) = o;
}

// ---------------- landmarks (fused Q+K) ----------------
__global__ void k_landmark2(const us* __restrict__ Q, const us* __restrict__ K,
                            us* __restrict__ QL, us* __restrict__ KL)
{
  int hm = blockIdx.x;
  bool isK = hm >= NH*MM;
  if (isK) hm -= NH*MM;
  int h = hm>>8, m = hm&255; int d = threadIdx.x;
  const us* base = (isK?K:Q) + ((size_t)h*NPAD + (size_t)m*LLM)*DHD + d;
  float s = 0.f;
  for (int j=0;j<LLM;++j) s += bf2f(base[(size_t)j*DHD]);
  (isK?KL:QL)[((size_t)h*MM + m)*DHD + d] = f2b(s * (1.f/(float)LLM));
}
__global__ void k_landmark2f(const float* __restrict__ Q, const float* __restrict__ K,
                             float* __restrict__ QL, float* __restrict__ KL)
{
  int hm = blockIdx.x;
  bool isK = hm >= MM;
  int m = isK ? hm-MM : hm; int d = threadIdx.x;
  const float* base = (isK?K:Q) + (size_t)m*LLM*DHD + d;
  float s = 0.f;
  for (int j=0;j<LLM;++j) s += base[(size_t)j*DHD];
  (isK?KL:QL)[(size_t)m*DHD + d] = s * (1.f/(float)LLM);
}

// ---------------- MFMA NT gemm K=64, fp32 inputs ----------------
__global__ __launch_bounds__(64) void k_nt64(const float* __restrict__ A,
    const float* __restrict__ B, float* __restrict__ C,
    long sA, long sB, long sC, int Nr)
{
  int lane = threadIdx.x;
  int n0 = blockIdx.x*64, m0 = blockIdx.y*64;
  A += (size_t)blockIdx.z*sA; B += (size_t)blockIdx.z*sB; C += (size_t)blockIdx.z*sC;
  f32x4 acc[4][4] = {};
#pragma unroll
  for (int ks=0;ks<2;++ks){
    int kk = ks*32 + (lane>>4)*8;
    bf16x8 af[4], bfr[4];
#pragma unroll
    for (int mt=0;mt<4;++mt){
      const float* p = A + (size_t)(m0+mt*16+(lane&15))*64 + kk;
      af[mt] = cvt8(*(const float4*)p, *(const float4*)(p+4));
    }
#pragma unroll
    for (int nt=0;nt<4;++nt){
      const float* p = B + (size_t)(n0+nt*16+(lane&15))*64 + kk;
      bfr[nt] = cvt8(*(const float4*)p, *(const float4*)(p+4));
    }
#pragma unroll
    for (int mt=0;mt<4;++mt)
#pragma unroll
      for (int nt=0;nt<4;++nt)
        acc[mt][nt] = __builtin_amdgcn_mfma_f32_16x16x32_bf16(af[mt], bfr[nt], acc[mt][nt], 0,0,0);
  }
#pragma unroll
  for (int mt=0;mt<4;++mt)
#pragma unroll
    for (int r=0;r<4;++r){
      int row = m0+mt*16+(lane>>4)*4+r;
#pragma unroll
      for (int nt=0;nt<4;++nt){
        int col = n0+nt*16+(lane&15);
        C[(size_t)row*Nr + col] = acc[mt][nt][r];
      }
    }
}

// ---------------- MFMA NT gemm K=64, bf16 inputs (attn2 logits) ----------------
__global__ __launch_bounds__(64) void k_nt64b(const us* __restrict__ A,
    const us* __restrict__ B, float* __restrict__ C,
    long sA, long sB, long sC, int Nr)
{
  int lane = threadIdx.x;
  int n0 = blockIdx.x*64, m0 = blockIdx.y*64;
  A += (size_t)blockIdx.z*sA; B += (size_t)blockIdx.z*sB; C += (size_t)blockIdx.z*sC;
  f32x4 acc[4][4] = {};
#pragma unroll
  for (int ks=0;ks<2;++ks){
    int kk = ks*32 + (lane>>4)*8;
    bf16x8 af[4], bfr[4];
#pragma unroll
    for (int mt=0;mt<4;++mt)
      af[mt] = *(const bf16x8*)(A + (size_t)(m0+mt*16+(lane&15))*64 + kk);
#pragma unroll
    for (int nt=0;nt<4;++nt)
      bfr[nt] = *(const bf16x8*)(B + (size_t)(n0+nt*16+(lane&15))*64 + kk);
#pragma unroll
    for (int mt=0;mt<4;++mt)
#pragma unroll
      for (int nt=0;nt<4;++nt)
        acc[mt][nt] = __builtin_amdgcn_mfma_f32_16x16x32_bf16(af[mt], bfr[nt], acc[mt][nt], 0,0,0);
  }
#pragma unroll
  for (int mt=0;mt<4;++mt)
#pragma unroll
    for (int r=0;r<4;++r){
      int row = m0+mt*16+(lane>>4)*4+r;
#pragma unroll
      for (int nt=0;nt<4;++nt){
        int col = n0+nt*16+(lane&15);
        C[(size_t)row*Nr + col] = acc[mt][nt][r];
      }
    }
}

// ---------------- pinv MFMA gemm, all-bf16 ----------------
template<int PM>
__global__ __launch_bounds__(256) void k_pgemm(const us* __restrict__ A,
    const us* __restrict__ Bt, us* __restrict__ C, us* __restrict__ Ct,
    float dc, float alpha, int writeC)
{
  __shared__ us As[64*256];
  __shared__ us Bs[64*256];
  const int tid = threadIdx.x, lane = tid&63, wid = tid>>6;
  const int n0 = blockIdx.x*64, m0 = blockIdx.y*64;
  const us* Ab = A + (size_t)blockIdx.z*65536;
  const us* Bb = Bt + (size_t)blockIdx.z*(PM==2?16384:65536);
  for (int i=tid; i<4096; i+=256){
    int r = i>>6, c4 = (i&63)*4;
    *(ushort4*)(&As[r*256 + (c4 ^ ((r&7)<<3))]) = *(const ushort4*)(Ab + (size_t)(m0+r)*256 + c4);
    *(ushort4*)(&Bs[r*256 + (c4 ^ ((r&7)<<3))]) = *(const ushort4*)(Bb + (size_t)(n0+r)*256 + c4);
  }
  __syncthreads();
  const int wm = (wid>>1)*32, wn = (wid&1)*32;
  f32x4 acc[2][2] = {};
#pragma unroll
  for (int ks=0;ks<8;++ks){
    int kk = ks*32 + (lane>>4)*8;
    bf16x8 af[2], bfr[2];
#pragma unroll
    for (int t=0;t<2;++t){
      int rr = wm + t*16 + (lane&15);
      af[t] = *(const bf16x8*)(&As[rr*256 + (kk ^ ((rr&7)<<3))]);
      int cc = wn + t*16 + (lane&15);
      bfr[t] = *(const bf16x8*)(&Bs[cc*256 + (kk ^ ((cc&7)<<3))]);
    }
#pragma unroll
    for (int mt=0;mt<2;++mt)
#pragma unroll
      for (int nt=0;nt<2;++nt)
        acc[mt][nt] = __builtin_amdgcn_mfma_f32_16x16x32_bf16(af[mt], bfr[nt], acc[mt][nt], 0,0,0);
  }
#pragma unroll
  for (int mt=0;mt<2;++mt)
#pragma unroll
    for (int r=0;r<4;++r){
      int row = m0 + wm + mt*16 + (lane>>4)*4 + r;
#pragma unroll
      for (int nt=0;nt<2;++nt){
        int col = n0 + wn + nt*16 + (lane&15);
        float v = acc[mt][nt][r];
        if (PM==1) v = alpha*(dc*bf2f(Ab[(size_t)row*256+col]) - v);
        if (PM==2){
          Ct[(size_t)blockIdx.z*16384 + (size_t)col*256 + row] = f2b(v);
        } else {
          us bv = f2b(v);
          if (PM==0 || writeC) C[(size_t)blockIdx.z*65536 + (size_t)row*256 + col] = bv;
          Ct[(size_t)blockIdx.z*65536 + (size_t)col*256 + row] = bv;
        }
      }
    }
}

// ---------------- small elementwise ----------------
__global__ void k_softmax256(float* __restrict__ S, us* __restrict__ Sb)
{
  __shared__ float sb[4];
  float* row = S + ((size_t)blockIdx.x<<8);
  float x = row[threadIdx.x];
  float m = blockMax256(x, sb);
  float e = __expf(x-m);
  float s = blockSum256(e, sb);
  float p = e/s;
  row[threadIdx.x] = p;
  Sb[((size_t)blockIdx.x<<8) + threadIdx.x] = f2b(p);
}
// col-sum max per head (row sums of softmax are exactly 1)
__global__ void k_csmax(const float* __restrict__ A2, float* __restrict__ sums)
{
  __shared__ float sb[4];
  int b = blockIdx.x, j = threadIdx.x;
  const float* Ab = A2 + ((size_t)b<<16);
  float s = 0.f;
  for (int i=0;i<256;++i) s += Ab[((size_t)i<<8)+j];
  float m = blockMax256(s, sb);
  if (j==0) sums[b] = m;
}
__global__ void k_scale2(const float* __restrict__ sums, float* __restrict__ scl, int nb)
{
  __shared__ float sb[4];
  float m=-1e30f;
  for (int i=threadIdx.x;i<nb;i+=256) m = fmaxf(m, sums[i]);
  m = blockMax256(m, sb);
  if (threadIdx.x==0) scl[0] = 1.f/m;
}
__global__ void k_z0(const float* __restrict__ A2, us* __restrict__ Z, us* __restrict__ Zt,
                     const float* __restrict__ scl)
{
  size_t idx = (size_t)blockIdx.x*256 + threadIdx.x;
  size_t b = idx>>16; int i=(int)((idx>>8)&255), j=(int)(idx&255);
  float v = A2[idx]*scl[0];
  us bv = f2b(v);
  Zt[idx] = bv;
  Z[(b<<16)+((size_t)j<<8)+i] = bv;
}

// ---------------- attn3: MFMA flash ----------------
__global__ __launch_bounds__(256) void k_attn3(const us* __restrict__ QLb,
    const us* __restrict__ Kb, const us* __restrict__ Vt,
    float* __restrict__ Pmax, float* __restrict__ Psum, us* __restrict__ Pacc)
{
  __shared__ us Ks[64*64];
  __shared__ us Vs[64*64];
  __shared__ us Ps[4*64*64];
  int h = blockIdx.y, cx = blockIdx.x;
  int tid = threadIdx.x, wid = tid>>6, lane = tid&63;
  bf16x8 aq[4][2];
#pragma unroll
  for (int mt=0;mt<4;++mt){
    const us* qp = QLb + ((size_t)h*MM + wid*64 + mt*16 + (lane&15))*DHD;
#pragma unroll
    for (int ks=0;ks<2;++ks)
      aq[mt][ks] = *(const bf16x8*)(qp + ks*32 + (lane>>4)*8);
  }
  float m_[4][4], l_[4][4];
  f32x4 acc[4][4] = {};
#pragma unroll
  for (int mt=0;mt<4;++mt)
#pragma unroll
    for (int r=0;r<4;++r){ m_[mt][r] = -1e30f; l_[mt][r] = 0.f; }

  us* Pw = &Ps[wid*4096];
  for (int t=0;t<4;++t){
    int kb0 = cx*CSZ + t*64;
    __syncthreads();
    for (int i=tid;i<1024;i+=256){
      int rr = i>>4, c4 = (i&15)*4;
      ushort4 ku = *(const ushort4*)(Kb + ((size_t)h*NPAD + kb0 + rr)*DHD + c4);
      *(ushort4*)(&Ks[rr*64 + (c4 ^ ((rr&7)<<3))]) = ku;
      ushort4 vu = *(const ushort4*)(Vt + ((size_t)h*DHD + rr)*NPAD + kb0 + c4);
      *(ushort4*)(&Vs[rr*64 + (c4 ^ ((rr&7)<<3))]) = vu;
    }
    __syncthreads();
    f32x4 s[4][4] = {};
#pragma unroll
    for (int ks=0;ks<2;++ks){
      int kk = ks*32 + (lane>>4)*8;
      bf16x8 kbf[4];
#pragma unroll
      for (int nt=0;nt<4;++nt){
        int key = nt*16 + (lane&15);
        kbf[nt] = *(const bf16x8*)(&Ks[key*64 + (kk ^ ((key&7)<<3))]);
      }
#pragma unroll
      for (int mt=0;mt<4;++mt)
#pragma unroll
        for (int nt=0;nt<4;++nt)
          s[mt][nt] = __builtin_amdgcn_mfma_f32_16x16x32_bf16(aq[mt][ks], kbf[nt], s[mt][nt], 0,0,0);
    }
#pragma unroll
    for (int mt=0;mt<4;++mt){
#pragma unroll
      for (int r=0;r<4;++r){
        float mx = fmaxf(fmaxf(s[mt][0][r], s[mt][1][r]), fmaxf(s[mt][2][r], s[mt][3][r]));
#pragma unroll
        for (int off=8;off>=1;off>>=1) mx = fmaxf(mx, __shfl_xor(mx, off));
        float mn = fmaxf(m_[mt][r], mx);
        float f = __expf(m_[mt][r]-mn);
        float la = 0.f;
#pragma unroll
        for (int nt=0;nt<4;++nt){ float p=__expf(s[mt][nt][r]-mn); s[mt][nt][r]=p; la+=p; }
#pragma unroll
        for (int off=8;off>=1;off>>=1) la += __shfl_xor(la, off);
        l_[mt][r] = l_[mt][r]*f + la;
        m_[mt][r] = mn;
#pragma unroll
        for (int dt=0;dt<4;++dt) acc[mt][dt][r] *= f;
      }
    }
#pragma unroll
    for (int mt=0;mt<4;++mt)
#pragma unroll
      for (int r=0;r<4;++r){
        int row = mt*16 + (lane>>4)*4 + r;
        int sw = (row&7)<<3;
#pragma unroll
        for (int nt=0;nt<4;++nt){
          int col = nt*16 + (lane&15);
          Pw[row*64 + (col ^ sw)] = f2b(s[mt][nt][r]);
        }
      }
#pragma unroll
    for (int ks=0;ks<2;++ks){
      int kk = ks*32 + (lane>>4)*8;
      bf16x8 pa[4], vb[4];
#pragma unroll
      for (int mt=0;mt<4;++mt){
        int arow = mt*16 + (lane&15);
        pa[mt] = *(const bf16x8*)(&Pw[arow*64 + (kk ^ ((arow&7)<<3))]);
      }
#pragma unroll
      for (int dt=0;dt<4;++dt){
        int d = dt*16 + (lane&15);
        vb[dt] = *(const bf16x8*)(&Vs[d*64 + (kk ^ ((d&7)<<3))]);
      }
#pragma unroll
      for (int mt=0;mt<4;++mt)
#pragma unroll
        for (int dt=0;dt<4;++dt)
          acc[mt][dt] = __builtin_amdgcn_mfma_f32_16x16x32_bf16(pa[mt], vb[dt], acc[mt][dt], 0,0,0);
    }
  }
  size_t pbase = ((size_t)h*NCH + cx)*MM;
#pragma unroll
  for (int mt=0;mt<4;++mt)
#pragma unroll
    for (int r=0;r<4;++r){
      int row = wid*64 + mt*16 + (lane>>4)*4 + r;
      if ((lane&15)==0){ Pmax[pbase+row]=m_[mt][r]; Psum[pbase+row]=l_[mt][r]; }
#pragma unroll
      for (int dt=0;dt<4;++dt)
        Pacc[(pbase+row)*DHD + dt*16+(lane&15)] = f2b(acc[mt][dt][r]);
    }
}

__global__ void k_attn3_merge(const float* __restrict__ Pmax, const float* __restrict__ Psum,
    const us* __restrict__ Pacc, us* __restrict__ A3Vtb)
{
  int hm = blockIdx.x; int h = hm>>8, m = hm&255; int d = threadIdx.x;
  float gm = -1e30f;
  for (int c=0;c<NCH;++c) gm = fmaxf(gm, Pmax[((size_t)h*NCH+c)*MM+m]);
  float tot=0.f, acc=0.f;
  for (int c=0;c<NCH;++c){
    size_t pi = ((size_t)h*NCH+c)*MM+m;
    float w = __expf(Pmax[pi]-gm);
    tot += Psum[pi]*w;
    acc += bf2f(Pacc[pi*DHD+d])*w;
  }
  A3Vtb[((size_t)h*DHD + d)*MM + m] = f2b(acc/tot);
}

// ---------------- attn1 ----------------
__global__ __launch_bounds__(256) void k_attn1(const us* __restrict__ Qb,
    const us* __restrict__ KLb, const us* __restrict__ WmT,
    us* __restrict__ OH)
{
  __shared__ us KWs[64*256];
  __shared__ us Ps[64*256];
  int h = blockIdx.y, tid = threadIdx.x;
  int wid = tid>>6, lane = tid&63;
  int q0 = blockIdx.x*64;
  for (int i=tid; i<4096; i+=256){
    int lm = i>>4, k4 = (i&15)*4;
    *(ushort4*)(&KWs[lm*64 + (k4 ^ ((lm&7)<<3))]) =
        *(const ushort4*)(KLb + ((size_t)h*MM + lm)*DHD + k4);
  }
  bf16x8 aq[2];
  const us* qp = Qb + ((size_t)h*NPAD + q0 + wid*16 + (lane&15))*DHD;
#pragma unroll
  for (int ks=0;ks<2;++ks)
    aq[ks] = *(const bf16x8*)(qp + ks*32 + (lane>>4)*8);
  __syncthreads();
  f32x4 s[16];
#pragma unroll
  for (int nt=0;nt<16;++nt) s[nt] = (f32x4){0.f,0.f,0.f,0.f};
#pragma unroll
  for (int ks=0;ks<2;++ks){
    int kk = ks*32 + (lane>>4)*8;
#pragma unroll
    for (int nt=0;nt<16;++nt){
      int col = nt*16 + (lane&15);
      bf16x8 b = *(const bf16x8*)(&KWs[col*64 + (kk ^ ((col&7)<<3))]);
      s[nt] = __builtin_amdgcn_mfma_f32_16x16x32_bf16(aq[ks], b, s[nt], 0,0,0);
    }
  }
  float rcp[4];
#pragma unroll
  for (int r=0;r<4;++r){
    float m = -1e30f;
#pragma unroll
    for (int nt=0;nt<16;++nt) m = fmaxf(m, s[nt][r]);
#pragma unroll
    for (int off=8;off>=1;off>>=1) m = fmaxf(m, __shfl_xor(m, off));
    float l = 0.f;
#pragma unroll
    for (int nt=0;nt<16;++nt){ float p=__expf(s[nt][r]-m); s[nt][r]=p; l+=p; }
#pragma unroll
    for (int off=8;off>=1;off>>=1) l += __shfl_xor(l, off);
    rcp[r] = 1.f/l;
  }
  int prow_base = wid*16 + (lane>>4)*4;
#pragma unroll
  for (int nt=0;nt<16;++nt){
    int col = nt*16 + (lane&15);
#pragma unroll
    for (int r=0;r<4;++r){
      int row = prow_base + r;
      Ps[row*256 + (col ^ ((row&7)<<3))] = f2b(s[nt][r]);
    }
  }
  __syncthreads();
  for (int i=tid; i<4096; i+=256){
    int d = i>>6, k4 = (i&63)*4;
    ushort4 u = *(const ushort4*)(WmT + ((size_t)h*DHD + d)*MM + k4);
    *(ushort4*)(&KWs[d*256 + (k4 ^ ((d&7)<<3))]) = u;
  }
  __syncthreads();
  f32x4 acc[4] = {};
  int arow = wid*16 + (lane&15);
#pragma unroll
  for (int ks=0;ks<8;++ks){
    int kk = ks*32 + (lane>>4)*8;
    bf16x8 a = *(const bf16x8*)(&Ps[arow*256 + (kk ^ ((arow&7)<<3))]);
#pragma unroll
    for (int dt=0;dt<4;++dt){
      int d = dt*16 + (lane&15);
      bf16x8 b = *(const bf16x8*)(&KWs[d*256 + (kk ^ ((d&7)<<3))]);
      acc[dt] = __builtin_amdgcn_mfma_f32_16x16x32_bf16(a, b, acc[dt], 0,0,0);
    }
  }
#pragma unroll
  for (int r=0;r<4;++r){
    int row = q0 + prow_base + r;
    us* op = OH + (size_t)row*DIM + h*DHD;
#pragma unroll
    for (int dt=0;dt<4;++dt)
      op[dt*16 + (lane&15)] = f2b(acc[dt][r]*rcp[r]);
  }
}

// ---------------- depthwise conv along seq, bf16 RMW ----------------
#define SCBLK 32
__global__ __launch_bounds__(256) void k_seqconv(const us* __restrict__ Vb,
    const float* __restrict__ resk, us* __restrict__ OH)
{
  __shared__ us Vs[64*512];
  int tid = threadIdx.x;
  int p0 = blockIdx.x*SCBLK;
  for (int i=tid; i<16384; i+=256){
    int pl = i>>8, c2 = i&255;
    int gp = p0 - 16 + pl;
    int hh = c2>>5, d2 = (c2&31)*2;
    ushort2 v = make_ushort2(0,0);
    if (gp>=0 && gp<NPAD) v = *(const ushort2*)(Vb + ((size_t)hh*NPAD+gp)*DHD + d2);
    *(ushort2*)(&Vs[pl*512 + c2*2]) = v;
  }
  __syncthreads();
  int h = tid>>5;
  float kr[33];
#pragma unroll
  for (int r=0;r<33;++r) kr[r] = resk[h*33+r];
  for (int pl=0; pl<SCBLK; ++pl){
    float s0=0.f, s1=0.f;
#pragma unroll
    for (int r=0;r<33;++r){
      ushort2 v = *(const ushort2*)(&Vs[(pl+r)*512 + tid*2]);
      s0 += bf2f(v.x)*kr[r];
      s1 += bf2f(v.y)*kr[r];
    }
    size_t o = (size_t)(p0+pl)*DIM + tid*2;
    ushort2 cur = *(ushort2*)(OH + o);
    *(ushort2*)(OH + o) = make_ushort2(f2b(bf2f(cur.x)+s0), f2b(bf2f(cur.y)+s1));
  }
}

// ---------------- leff (bf16 planes, bf16 X) ----------------
__global__ void k_tfwd(const us* __restrict__ X, us* __restrict__ T)
{
  __shared__ us tile[32][33];
  int tx = threadIdx.x & 31, ty = threadIdx.x >> 5;
  int s0 = blockIdx.x*32, c0 = blockIdx.y*32;
  for (int yy=0; yy<4; ++yy){
    int s = s0 + ty + yy*8;
    if (s < NTOK) tile[ty+yy*8][tx] = X[(size_t)(1+s)*DIM + c0+tx];
  }
  __syncthreads();
  for (int yy=0; yy<4; ++yy){
    int c = c0 + ty + yy*8;
    int s = s0 + tx;
    if (s < NTOK) T[(size_t)c*NTOK + s] = tile[tx][ty+yy*8];
  }
}
__global__ void k_tbwd(const us* __restrict__ T, us* __restrict__ X)
{
  __shared__ us tile[32][33];
  int tx = threadIdx.x & 31, ty = threadIdx.x >> 5;
  int s0 = blockIdx.x*32, c0 = blockIdx.y*32;
  for (int yy=0; yy<4; ++yy){
    int c = c0 + ty + yy*8, s = s0 + tx;
    if (s < NTOK) tile[ty+yy*8][tx] = T[(size_t)c*NTOK + s];
  }
  __syncthreads();
  for (int yy=0; yy<4; ++yy){
    int s = s0 + ty + yy*8, c = c0 + tx;
    if (s < NTOK) X[(size_t)(1+s)*DIM + c] = tile[tx][ty+yy*8];
  }
}
__global__ __launch_bounds__(256) void k_leff(const us* __restrict__ T,
    const float* __restrict__ k7, const float* __restrict__ b7,
    const float* __restrict__ k5, const float* __restrict__ b5,
    const float* __restrict__ k3, const float* __restrict__ b3,
    us* __restrict__ T2)
{
  __shared__ float tile[21*21];
  int c = blockIdx.y;
  int ti = blockIdx.x/10, tj = blockIdx.x%10;
  int i0 = ti*15-3, j0 = tj*15-3;
  const us* img = T + (size_t)c*NTOK;
  for (int idx=threadIdx.x; idx<441; idx+=256){
    int ii = idx/21, jj = idx%21;
    int gi = i0+ii, gj = j0+jj;
    tile[idx] = (gi>=0 && gi<HSZ && gj>=0 && gj<HSZ) ? bf2f(img[gi*HSZ+gj]) : 0.f;
  }
  __syncthreads();
  if (threadIdx.x < 225){
    int li = threadIdx.x/15, lj = threadIdx.x%15;
    int gi = ti*15+li, gj = tj*15+lj;
    float acc = tile[(li+3)*21 + (lj+3)] + b7[c]+b5[c]+b3[c];
    const float* w7 = k7 + c*49;
#pragma unroll
    for (int a=0;a<7;++a)
#pragma unroll
      for (int bb=0;bb<7;++bb) acc += tile[(li+a)*21 + (lj+bb)]*w7[a*7+bb];
    const float* w5 = k5 + c*25;
#pragma unroll
    for (int a=0;a<5;++a)
#pragma unroll
      for (int bb=0;bb<5;++bb) acc += tile[(li+1+a)*21 + (lj+1+bb)]*w5[a*5+bb];
    const float* w3 = k3 + c*9;
#pragma unroll
    for (int a=0;a<3;++a)
#pragma unroll
      for (int bb=0;bb<3;++bb) acc += tile[(li+2+a)*21 + (lj+2+bb)]*w3[a*3+bb];
    T2[(size_t)c*NTOK + gi*HSZ+gj] = f2b(acc);
  }
}

// ---------------- cls-row pieces ----------------
__global__ void k_row1(const float* __restrict__ Q0, const float* __restrict__ KL0,
                       float* __restrict__ row1)
{
  __shared__ float sb[4];
  __shared__ float qv[64];
  int t = threadIdx.x;
  if (t<64) qv[t] = Q0[PADR*DHD + t];
  __syncthreads();
  float l = 0.f;
#pragma unroll
  for (int d=0;d<64;++d) l += qv[d]*KL0[(size_t)t*DHD+d];
  float m = blockMax256(l, sb);
  float e = __expf(l-m);
  float s = blockSum256(e, sb);
  row1[t] = e/s;
}
__global__ void k_rz(const float* __restrict__ row1, const us* __restrict__ Zt,
                     float* __restrict__ rz)
{
  __shared__ float r1[256];
  int t = threadIdx.x;
  r1[t] = row1[t];
  __syncthreads();
  float s = 0.f;
  for (int k2=0;k2<256;++k2) s += r1[k2]*bf2f(Zt[(size_t)t*MM + k2]);
  rz[t] = s;
}
__global__ void k_rowstat(const float* __restrict__ L0, float* __restrict__ mx, float* __restrict__ se)
{
  __shared__ float sb[4];
  const float* row = L0 + (size_t)blockIdx.x*NPAD;
  float m = -1e30f;
  for (int i=threadIdx.x;i<NPAD;i+=256) m = fmaxf(m, row[i]);
  m = blockMax256(m, sb);
  float s = 0.f;
  for (int i=threadIdx.x;i<NPAD;i+=256) s += __expf(row[i]-m);
  s = blockSum256(s, sb);
  if (threadIdx.x==0){ mx[blockIdx.x]=m; se[blockIdx.x]=s; }
}
__global__ void k_aout(const float* __restrict__ L0, const float* __restrict__ rz,
    const float* __restrict__ mx, const float* __restrict__ se, float* __restrict__ out)
{
  __shared__ float wk[256], mk[256];
  int t = threadIdx.x;
  wk[t] = rz[t]/se[t];
  mk[t] = mx[t];
  __syncthreads();
  int p = blockIdx.x*256 + t;
  if (p >= NTOK) return;
  size_t pp = (size_t)(PADR+1+p);
  float a = 0.f;
  for (int k2=0;k2<256;++k2) a += wk[k2]*__expf(L0[(size_t)k2*NPAD+pp]-mk[k2]);
  out[4+p] = a;
}
__global__ void k_final(const us* __restrict__ H2r, const float* __restrict__ nw,
    const float* __restrict__ nbb, const float* __restrict__ w2, const float* __restrict__ b2,
    float* __restrict__ out)
{
  __shared__ float sb[4];
  __shared__ float hf[512];
  int t = threadIdx.x;
  float x0 = bf2f(H2r[t]), x1 = bf2f(H2r[256+t]);
  float s = blockSum256(x0+x1, sb);
  float q = blockSum256(x0*x0+x1*x1, sb);
  float mean = s*(1.f/512.f);
  float var = q*(1.f/512.f) - mean*mean;
  float rstd = rsqrtf(var+1e-5f);
  hf[t]     = (x0-mean)*rstd*nw[t]+nbb[t];
  hf[256+t] = (x1-mean)*rstd*nw[256+t]+nbb[256+t];
  __syncthreads();
  float p0 = hf[t]*w2[t*2]   + hf[256+t]*w2[(256+t)*2];
  float p1 = hf[t]*w2[t*2+1] + hf[256+t]*w2[(256+t)*2+1];
  p0 = blockSum256(p0, sb);
  p1 = blockSum256(p1, sb);
  if (t==0){
    float l0 = p0+b2[0], l1 = p1+b2[1];
    float m = fmaxf(l0,l1);
    float e0 = __expf(l0-m), e1 = __expf(l1-m), si = 1.f/(e0+e1);
    out[0]=l0; out[1]=l1; out[2]=e0*si; out[3]=e1*si;
  }
}

// ---------------- host orchestration ----------------
struct Bufs {
  float *A2,*sums,*scl,*Pmax,*Psum;
  us *Xb,*Yb,*OHb,*Qb,*Kb,*Vb,*Vtb,*QLb,*KLb,*A2b;
  us *Z0b,*Z0tb,*Z1b,*Z1tb,*XZb,*XZtb,*T1tb,*T2tb;
  us *A3Vtb,*WmT,*Pacc,*zpg;
};

static void run_pinv(const us* A2b, Bufs& b, int NB, hipStream_t st,
                     us** outZ, us** outZt)
{
  dim3 g(4,4,NB);
  us *Zc=b.Z0b, *Zct=b.Z0tb, *Zn=b.Z1b, *Znt=b.Z1tb;
  for (int it=0; it<6; ++it){
    k_pgemm<0><<<g,256,0,st>>>(A2b, Zct, b.XZb, b.XZtb, 0.f, 1.f, 1);
    k_pgemm<1><<<g,256,0,st>>>(b.XZb, b.XZtb, nullptr, b.T1tb, 7.f, 1.f, 0);
    k_pgemm<1><<<g,256,0,st>>>(b.XZb, b.T1tb, nullptr, b.T2tb, 15.f, 1.f, 0);
    k_pgemm<1><<<g,256,0,st>>>(Zc, b.T2tb, Zn, Znt, 13.f, 0.25f, 1);
    us* t1=Zc; Zc=Zn; Zn=t1;
    us* t2=Zct; Zct=Znt; Znt=t2;
  }
  *outZ = Zc; *outZt = Zct;
}

static void nystrom_layer(Bufs& b, const float* lnw, const float* lnb,
    const us* wqkvT, const us* woutT,
    const float* bout, const float* resk, hipStream_t st)
{
  k_ln<<<N1,256,0,st>>>(b.Xb, b.Yb, lnw, lnb);
  k_gemm<1><<<dim3(NPAD/128,12),256,0,st>>>(nullptr, b.Yb, wqkvT, nullptr,
      nullptr, nullptr, nullptr, b.Qb, b.Kb, b.Vb, b.zpg, DIM);
  k_vT<<<dim3(NPAD/32,16),256,0,st>>>(b.Vb, b.Vtb);
  k_landmark2<<<2*NH*MM,64,0,st>>>(b.Qb, b.Kb, b.QLb, b.KLb);
  k_nt64b<<<dim3(4,4,NH),64,0,st>>>(b.QLb, b.KLb, b.A2,
      (long)MM*DHD,(long)MM*DHD,(long)MM*MM, MM);
  k_softmax256<<<NH*MM,256,0,st>>>(b.A2, b.A2b);
  k_csmax<<<NH,256,0,st>>>(b.A2, b.sums);
  k_scale2<<<1,256,0,st>>>(b.sums, b.scl, NH);
  k_z0<<<NH*MM*MM/256,256,0,st>>>(b.A2, b.Z0b, b.Z0tb, b.scl);
  us *Zc, *Zct;
  run_pinv(b.A2b, b, NH, st, &Zc, &Zct);
  k_attn3<<<dim3(NCH,NH),256,0,st>>>(b.QLb, b.Kb, b.Vtb, b.Pmax, b.Psum, b.Pacc);
  k_attn3_merge<<<NH*MM,64,0,st>>>(b.Pmax, b.Psum, b.Pacc, b.A3Vtb);
  k_pgemm<2><<<dim3(1,4,NH),256,0,st>>>(Zc, b.A3Vtb, nullptr, b.WmT, 0.f, 1.f, 0);
  k_attn1<<<dim3(NPAD/64,NH),256,0,st>>>(b.Qb, b.KLb, b.WmT, b.OHb);
  k_seqconv<<<NPAD/SCBLK,256,0,st>>>(b.Vb, resk, b.OHb);
  k_gemm<2><<<dim3(176,4),256,0,st>>>(nullptr, b.OHb, woutT, bout,
      b.Xb, nullptr, nullptr, nullptr, nullptr, nullptr, b.zpg, DIM);
}

extern "C" void kernel_launch(void* const* d_in, const int* in_sizes, int n_in,
                              void* d_out, int out_size, void* d_ws, size_t ws_size,
                              hipStream_t stream)
{
  (void)n_in; (void)out_size;
  bool sig_order = (in_sizes[10] == 25088);
  int iL2 = sig_order ? 16 : 10;
  int iLf = sig_order ? 10 : 16;

  const float* h       = (const float*)d_in[0];
  const float* fc1_w   = (const float*)d_in[1];
  const float* fc1_b   = (const float*)d_in[2];
  const float* cls_tok = (const float*)d_in[3];
  const float* l1_lnw  = (const float*)d_in[4];
  const float* l1_lnb  = (const float*)d_in[5];
  const float* l1_wqkv = (const float*)d_in[6];
  const float* l1_wout = (const float*)d_in[7];
  const float* l1_bout = (const float*)d_in[8];
  const float* l1_resk = (const float*)d_in[9];
  const float* l2_lnw  = (const float*)d_in[iL2+0];
  const float* l2_lnb  = (const float*)d_in[iL2+1];
  const float* l2_wqkv = (const float*)d_in[iL2+2];
  const float* l2_wout = (const float*)d_in[iL2+3];
  const float* l2_bout = (const float*)d_in[iL2+4];
  const float* l2_resk = (const float*)d_in[iL2+5];
  const float* k7 = (const float*)d_in[iLf+0];
  const float* b7 = (const float*)d_in[iLf+1];
  const float* k5 = (const float*)d_in[iLf+2];
  const float* b5 = (const float*)d_in[iLf+3];
  const float* k3 = (const float*)d_in[iLf+4];
  const float* b3 = (const float*)d_in[iLf+5];
  const float* nw = (const float*)d_in[22];
  const float* nbb= (const float*)d_in[23];
  const float* w2 = (const float*)d_in[24];
  const float* b2 = (const float*)d_in[25];
  float* out = (float*)d_out;

  char* base = (char*)d_ws;
  auto allocF = [&](size_t n)->float*{
    float* p=(float*)base; base += ((n*sizeof(float)+255)&~(size_t)255); return p; };
  auto allocU = [&](size_t n)->us*{
    us* p=(us*)base; base += ((n*sizeof(us)+255)&~(size_t)255); return p; };

  const size_t S = (size_t)NPAD*DIM;
  const size_t SQ = (size_t)MM*MM;
  Bufs b;
  b.Xb  = allocU(S);
  b.Yb  = allocU(S);
  b.OHb = allocU(S);
  b.Qb  = allocU(S);
  b.Kb  = allocU(S);
  b.Vb  = allocU(S);
  b.Vtb = allocU(S);
  b.QLb = allocU((size_t)NH*MM*DHD);
  b.KLb = allocU((size_t)NH*MM*DHD);
  b.A2  = allocF((size_t)NH*SQ);
  b.A2b = allocU((size_t)NH*SQ);
  b.Z0b = allocU((size_t)NH*SQ);  b.Z0tb = allocU((size_t)NH*SQ);
  b.Z1b = allocU((size_t)NH*SQ);  b.Z1tb = allocU((size_t)NH*SQ);
  b.XZb = allocU((size_t)NH*SQ);  b.XZtb = allocU((size_t)NH*SQ);
  b.T1tb= allocU((size_t)NH*SQ);
  b.T2tb= allocU((size_t)NH*SQ);
  b.A3Vtb = allocU((size_t)NH*MM*DHD);
  b.WmT   = allocU((size_t)NH*MM*DHD);
  b.sums  = allocF(2*(size_t)NH*MM);
  b.scl   = allocF(16);
  b.Pmax  = allocF((size_t)NH*NCH*MM);
  b.Psum  = allocF((size_t)NH*NCH*MM);
  b.Pacc  = allocU((size_t)NH*NCH*MM*DHD);
  b.zpg   = allocU(512);
  us* fc1T   = allocU((size_t)DIM*1024);
  us* wqkvT1 = allocU((size_t)1536*DIM);
  us* wqkvT2 = allocU((size_t)1536*DIM);
  us* woutT1 = allocU((size_t)DIM*DIM);
  us* woutT2 = allocU((size_t)DIM*DIM);
  float* Q0   = allocF((size_t)NPAD*DHD);
  float* K0   = allocF((size_t)NPAD*DHD);
  float* QL0f = allocF((size_t)MM*DHD);
  float* KL0f = allocF((size_t)MM*DHD);
  float* row1 = allocF(256);
  float* rzv  = allocF(256);
  float* mxv  = allocF(256);
  float* sev  = allocF(256);
  us* h2row = allocU(512);
  if ((size_t)(base - (char*)d_ws) > ws_size) return;

  hipMemsetAsync((void*)b.zpg, 0, 1024, stream);

  // weight transposes (fp32 -> bf16 [N][K])
  k_wT<<<dim3(32,16),256,0,stream>>>(fc1_w, fc1T, 1024, DIM);
  k_wT<<<dim3(16,48),256,0,stream>>>(l1_wqkv, wqkvT1, DIM, 1536);
  k_wT<<<dim3(16,48),256,0,stream>>>(l2_wqkv, wqkvT2, DIM, 1536);
  k_wT<<<dim3(16,16),256,0,stream>>>(l1_wout, woutT1, DIM, DIM);
  k_wT<<<dim3(16,16),256,0,stream>>>(l2_wout, woutT2, DIM, DIM);

  // stage 0: fc1 + cls token
  k_gemm<0><<<dim3(176,4),256,0,stream>>>(h, nullptr, fc1T, fc1_b,
      b.Xb, nullptr, nullptr, nullptr, nullptr, nullptr, b.zpg, 1024);
  k_setcls<<<2,256,0,stream>>>(b.Xb, cls_tok);

  // layer 1 + LeFF
  nystrom_layer(b, l1_lnw, l1_lnb, wqkvT1, woutT1, l1_bout, l1_resk, stream);
  k_tfwd<<<dim3(704,16),256,0,stream>>>(b.Xb, b.OHb);
  k_leff<<<dim3(100,512),256,0,stream>>>(b.OHb, k7,b7,k5,b5,k3,b3, b.Qb);
  k_tbwd<<<dim3(704,16),256,0,stream>>>(b.Qb, b.Xb);

  // layer 2 (save h2 row 0)
  nystrom_layer(b, l2_lnw, l2_lnb, wqkvT2, woutT2, l2_bout, l2_resk, stream);
  k_copyu<<<2,256,0,stream>>>(h2row, b.Xb, 512);

  // layer 3 -> h3
  nystrom_layer(b, l2_lnw, l2_lnb, wqkvT2, woutT2, l2_bout, l2_resk, stream);

  // cls-row stage (head 0, l2 weights, LN(h3))
  k_ln<<<N1,256,0,stream>>>(b.Xb, b.Yb, l2_lnw, l2_lnb);
  k_gemm<3><<<dim3(176,1),256,0,stream>>>(nullptr, b.Yb, wqkvT2, nullptr,
      nullptr, Q0, K0, nullptr, nullptr, nullptr, b.zpg, DIM);
  k_landmark2f<<<2*MM,64,0,stream>>>(Q0, K0, QL0f, KL0f);
  k_nt64<<<dim3(4,4,1),64,0,stream>>>(QL0f, KL0f, b.A2, 0,0,0, MM);
  k_softmax256<<<MM,256,0,stream>>>(b.A2, b.A2b);
  k_csmax<<<1,256,0,stream>>>(b.A2, b.sums);
  k_scale2<<<1,256,0,stream>>>(b.sums, b.scl, 1);
  k_z0<<<MM*MM/256,256,0,stream>>>(b.A2, b.Z0b, b.Z0tb, b.scl);
  us *Zc, *Zct;
  run_pinv(b.A2b, b, 1, stream, &Zc, &Zct);
  k_row1<<<1,256,0,stream>>>(Q0, KL0f, row1);
  k_rz<<<1,256,0,stream>>>(row1, Zct, rzv);
  // L0 = QL0 @ K0^T (256 x NPAD), into Yb's storage (NPAD*256 floats)
  float* L0 = (float*)b.Yb;
  k_nt64<<<dim3(NPAD/64,4,1),64,0,stream>>>(QL0f, K0, L0, 0,0,0, NPAD);
  k_rowstat<<<MM,256,0,stream>>>(L0, mxv, sev);
  k_aout<<<88,256,0,stream>>>(L0, rzv, mxv, sev, out);
  k_final<<<1,256,0,stream>>>(h2row, nw, nbb, w2, b2, out);
}